// Round 10
// baseline (1045.115 us; speedup 1.0000x reference)
//
#include <hip/hip_runtime.h>
#include <math.h>

#define B_ 4
#define H_ 8
#define L_ 1520
#define DM_ 512
#define DFF_ 2048
#define SK_ 40
#define ML_ (B_*L_)   /* 6080 rows */
#define MP_ 6144      /* padded rows for MFMA GEMM */
#define LP_ 1536      /* padded key count for V^T */

typedef unsigned short u16;
typedef short s8v __attribute__((ext_vector_type(8)));
typedef float f4 __attribute__((ext_vector_type(4)));

__device__ __forceinline__ u16 f2b(float x) {
  union { float f; unsigned u; } c; c.f = x;
  unsigned r = c.u + 0x7FFFu + ((c.u >> 16) & 1u);
  return (u16)(r >> 16);
}
__device__ __forceinline__ float b2f(u16 h) {
  union { unsigned u; float f; } c; c.u = ((unsigned)h) << 16;
  return c.f;
}
__device__ __forceinline__ float gelu_tanh(float x) {
  float x3 = x * x * x;
  return 0.5f * x * (1.f + tanhf(0.79788456080286536f * (x + 0.044715f * x3)));
}
// XCD-chunked bijective swizzle; requires nwg % 8 == 0 (cpx = nwg/8).
__device__ __forceinline__ int xswz(int bid, int cpx) {
  return (bid & 7) * cpx + (bid >> 3);
}

// ---------------- positional encoding (double precision to match numpy) ----
__global__ __launch_bounds__(256) void pe_kernel(float* __restrict__ pe) {
  int idx = blockIdx.x * 256 + threadIdx.x;
  if (idx >= L_ * DM_) return;
  int pos = idx / DM_, i = idx % DM_;
  double expo = (double)(2 * (i / 2)) / (double)DM_;
  double ang = (double)pos / pow(10000.0, expo);
  pe[idx] = (i & 1) ? (float)cos(ang) : (float)sin(ang);
}

// ---------------- x = inflow[:,2:14].reshape (contiguous slice) -------------
__global__ __launch_bounds__(256) void extract_x(const float* __restrict__ inflow,
                                                 float* __restrict__ X) {
  int idx = blockIdx.x * 256 + threadIdx.x;
  if (idx >= ML_ * 12) return;
  int b = idx / (L_ * 12);
  int rem = idx - b * (L_ * 12);
  X[idx] = inflow[(size_t)b * 14 * L_ + 2 * L_ + rem];
}

// ---------------- fused weight convert+transpose (LDS tiled, coalesced) -----
// Each block transposes one 32(k)x32(n) tile of one source matrix.
struct CvtArgs {
  const float* src[15];
  unsigned cumt[16];   // cumulative 32x32-tile counts
  unsigned lk[15];     // log2(K) per segment
};
__global__ __launch_bounds__(256) void cvt_all(CvtArgs a, u16* __restrict__ dst) {
  __shared__ float tl[32][33];
  int bt = blockIdx.x;                 // grid exact: 10240 tiles
  int s = 0;
#pragma unroll
  for (int i = 1; i < 15; ++i) s += (bt >= (int)a.cumt[i]);
  int lt = bt - a.cumt[s];
  unsigned lk = a.lk[s];
  unsigned K = 1u << lk;
  unsigned N = ((a.cumt[s + 1] - a.cumt[s]) << 10) >> lk;
  unsigned tiles_n = N >> 5;
  unsigned k0 = (lt / tiles_n) * 32, n0 = (lt % tiles_n) * 32;
  const float* src = a.src[s];
  int r = threadIdx.x >> 5, c = threadIdx.x & 31;
#pragma unroll
  for (int i = 0; i < 4; ++i)
    tl[r + 8 * i][c] = src[(size_t)(k0 + r + 8 * i) * N + n0 + c];
  __syncthreads();
  u16* d = dst + ((size_t)a.cumt[s] << 10);
#pragma unroll
  for (int i = 0; i < 4; ++i)
    d[(size_t)(n0 + r + 8 * i) * K + k0 + c] = f2b(tl[c][r + 8 * i]);
}

// ---------------- fused embed: ACT = X@W + b + PE ; ACTb = bf16(ACT) --------
__global__ __launch_bounds__(256) void embed_fused(
    const float* __restrict__ X, const float* __restrict__ W,
    const float* __restrict__ bias, const float* __restrict__ PE,
    float* __restrict__ ACT, u16* __restrict__ ACTb) {
  int row = blockIdx.x * 4 + (threadIdx.x >> 6);
  int lane = threadIdx.x & 63;
  int d0 = lane * 8;
  if (row >= ML_) {
    s8v z = {0, 0, 0, 0, 0, 0, 0, 0};
    *(s8v*)(ACTb + (size_t)row * DM_ + d0) = z;
    return;
  }
  int prow = row % L_;
  f4 a0 = *(const f4*)(bias + d0);
  f4 a1 = *(const f4*)(bias + d0 + 4);
  a0 += *(const f4*)(PE + (size_t)prow * DM_ + d0);
  a1 += *(const f4*)(PE + (size_t)prow * DM_ + d0 + 4);
  const float* xr = X + (size_t)row * 12;
#pragma unroll
  for (int t = 0; t < 12; ++t) {
    float xv = xr[t];
    a0 += xv * *(const f4*)(W + (size_t)t * DM_ + d0);
    a1 += xv * *(const f4*)(W + (size_t)t * DM_ + d0 + 4);
  }
  float* dst = ACT + (size_t)row * DM_ + d0;
  *(f4*)dst = a0;
  *(f4*)(dst + 4) = a1;
  u16 ob[8];
#pragma unroll
  for (int i = 0; i < 4; ++i) { ob[i] = f2b(a0[i]); ob[4 + i] = f2b(a1[i]); }
  *(s8v*)(ACTb + (size_t)row * DM_ + d0) = *(s8v*)ob;
}

// ---------------- fused head: out = relu((DEC@Wp+bp+X)@W1+b1)@W3+b3 ---------
__global__ __launch_bounds__(256) void head_fused(
    const float* __restrict__ DEC, const float* __restrict__ X,
    const float* __restrict__ Wp, const float* __restrict__ bp,
    const float* __restrict__ W1, const float* __restrict__ b1,
    const float* __restrict__ W3, const float* __restrict__ b3,
    float* __restrict__ out) {
  int row = blockIdx.x * 4 + (threadIdx.x >> 6);
  int lane = threadIdx.x & 63;
  int d0 = lane * 8;
  const float* dec = DEC + (size_t)row * DM_ + d0;
  f4 v0 = *(const f4*)dec;
  f4 v1 = *(const f4*)(dec + 4);
  float pj[12];
#pragma unroll
  for (int j = 0; j < 12; ++j) pj[j] = 0.f;
#pragma unroll
  for (int i = 0; i < 8; ++i) {
    float dv = (i < 4) ? v0[i] : v1[i - 4];
    const float* wr = Wp + (size_t)(d0 + i) * 12;
#pragma unroll
    for (int j = 0; j < 12; ++j) pj[j] += dv * wr[j];
  }
  for (int off = 32; off; off >>= 1) {
#pragma unroll
    for (int j = 0; j < 12; ++j) pj[j] += __shfl_xor(pj[j], off);
  }
  float o12[12];
#pragma unroll
  for (int j = 0; j < 12; ++j) o12[j] = pj[j] + bp[j] + X[(size_t)row * 12 + j];
  int k0 = lane * 2;
  float h0 = b1[k0], h1 = b1[k0 + 1];
#pragma unroll
  for (int j = 0; j < 12; ++j) {
    h0 += o12[j] * W1[j * 128 + k0];
    h1 += o12[j] * W1[j * 128 + k0 + 1];
  }
  h0 = fmaxf(h0, 0.f);
  h1 = fmaxf(h1, 0.f);
  float op[3];
#pragma unroll
  for (int p = 0; p < 3; ++p)
    op[p] = h0 * W3[k0 * 3 + p] + h1 * W3[(k0 + 1) * 3 + p];
  for (int off = 32; off; off >>= 1) {
#pragma unroll
    for (int p = 0; p < 3; ++p) op[p] += __shfl_xor(op[p], off);
  }
  if (lane == 0) {
#pragma unroll
    for (int p = 0; p < 3; ++p) out[(size_t)row * 3 + p] = op[p] + b3[p];
  }
}

// ---------------- bf16 MFMA GEMM, 2-phase double-buffered, XCD-swizzled -----
// Per iteration: STAGE(next buf) -> ds_read/MFMA(cur) -> one __syncthreads
// (emits vmcnt(0)+barrier: completes next staging, protects overwrite).
template<int BM>
__global__ __launch_bounds__(256) void gemm_bf16(
    const u16* __restrict__ A, const u16* __restrict__ Bt,
    const float* __restrict__ bias, const float* __restrict__ res,
    float* __restrict__ Cf, u16* __restrict__ Cb,
    int N, int K, int act) {
  __shared__ __align__(16) u16 As[2][BM * 32];
  __shared__ __align__(16) u16 Bs[2][128 * 32];
  constexpr int MI = BM / 32;
  const int nwg = gridDim.x * gridDim.y;
  const int lin = blockIdx.y * gridDim.x + blockIdx.x;
  const int o = xswz(lin, nwg >> 3);
  const int bxi = o % gridDim.x, byi = o / gridDim.x;
  const int t = threadIdx.x, w = t >> 6, lane = t & 63;
  const int lg = lane >> 4, li = lane & 15;
  const int bm = byi * BM, bn = bxi * 128;
  const int wr = (w >> 1) * (BM / 2), wc = (w & 1) * 64;
  f4 acc[MI][4];
#pragma unroll
  for (int i = 0; i < MI; ++i)
#pragma unroll
    for (int j = 0; j < 4; ++j) acc[i][j] = f4{0.f, 0.f, 0.f, 0.f};
  const int rB = w * 32 + (lane >> 2);
  const int rA = (BM == 128) ? rB : (w * 16 + (lane >> 2));
  const int ps = lane & 3;

  auto STAGE = [&](int bf, int k0) {
    if (BM == 128) {
#pragma unroll
      for (int j = 0; j < 2; ++j) {
        int r = rA + j * 16;
        int ls = ps ^ ((r >> 1) & 3);
        __builtin_amdgcn_global_load_lds(
            (const __attribute__((address_space(1))) void*)(A + (size_t)(bm + r) * K + k0 + ls * 8),
            (__attribute__((address_space(3))) void*)(&As[bf][(w * 32 + j * 16) * 32]),
            16, 0, 0);
      }
    } else {
      int ls = ps ^ ((rA >> 1) & 3);
      __builtin_amdgcn_global_load_lds(
          (const __attribute__((address_space(1))) void*)(A + (size_t)(bm + rA) * K + k0 + ls * 8),
          (__attribute__((address_space(3))) void*)(&As[bf][(w * 16) * 32]),
          16, 0, 0);
    }
#pragma unroll
    for (int j = 0; j < 2; ++j) {
      int r = rB + j * 16;
      int ls = ps ^ ((r >> 1) & 3);
      __builtin_amdgcn_global_load_lds(
          (const __attribute__((address_space(1))) void*)(Bt + (size_t)(bn + r) * K + k0 + ls * 8),
          (__attribute__((address_space(3))) void*)(&Bs[bf][(w * 32 + j * 16) * 32]),
          16, 0, 0);
    }
  };

  STAGE(0, 0);
  __syncthreads();
  int cur = 0;
  for (int k0 = 0; k0 < K; k0 += 32) {
    const bool has_next = (k0 + 32 < K);
    if (has_next) STAGE(cur ^ 1, k0 + 32);
    s8v af[MI], bf[4];
#pragma unroll
    for (int f = 0; f < MI; ++f) {
      int ra = wr + f * 16 + li;
      af[f] = *(const s8v*)(&As[cur][ra * 32 + ((lg ^ ((ra >> 1) & 3)) * 8)]);
    }
#pragma unroll
    for (int f = 0; f < 4; ++f) {
      int rb = wc + f * 16 + li;
      bf[f] = *(const s8v*)(&Bs[cur][rb * 32 + ((lg ^ ((rb >> 1) & 3)) * 8)]);
    }
#pragma unroll
    for (int fi = 0; fi < MI; ++fi)
#pragma unroll
      for (int fj = 0; fj < 4; ++fj)
        acc[fi][fj] = __builtin_amdgcn_mfma_f32_16x16x32_bf16(af[fi], bf[fj], acc[fi][fj], 0, 0, 0);
    if (has_next) __syncthreads();
    cur ^= 1;
  }
#pragma unroll
  for (int fi = 0; fi < MI; ++fi)
#pragma unroll
    for (int fj = 0; fj < 4; ++fj)
#pragma unroll
      for (int r = 0; r < 4; ++r) {
        int row = bm + wr + fi * 16 + lg * 4 + r;
        int col = bn + wc + fj * 16 + li;
        float v = acc[fi][fj][r] + bias[col];
        if (res && row < ML_) v += res[(size_t)row * N + col];
        if (act == 1) v = gelu_tanh(v);
        if (Cf && row < ML_) Cf[(size_t)row * N + col] = v;
        if (Cb) Cb[(size_t)row * N + col] = f2b(v);
      }
}

// ---------------- layernorm: wave per row, vectorized -----------------------
__global__ __launch_bounds__(256) void layernorm_ip(float* __restrict__ Xb,
                                                    const float* __restrict__ g,
                                                    const float* __restrict__ bta,
                                                    u16* __restrict__ outb) {
  int row = blockIdx.x * 4 + (threadIdx.x >> 6);
  int lane = threadIdx.x & 63;
  float* x = Xb + (size_t)row * DM_;
  f4 a = *(f4*)(x + lane * 8);
  f4 b = *(f4*)(x + lane * 8 + 4);
  float s = a[0] + a[1] + a[2] + a[3] + b[0] + b[1] + b[2] + b[3];
  for (int off = 32; off; off >>= 1) s += __shfl_xor(s, off);
  float mu = s * (1.f / 512.f);
  float vs = 0.f;
#pragma unroll
  for (int i = 0; i < 4; ++i) { a[i] -= mu; b[i] -= mu; vs += a[i] * a[i] + b[i] * b[i]; }
  for (int off = 32; off; off >>= 1) vs += __shfl_xor(vs, off);
  float rs = rsqrtf(vs * (1.f / 512.f) + 1e-5f);
  f4 g0 = *(const f4*)(g + lane * 8), g1 = *(const f4*)(g + lane * 8 + 4);
  f4 c0 = *(const f4*)(bta + lane * 8), c1 = *(const f4*)(bta + lane * 8 + 4);
  u16 ob[8];
#pragma unroll
  for (int i = 0; i < 4; ++i) {
    float r1 = a[i] * rs * g0[i] + c0[i]; x[lane * 8 + i] = r1;     ob[i] = f2b(r1);
    float r2 = b[i] * rs * g1[i] + c1[i]; x[lane * 8 + 4 + i] = r2; ob[4 + i] = f2b(r2);
  }
  *(s8v*)(outb + (size_t)row * DM_ + lane * 8) = *(s8v*)ob;
}

// ---------------- ProbSparse sparsity measure M (bf16 qkv), swizzled --------
__global__ __launch_bounds__(256) void probM(const u16* __restrict__ qkv,
                                             const int* __restrict__ sidx,
                                             float* __restrict__ Mout) {
  int wid = threadIdx.x / 64, lane = threadIdx.x % 64;
  int o = xswz(blockIdx.x, (B_ * H_ * L_ / 4) >> 3);
  int g = o * 4 + wid;
  int l = g % L_;
  int bh = g / L_;
  int h = bh % H_, b = bh / H_;
  __shared__ float qs[4][64];
  qs[wid][lane] = b2f(qkv[((size_t)b * L_ + l) * 1536 + h * 64 + lane]);
  __syncthreads();
  float dot = 0.f;
  if (lane < SK_) {
    int ks = sidx[l * SK_ + lane];
    const u16* kr = qkv + ((size_t)b * L_ + ks) * 1536 + 512 + h * 64;
#pragma unroll
    for (int j = 0; j < 8; ++j) {
      s8v v = *(const s8v*)(kr + j * 8);
#pragma unroll
      for (int i = 0; i < 8; ++i) dot += qs[wid][j * 8 + i] * b2f((u16)v[i]);
    }
  }
  float vmax = (lane < SK_) ? dot : -INFINITY;
  float vsum = (lane < SK_) ? dot : 0.f;
  for (int off = 32; off; off >>= 1) {
    vmax = fmaxf(vmax, __shfl_xor(vmax, off));
    vsum += __shfl_xor(vsum, off);
  }
  if (lane == 0) Mout[g] = vmax - vsum / (float)L_;
}

// ---------------- radix-select top-40 (matches lax.top_k selection set) -----
__global__ __launch_bounds__(256) void radix_topk(const float* __restrict__ Mv,
                                                  int* __restrict__ top) {
  const int bh = blockIdx.x;
  const int t = threadIdx.x;
  const int base = t * 6;
  unsigned key[6];
#pragma unroll
  for (int i = 0; i < 6; ++i) {
    int ix = base + i;
    unsigned k = 0u;
    if (ix < L_) {
      union { float f; unsigned u; } c; c.f = Mv[(size_t)bh * L_ + ix];
      k = c.u ^ ((c.u & 0x80000000u) ? 0xFFFFFFFFu : 0x80000000u);
    }
    key[i] = k;
  }
  __shared__ int wred[4];
  __shared__ int s_a[256], s_b[256];
  unsigned prefix = 0u;
  for (int b = 31; b >= 0; --b) {
    unsigned cand = prefix | (1u << b);
    int c = 0;
#pragma unroll
    for (int i = 0; i < 6; ++i) c += (key[i] >= cand);
    for (int off = 32; off; off >>= 1) c += __shfl_xor(c, off);
    if ((t & 63) == 0) wred[t >> 6] = c;
    __syncthreads();
    int tot = wred[0] + wred[1] + wred[2] + wred[3];
    if (tot >= SK_) prefix = cand;
    __syncthreads();
  }
  const unsigned T = prefix;
  int gt = 0, tie = 0;
#pragma unroll
  for (int i = 0; i < 6; ++i) { gt += (key[i] > T); tie += (key[i] == T); }
  s_a[t] = gt; s_b[t] = tie;
  __syncthreads();
  for (int off = 1; off < 256; off <<= 1) {
    int va = (t >= off) ? s_a[t - off] : 0;
    int vb = (t >= off) ? s_b[t - off] : 0;
    __syncthreads();
    s_a[t] += va; s_b[t] += vb;
    __syncthreads();
  }
  const int n_strict = s_a[255];
  const int gt_base = s_a[t] - gt;
  const int tie_base = s_b[t] - tie;
  const int need = SK_ - n_strict;
  int lgt = 0, ltie = 0;
#pragma unroll
  for (int i = 0; i < 6; ++i) {
    int ix = base + i;
    if (key[i] > T) {
      top[bh * SK_ + gt_base + lgt] = ix; ++lgt;
    } else if (key[i] == T) {
      int r = tie_base + ltie; ++ltie;
      if (r < need) top[bh * SK_ + n_strict + r] = ix;
    }
  }
}

// ---------------- V^T build: VT[bh][64][LP_] from V columns, swizzled -------
__global__ __launch_bounds__(256) void transpose_v(const u16* __restrict__ src,
                                                   int stride, int voff0,
                                                   u16* __restrict__ VT) {
  int o = xswz(blockIdx.x, (B_ * H_ * 24) >> 3);
  int kt = o % 24, bh = o / 24;
  int h = bh & 7, b = bh >> 3;
  int kb = kt * 64;
  __shared__ u16 tile[64][72];
  int t = threadIdx.x;
#pragma unroll
  for (int rr = 0; rr < 2; ++rr) {
    int slot = rr * 256 + t;
    int key = slot >> 3, d = (slot & 7) * 8;
    int gk = kb + key; if (gk >= L_) gk = L_ - 1;
    s8v v = *(const s8v*)(src + (size_t)(b * L_ + gk) * stride + voff0 + h * 64 + d);
    *(s8v*)(&tile[key][d]) = v;
  }
  __syncthreads();
  int dim = t >> 2, k0 = (t & 3) * 16;
  u16 buf[16];
#pragma unroll
  for (int i = 0; i < 16; ++i) {
    int key = k0 + i;
    buf[i] = (kb + key < L_) ? tile[key][dim] : (u16)0;
  }
  *(s8v*)(VT + ((size_t)bh * 64 + dim) * LP_ + kb + k0) = *(s8v*)buf;
  *(s8v*)(VT + ((size_t)bh * 64 + dim) * LP_ + kb + k0 + 8) = *(s8v*)(buf + 8);
}

// ---------------- LDS-staged swapped-operand MFMA flash attention -----------
template<int MODE>
__global__ __launch_bounds__(256) void flash_attn(
    const u16* __restrict__ Qm, const u16* __restrict__ Kg,
    const u16* __restrict__ VT, const int* __restrict__ top,
    float* __restrict__ POf, u16* POa, u16* POb,
    float* __restrict__ PM, float* __restrict__ PL) {
  constexpr int QSTR = (MODE == 0) ? 512 : 1536;
  constexpr int KSTR = (MODE == 0) ? 512 : 1536;
  constexpr int TILES = (MODE == 0) ? 12 : 3;
  constexpr int NB = (MODE == 0) ? 48 : 8;
  __shared__ __align__(16) u16 Kt[64 * 64];        // [key][slot^(key&7)]
  __shared__ __align__(16) u16 Vt[64 * 64];        // [dim][slot^(dim&7)]
  __shared__ __align__(16) unsigned Xch[4][576];   // per-wave P exchange
  const int o = xswz(blockIdx.x, (B_ * H_ * NB) >> 3);
  int bh, sp, qb;
  if (MODE == 0) {
    bh = o / 48; int rem = o % 48; qb = rem >> 1; sp = rem & 1;
  } else {
    bh = o / 8; sp = o % 8; qb = 0;
  }
  const int h = bh & 7, b = bh >> 3;
  const int qoff = h * 64;
  const int koff = ((MODE == 0) ? 0 : 512) + h * 64;
  const int t = threadIdx.x, w = t >> 6, lane = t & 63;
  const int lg = lane >> 4, li = lane & 15;
  const u16* vtg = VT + (size_t)bh * 64 * LP_;
  unsigned* xw = Xch[w];
  u16* xw16 = (u16*)xw;

  int qrow;
  if (MODE == 0) {
    int q = qb * 64 + w * 16 + li;
    qrow = b * L_ + ((q < L_) ? q : (L_ - 1));
  } else {
    int u = w * 16 + li; if (u >= SK_) u = SK_ - 1;
    qrow = b * L_ + top[bh * SK_ + u];
  }
  s8v qf0 = *(const s8v*)(Qm + (size_t)qrow * QSTR + qoff + lg * 8);
  s8v qf1 = *(const s8v*)(Qm + (size_t)qrow * QSTR + qoff + 32 + lg * 8);

  f4 o4[4];                          // o4[n][r] = O^T[d=n*16+lg*4+r][q=li]
#pragma unroll
  for (int n = 0; n < 4; ++n) o4[n] = f4{0.f, 0.f, 0.f, 0.f};
  float m_run = -INFINITY, l_run = 0.f;   // per-lane (q=li)
  const int kt0 = sp * TILES;
  const int skey = lane >> 3;
  const int sslot = lane & 7;

#pragma unroll 1
  for (int ki = 0; ki < TILES; ++ki) {
    const int kb = (kt0 + ki) * 64;
#pragma unroll
    for (int j = 0; j < 2; ++j) {
      int row = w * 16 + j * 8 + skey;
      int gk = kb + row; if (gk >= L_) gk = L_ - 1;
      int ck = sslot ^ (row & 7);
      __builtin_amdgcn_global_load_lds(
          (const __attribute__((address_space(1))) void*)(Kg + (size_t)(b * L_ + gk) * KSTR + koff + ck * 8),
          (__attribute__((address_space(3))) void*)(Kt + (w * 16 + j * 8) * 64),
          16, 0, 0);
      int cv = sslot ^ (row & 7);
      __builtin_amdgcn_global_load_lds(
          (const __attribute__((address_space(1))) void*)(vtg + (size_t)row * LP_ + kb + cv * 8),
          (__attribute__((address_space(3))) void*)(Vt + (w * 16 + j * 8) * 64),
          16, 0, 0);
    }
    __syncthreads();
    f4 s[4];
#pragma unroll
    for (int c = 0; c < 4; ++c) {
      int key = c * 16 + li;
      s8v kf = *(const s8v*)(Kt + key * 64 + ((lg ^ (key & 7)) * 8));
      s8v kg2 = *(const s8v*)(Kt + key * 64 + (((lg + 4) ^ (key & 7)) * 8));
      f4 z = f4{0.f, 0.f, 0.f, 0.f};
      z = __builtin_amdgcn_mfma_f32_16x16x32_bf16(kf, qf0, z, 0, 0, 0);
      z = __builtin_amdgcn_mfma_f32_16x16x32_bf16(kg2, qf1, z, 0, 0, 0);
      s[c] = z * 0.125f;
    }
    if (kb + 64 > L_) {
#pragma unroll
      for (int c = 0; c < 4; ++c)
#pragma unroll
        for (int r = 0; r < 4; ++r)
          if (kb + c * 16 + lg * 4 + r >= L_) s[c][r] = -INFINITY;
    }
    float tm = -INFINITY;
#pragma unroll
    for (int c = 0; c < 4; ++c)
      tm = fmaxf(tm, fmaxf(fmaxf(s[c][0], s[c][1]), fmaxf(s[c][2], s[c][3])));
    tm = fmaxf(tm, __shfl_xor(tm, 16));
    tm = fmaxf(tm, __shfl_xor(tm, 32));
    float mn = fmaxf(m_run, tm);
    float sc = __expf(m_run - mn);
    float p[4][4];
    float rs = 0.f;
#pragma unroll
    for (int c = 0; c < 4; ++c)
#pragma unroll
      for (int r = 0; r < 4; ++r) { p[c][r] = __expf(s[c][r] - mn); rs += p[c][r]; }
    rs += __shfl_xor(rs, 16);
    rs += __shfl_xor(rs, 32);
    l_run = l_run * sc + rs;
    m_run = mn;
#pragma unroll
    for (int n = 0; n < 4; ++n) o4[n] *= sc;
#pragma unroll
    for (int c = 0; c < 4; ++c)
#pragma unroll
      for (int rp = 0; rp < 2; ++rp) {
        unsigned v = (unsigned)f2b(p[c][2 * rp]) | ((unsigned)f2b(p[c][2 * rp + 1]) << 16);
        xw[li * 36 + c * 8 + lg * 2 + rp] = v;
      }
    s8v pb0 = *(const s8v*)(xw + li * 36 + lg * 4);
    s8v pb1 = *(const s8v*)(xw + li * 36 + 16 + lg * 4);
#pragma unroll
    for (int n = 0; n < 4; ++n) {
      int dim = n * 16 + li;
      s8v vb0 = *(const s8v*)(Vt + dim * 64 + ((lg ^ (dim & 7)) * 8));
      o4[n] = __builtin_amdgcn_mfma_f32_16x16x32_bf16(vb0, pb0, o4[n], 0, 0, 0);
    }
#pragma unroll
    for (int n = 0; n < 4; ++n) {
      int dim = n * 16 + li;
      s8v vb1 = *(const s8v*)(Vt + dim * 64 + (((lg + 4) ^ (dim & 7)) * 8));
      o4[n] = __builtin_amdgcn_mfma_f32_16x16x32_bf16(vb1, pb1, o4[n], 0, 0, 0);
    }
    __syncthreads();
  }

  if (MODE == 0) {
#pragma unroll
    for (int n = 0; n < 4; ++n)
#pragma unroll
      for (int r = 0; r < 4; ++r)
        xw16[li * 72 + n * 16 + lg * 4 + r] = f2b(o4[n][r]);
    u16* PO = sp ? POb : POa;
    const int pid = (bh * 24 + qb) * 2 + sp;
    int q_local = lane >> 2, d0 = (lane & 3) * 16;
    int q = qb * 64 + w * 16 + q_local;
    s8v v0 = *(const s8v*)(xw16 + q_local * 72 + d0);
    s8v v1 = *(const s8v*)(xw16 + q_local * 72 + d0 + 8);
    if (q < L_) {
      u16* dst = PO + ((size_t)(b * L_ + q)) * DM_ + qoff + d0;
      *(s8v*)dst = v0;
      *(s8v*)(dst + 8) = v1;
    }
    if (lg == 0) {
      PM[pid * 64 + w * 16 + li] = m_run;
      PL[pid * 64 + w * 16 + li] = l_run;
    }
  } else {
    int base = (bh * 8 + sp) * 64 + w * 16 + li;
#pragma unroll
    for (int n = 0; n < 4; ++n)
#pragma unroll
      for (int r = 0; r < 4; ++r)
        POf[(size_t)base * 64 + n * 16 + lg * 4 + r] = o4[n][r];
    if (lg == 0) {
      PM[base] = m_run;
      PL[base] = l_run;
    }
  }
}

// ---------------- combine 2-way cross partials (POb == ctxb, in place) ------
__global__ __launch_bounds__(256) void combine_cross(const u16* __restrict__ PO0,
                                                     const float* __restrict__ PM,
                                                     const float* __restrict__ PL,
                                                     u16* ctxb) {
  int idx = blockIdx.x * 256 + threadIdx.x;
  int row = idx >> 9, col = idx & 511;
  int b = row / L_, q = row - b * L_;
  int h = col >> 6;
  int bh = b * 8 + h, qbk = q >> 6, qi = q & 63;
  int p0 = ((bh * 24 + qbk) * 2) * 64 + qi;
  float m0 = PM[p0], m1 = PM[p0 + 64];
  float l0 = PL[p0], l1 = PL[p0 + 64];
  float M = fmaxf(m0, m1);
  float w0 = __expf(m0 - M), w1 = __expf(m1 - M);
  float inv = 1.f / (w0 * l0 + w1 * l1);
  float o0 = b2f(PO0[idx]);
  float o1 = b2f(ctxb[idx]);
  ctxb[idx] = f2b((w0 * o0 + w1 * o1) * inv);
}

// ---------------- combine split-K partials -> ctt ----------------------------
__global__ __launch_bounds__(256) void combine_prob(const float* __restrict__ PO,
                                                    const float* __restrict__ PM,
                                                    const float* __restrict__ PL,
                                                    float* __restrict__ ctt) {
  int bh = blockIdx.x;
  int t = threadIdx.x;
  int u = t >> 2, dg = (t & 3) * 16;
  if (u >= SK_) return;
  float M = -INFINITY;
  for (int s = 0; s < 8; ++s) M = fmaxf(M, PM[(bh * 8 + s) * 64 + u]);
  float wgt[8];
  float den = 0.f;
  for (int s = 0; s < 8; ++s) {
    wgt[s] = __expf(PM[(bh * 8 + s) * 64 + u] - M);
    den += wgt[s] * PL[(bh * 8 + s) * 64 + u];
  }
  float inv = 1.f / den;
  for (int d = dg; d < dg + 16; ++d) {
    float acc = 0.f;
    for (int s = 0; s < 8; ++s) acc += wgt[s] * PO[(((size_t)bh * 8 + s) * 64 + u) * 64 + d];
    ctt[((size_t)bh * SK_ + u) * 64 + d] = acc * inv;
  }
}

// ---------------- V mean: 8-way partial + combine, swizzled -----------------
__global__ __launch_bounds__(256) void vmean_part(const u16* __restrict__ qkv,
                                                  float* __restrict__ part) {
  int g = xswz(blockIdx.x, (B_ * H_ * 8) >> 3);
  int bh = g >> 3, seg = g & 7;
  int h = bh & 7, b = bh >> 3;
  int lane = threadIdx.x & 63, grp = threadIdx.x >> 6;
  int k0 = seg * 190, k1 = k0 + 190;
  float acc = 0.f;
  for (int k = k0 + grp; k < k1; k += 4)
    acc += b2f(qkv[((size_t)b * L_ + k) * 1536 + 1024 + h * 64 + lane]);
  __shared__ float pv[4][64];
  pv[grp][lane] = acc;
  __syncthreads();
  if (threadIdx.x < 64)
    part[g * 64 + threadIdx.x] =
        pv[0][threadIdx.x] + pv[1][threadIdx.x] + pv[2][threadIdx.x] + pv[3][threadIdx.x];
}

__global__ __launch_bounds__(256) void vmean_comb(const float* __restrict__ part,
                                                  float* __restrict__ vmean) {
  int idx = blockIdx.x * 256 + threadIdx.x;
  int bh = idx >> 6, d = idx & 63;
  float s = 0.f;
#pragma unroll
  for (int seg = 0; seg < 8; ++seg) s += part[(bh * 8 + seg) * 64 + d];
  vmean[idx] = s / (float)L_;
}

// ---------------- ctx = broadcast vmean (bf16), then scatter top ------------
__global__ __launch_bounds__(256) void fill_ctx(const float* __restrict__ vmean,
                                                u16* __restrict__ ctxb) {
  int idx = blockIdx.x * 256 + threadIdx.x;
  int d = idx % 64;
  int h = (idx / 64) % H_;
  int b = idx / (L_ * DM_);
  ctxb[idx] = f2b(vmean[(b * H_ + h) * 64 + d]);
}

__global__ __launch_bounds__(256) void scatter_ctx(const float* __restrict__ ctt,
                                                   const int* __restrict__ top,
                                                   u16* __restrict__ ctxb) {
  int idx = blockIdx.x * 256 + threadIdx.x;
  int d = idx % 64;
  int u = (idx / 64) % SK_;
  int bh = idx / (64 * SK_);
  int h = bh % H_, b = bh / H_;
  int l = top[bh * SK_ + u];
  ctxb[((size_t)b * L_ + l) * DM_ + h * 64 + d] = f2b(ctt[idx]);
}

// ---------------- host side --------------------------------------------------
extern "C" void kernel_launch(void* const* d_in, const int* in_sizes, int n_in,
                              void* d_out, int out_size, void* d_ws, size_t ws_size,
                              hipStream_t stream) {
  const float* inflow   = (const float*)d_in[4];
  const float* W_emb_e  = (const float*)d_in[5];
  const float* b_emb_e  = (const float*)d_in[6];
  const float* W_emb_d  = (const float*)d_in[7];
  const float* b_emb_d  = (const float*)d_in[8];
  const float* enc_Wqkv = (const float*)d_in[9];
  const float* enc_bqkv = (const float*)d_in[10];
  const float* enc_Wo   = (const float*)d_in[11];
  const float* enc_bo   = (const float*)d_in[12];
  const float* enc_ln1g = (const float*)d_in[13];
  const float* enc_ln1b = (const float*)d_in[14];
  const float* enc_Wf1  = (const float*)d_in[15];
  const float* enc_bf1  = (const float*)d_in[16];
  const float* enc_Wf2  = (const float*)d_in[17];
  const float* enc_bf2  = (const float*)d_in[18];
  const float* enc_ln2g = (const float*)d_in[19];
  const float* enc_ln2b = (const float*)d_in[20];
  const float* enc_ng   = (const float*)d_in[21];
  const float* enc_nb   = (const float*)d_in[22];
  const float* dec_Wqkv = (const float*)d_in[23];
  const float* dec_bqkv = (const float*)d_in[24];
  const float* dec_Wo_s = (const float*)d_in[25];
  const float* dec_bo_s = (const float*)d_in[26];
  const float* dec_ln1g = (const float*)d_in[27];
  const float* dec_ln1b = (const float*)d_in[28];
  const float* dec_Wq_c = (const float*)d_in[29];
  const float* dec_bq_c = (const float*)d_in[30];
  const float* dec_Wkv  = (const float*)d_in[31];
  const float* dec_bkv  = (const float*)d_in[32];
  const float* dec_Wo_c = (const float*)d_in[33];
  const float* dec_bo_c = (const float*)d_in[34];
  const float* dec_ln2g = (const float*)d_in[35];
  const float* dec_ln2b = (const float*)d_in[36];
  const float* dec_Wf1  = (const float*)d_in[37];
  const float* dec_bf1  = (const float*)d_in[38];
  const float* dec_Wf2  = (const float*)d_in[39];
  const float* dec_bf2  = (const float*)d_in[40];
  const float* dec_ln3g = (const float*)d_in[41];
  const float* dec_ln3b = (const float*)d_in[42];
  const float* W_proj   = (const float*)d_in[43];
  const float* b_proj   = (const float*)d_in[44];
  const float* W1       = (const float*)d_in[45];
  const float* b1       = (const float*)d_in[46];
  const float* W3       = (const float*)d_in[47];
  const float* b3       = (const float*)d_in[48];
  const int*   samp     = (const int*)d_in[49];
  float* out = (float*)d_out;

  float* ws  = (float*)d_ws;
  float* PE  = ws;                       // 778240 f (dead after embeds -> PM/PL)
  float* X   = PE + 778240;              // 72960 f
  float* ACT = X + 72960;                // 3112960 f
  float* REG = ACT + 3112960;            // 6291456 f shared region
  float* MME = REG + 6291456;            // 48640 f (VME8 overlay after topk)
  float* CTT = MME + 48640;              // 81920 f
  float* VME = CTT + 81920;              // 2048 f
  int*   TOP = (int*)(VME + 2048);       // 1280 i
  float* TAIL = VME + 2048 + 1280;
  u16* ENCb = (u16*)TAIL;                       // 6144*512 u16
  u16* DECb = (u16*)(TAIL + 1572864);
  u16* CTXb = (u16*)(TAIL + 2 * 1572864);
  u16* WBF  = (u16*)(TAIL + 3 * 1572864);       // 10485760 u16

  // region overlays (prob phase)
  u16* QKVb = (u16*)REG;                 // [6144][1536]
  u16* FFb  = (u16*)REG;                 // [6144][2048]
  u16* VT   = (u16*)REG + 9437184;       // [32][64][1536] u16
  // region overlays (cross phase)
  u16* QCb  = (u16*)REG;                 // [6144][512]
  u16* Kc   = (u16*)REG + 3145728;       // [6144][512]
  u16* Vc   = (u16*)REG + 6291456;       // [6144][512]; becomes PO-split0 after transpose
  // prob split-K partials overlay CTXb (rebuilt by fill_ctx afterwards)
  float* POp = (float*)CTXb;             // 32*8*64*64 f
  float* PMp = POp + 1048576;
  float* PLp = PMp + 16384;
  // cross partial stats in dead PE region (32*24*2*64 = 98304 each)
  float* PMc = PE;
  float* PLc = PE + 98304;
  float* VME8 = MME;                     // 16384 f (after radix_topk)

  auto GB = [&](const u16* A, const u16* Bt, const float* bias, const float* res,
                float* Cf, u16* Cb, int N, int K, int act) {
    if (N <= 512) {
      dim3 g(N / 128, MP_ / 64);
      gemm_bf16<64><<<g, 256, 0, stream>>>(A, Bt, bias, res, Cf, Cb, N, K, act);
    } else {
      dim3 g(N / 128, MP_ / 128);
      gemm_bf16<128><<<g, 256, 0, stream>>>(A, Bt, bias, res, Cf, Cb, N, K, act);
    }
  };
  auto PROB = [&](const int* sidx) {
    probM<<<B_ * H_ * L_ / 4, 256, 0, stream>>>(QKVb, sidx, MME);
    radix_topk<<<B_ * H_, 256, 0, stream>>>(MME, TOP);
    transpose_v<<<B_ * H_ * 24, 256, 0, stream>>>(QKVb, 1536, 1024, VT);
    flash_attn<1><<<B_ * H_ * 8, 256, 0, stream>>>(QKVb, QKVb, VT, TOP, POp,
                                                   nullptr, nullptr, PMp, PLp);
    combine_prob<<<B_ * H_, 256, 0, stream>>>(POp, PMp, PLp, CTT);
    vmean_part<<<B_ * H_ * 8, 256, 0, stream>>>(QKVb, VME8);
    vmean_comb<<<8, 256, 0, stream>>>(VME8, VME);
    fill_ctx<<<ML_ * DM_ / 256, 256, 0, stream>>>(VME, CTXb);
    scatter_ctx<<<B_ * H_ * SK_ * 64 / 256, 256, 0, stream>>>(CTT, TOP, CTXb);
  };

  pe_kernel<<<(L_ * DM_ + 255) / 256, 256, 0, stream>>>(PE);
  extract_x<<<(ML_ * 12 + 255) / 256, 256, 0, stream>>>(inflow, X);

  // one fused weight-conversion dispatch (LDS tiled transpose)
  {
    CvtArgs a;
    const float* s[15] = {
      enc_Wqkv, enc_Wqkv + 512 * 1536, enc_Wo, enc_Wo + 512 * 512,
      enc_Wf1, enc_Wf1 + 512 * 2048, enc_Wf2, enc_Wf2 + 2048 * 512,
      dec_Wqkv, dec_Wo_s, dec_Wq_c, dec_Wkv, dec_Wo_c, dec_Wf1, dec_Wf2 };
    unsigned cumt[16] = { 0u, 768u, 1536u, 1792u, 2048u, 3072u,
                          4096u, 5120u, 6144u, 6912u, 7168u,
                          7424u, 7936u, 8192u, 9216u, 10240u };
    unsigned lk[15] = { 9, 9, 9, 9, 9, 9, 11, 11, 9, 9, 9, 9, 9, 9, 11 };
    for (int i = 0; i < 15; ++i) { a.src[i] = s[i]; a.lk[i] = lk[i]; }
    for (int i = 0; i < 16; ++i) a.cumt[i] = cumt[i];
    cvt_all<<<10240, 256, 0, stream>>>(a, WBF);
  }
  u16* Wt_qkv_e0 = WBF + 0;
  u16* Wt_qkv_e1 = WBF + 786432;
  u16* Wt_o_e0   = WBF + 1572864;
  u16* Wt_o_e1   = WBF + 1835008;
  u16* Wt_f1_e0  = WBF + 2097152;
  u16* Wt_f1_e1  = WBF + 3145728;
  u16* Wt_f2_e0  = WBF + 4194304;
  u16* Wt_f2_e1  = WBF + 5242880;
  u16* Wt_qkv_d  = WBF + 6291456;
  u16* Wt_o_s    = WBF + 7077888;
  u16* Wt_q_c    = WBF + 7340032;
  u16* Wt_kv_c   = WBF + 7602176;
  u16* Wt_o_c    = WBF + 8126464;
  u16* Wt_f1_d   = WBF + 8388608;
  u16* Wt_f2_d   = WBF + 9437184;

  // ---------------- encoder ----------------
  embed_fused<<<MP_ / 4, 256, 0, stream>>>(X, W_emb_e, b_emb_e, PE, ACT, ENCb);

  const u16* Wqkv_e[2] = {Wt_qkv_e0, Wt_qkv_e1};
  const u16* Wo_e[2]   = {Wt_o_e0, Wt_o_e1};
  const u16* Wf1_e[2]  = {Wt_f1_e0, Wt_f1_e1};
  const u16* Wf2_e[2]  = {Wt_f2_e0, Wt_f2_e1};
  for (int i = 0; i < 2; ++i) {
    GB(ENCb, Wqkv_e[i], enc_bqkv + i * 1536, nullptr, nullptr, QKVb, 1536, 512, 0);
    PROB(samp + (size_t)i * L_ * SK_);
    GB(CTXb, Wo_e[i], enc_bo + i * 512, ACT, ACT, nullptr, 512, 512, 0);
    layernorm_ip<<<ML_ / 4, 256, 0, stream>>>(ACT, enc_ln1g + i * 512, enc_ln1b + i * 512, ENCb);
    GB(ENCb, Wf1_e[i], enc_bf1 + i * 2048, nullptr, nullptr, FFb, 2048, 512, 1);
    GB(FFb, Wf2_e[i], enc_bf2 + i * 512, ACT, ACT, nullptr, 512, 2048, 0);
    layernorm_ip<<<ML_ / 4, 256, 0, stream>>>(ACT, enc_ln2g + i * 512, enc_ln2b + i * 512, ENCb);
  }
  layernorm_ip<<<ML_ / 4, 256, 0, stream>>>(ACT, enc_ng, enc_nb, ENCb);

  // ---------------- decoder ----------------
  embed_fused<<<MP_ / 4, 256, 0, stream>>>(X, W_emb_d, b_emb_d, PE, ACT, DECb);
  GB(DECb, Wt_qkv_d, dec_bqkv, nullptr, nullptr, QKVb, 1536, 512, 0);
  PROB(samp + (size_t)2 * L_ * SK_);
  GB(CTXb, Wt_o_s, dec_bo_s, ACT, ACT, nullptr, 512, 512, 0);
  layernorm_ip<<<ML_ / 4, 256, 0, stream>>>(ACT, dec_ln1g, dec_ln1b, DECb);

  // cross attention: Q, K, V as separate [*,512] GEMMs; V buffer becomes split-0
  GB(DECb, Wt_q_c, dec_bq_c, nullptr, nullptr, QCb, 512, 512, 0);
  GB(ENCb, Wt_kv_c, dec_bkv, nullptr, nullptr, Kc, 512, 512, 0);
  GB(ENCb, Wt_kv_c + 512 * 512, dec_bkv + 512, nullptr, nullptr, Vc, 512, 512, 0);
  transpose_v<<<B_ * H_ * 24, 256, 0, stream>>>(Vc, 512, 0, VT);
  flash_attn<0><<<B_ * H_ * 48, 256, 0, stream>>>(QCb, Kc, VT, nullptr, nullptr,
                                                  Vc, CTXb, PMc, PLc);
  combine_cross<<<ML_ * DM_ / 256, 256, 0, stream>>>(Vc, PMc, PLc, CTXb);
  GB(CTXb, Wt_o_c, dec_bo_c, ACT, ACT, nullptr, 512, 512, 0);
  layernorm_ip<<<ML_ / 4, 256, 0, stream>>>(ACT, dec_ln2g, dec_ln2b, DECb);

  GB(DECb, Wt_f1_d, dec_bf1, nullptr, nullptr, FFb, 2048, 512, 1);
  GB(FFb, Wt_f2_d, dec_bf2, ACT, ACT, nullptr, 512, 2048, 0);
  layernorm_ip<<<ML_ / 4, 256, 0, stream>>>(ACT, dec_ln3g, dec_ln3b, DECb);

  // fused head
  head_fused<<<ML_ / 4, 256, 0, stream>>>(ACT, X, W_proj, b_proj, W1, b1, W3, b3, out);
}

// Round 11
// 888.860 us; speedup vs baseline: 1.1758x; 1.1758x over previous
//
#include <hip/hip_runtime.h>
#include <math.h>

#define B_ 4
#define H_ 8
#define L_ 1520
#define DM_ 512
#define DFF_ 2048
#define SK_ 40
#define ML_ (B_*L_)   /* 6080 rows */
#define MP_ 6144      /* padded rows for MFMA GEMM */
#define LP_ 1536      /* padded key count for V^T */

typedef unsigned short u16;
typedef short s8v __attribute__((ext_vector_type(8)));
typedef float f4 __attribute__((ext_vector_type(4)));

__device__ __forceinline__ u16 f2b(float x) {
  union { float f; unsigned u; } c; c.f = x;
  unsigned r = c.u + 0x7FFFu + ((c.u >> 16) & 1u);
  return (u16)(r >> 16);
}
__device__ __forceinline__ float b2f(u16 h) {
  union { unsigned u; float f; } c; c.u = ((unsigned)h) << 16;
  return c.f;
}
__device__ __forceinline__ float gelu_tanh(float x) {
  float x3 = x * x * x;
  return 0.5f * x * (1.f + tanhf(0.79788456080286536f * (x + 0.044715f * x3)));
}
// XCD-chunked bijective swizzle; requires nwg % 8 == 0 (cpx = nwg/8).
__device__ __forceinline__ int xswz(int bid, int cpx) {
  return (bid & 7) * cpx + (bid >> 3);
}

// ---------------- positional encoding (double precision to match numpy) ----
__global__ __launch_bounds__(256) void pe_kernel(float* __restrict__ pe) {
  int idx = blockIdx.x * 256 + threadIdx.x;
  if (idx >= L_ * DM_) return;
  int pos = idx / DM_, i = idx % DM_;
  double expo = (double)(2 * (i / 2)) / (double)DM_;
  double ang = (double)pos / pow(10000.0, expo);
  pe[idx] = (i & 1) ? (float)cos(ang) : (float)sin(ang);
}

// ---------------- x = inflow[:,2:14].reshape (contiguous slice) -------------
__global__ __launch_bounds__(256) void extract_x(const float* __restrict__ inflow,
                                                 float* __restrict__ X) {
  int idx = blockIdx.x * 256 + threadIdx.x;
  if (idx >= ML_ * 12) return;
  int b = idx / (L_ * 12);
  int rem = idx - b * (L_ * 12);
  X[idx] = inflow[(size_t)b * 14 * L_ + 2 * L_ + rem];
}

// ---------------- fused weight convert+transpose (LDS tiled, coalesced) -----
struct CvtArgs {
  const float* src[15];
  unsigned cumt[16];   // cumulative 32x32-tile counts
  unsigned lk[15];     // log2(K) per segment
};
__global__ __launch_bounds__(256) void cvt_all(CvtArgs a, u16* __restrict__ dst) {
  __shared__ float tl[32][33];
  int bt = blockIdx.x;                 // grid exact: 10240 tiles
  int s = 0;
#pragma unroll
  for (int i = 1; i < 15; ++i) s += (bt >= (int)a.cumt[i]);
  int lt = bt - a.cumt[s];
  unsigned lk = a.lk[s];
  unsigned K = 1u << lk;
  unsigned N = ((a.cumt[s + 1] - a.cumt[s]) << 10) >> lk;
  unsigned tiles_n = N >> 5;
  unsigned k0 = (lt / tiles_n) * 32, n0 = (lt % tiles_n) * 32;
  const float* src = a.src[s];
  int r = threadIdx.x >> 5, c = threadIdx.x & 31;
#pragma unroll
  for (int i = 0; i < 4; ++i)
    tl[r + 8 * i][c] = src[(size_t)(k0 + r + 8 * i) * N + n0 + c];
  __syncthreads();
  u16* d = dst + ((size_t)a.cumt[s] << 10);
#pragma unroll
  for (int i = 0; i < 4; ++i)
    d[(size_t)(n0 + r + 8 * i) * K + k0 + c] = f2b(tl[c][r + 8 * i]);
}

// ---------------- fused embed: ACT = X@W + b + PE ; ACTb = bf16(ACT) --------
__global__ __launch_bounds__(256) void embed_fused(
    const float* __restrict__ X, const float* __restrict__ W,
    const float* __restrict__ bias, const float* __restrict__ PE,
    float* __restrict__ ACT, u16* __restrict__ ACTb) {
  int row = blockIdx.x * 4 + (threadIdx.x >> 6);
  int lane = threadIdx.x & 63;
  int d0 = lane * 8;
  if (row >= ML_) {
    s8v z = {0, 0, 0, 0, 0, 0, 0, 0};
    *(s8v*)(ACTb + (size_t)row * DM_ + d0) = z;
    return;
  }
  int prow = row % L_;
  f4 a0 = *(const f4*)(bias + d0);
  f4 a1 = *(const f4*)(bias + d0 + 4);
  a0 += *(const f4*)(PE + (size_t)prow * DM_ + d0);
  a1 += *(const f4*)(PE + (size_t)prow * DM_ + d0 + 4);
  const float* xr = X + (size_t)row * 12;
#pragma unroll
  for (int t = 0; t < 12; ++t) {
    float xv = xr[t];
    a0 += xv * *(const f4*)(W + (size_t)t * DM_ + d0);
    a1 += xv * *(const f4*)(W + (size_t)t * DM_ + d0 + 4);
  }
  float* dst = ACT + (size_t)row * DM_ + d0;
  *(f4*)dst = a0;
  *(f4*)(dst + 4) = a1;
  u16 ob[8];
#pragma unroll
  for (int i = 0; i < 4; ++i) { ob[i] = f2b(a0[i]); ob[4 + i] = f2b(a1[i]); }
  *(s8v*)(ACTb + (size_t)row * DM_ + d0) = *(s8v*)ob;
}

// ---------------- fused head: out = relu((DEC@Wp+bp+X)@W1+b1)@W3+b3 ---------
__global__ __launch_bounds__(256) void head_fused(
    const float* __restrict__ DEC, const float* __restrict__ X,
    const float* __restrict__ Wp, const float* __restrict__ bp,
    const float* __restrict__ W1, const float* __restrict__ b1,
    const float* __restrict__ W3, const float* __restrict__ b3,
    float* __restrict__ out) {
  int row = blockIdx.x * 4 + (threadIdx.x >> 6);
  int lane = threadIdx.x & 63;
  int d0 = lane * 8;
  const float* dec = DEC + (size_t)row * DM_ + d0;
  f4 v0 = *(const f4*)dec;
  f4 v1 = *(const f4*)(dec + 4);
  float pj[12];
#pragma unroll
  for (int j = 0; j < 12; ++j) pj[j] = 0.f;
#pragma unroll
  for (int i = 0; i < 8; ++i) {
    float dv = (i < 4) ? v0[i] : v1[i - 4];
    const float* wr = Wp + (size_t)(d0 + i) * 12;
#pragma unroll
    for (int j = 0; j < 12; ++j) pj[j] += dv * wr[j];
  }
  for (int off = 32; off; off >>= 1) {
#pragma unroll
    for (int j = 0; j < 12; ++j) pj[j] += __shfl_xor(pj[j], off);
  }
  float o12[12];
#pragma unroll
  for (int j = 0; j < 12; ++j) o12[j] = pj[j] + bp[j] + X[(size_t)row * 12 + j];
  int k0 = lane * 2;
  float h0 = b1[k0], h1 = b1[k0 + 1];
#pragma unroll
  for (int j = 0; j < 12; ++j) {
    h0 += o12[j] * W1[j * 128 + k0];
    h1 += o12[j] * W1[j * 128 + k0 + 1];
  }
  h0 = fmaxf(h0, 0.f);
  h1 = fmaxf(h1, 0.f);
  float op[3];
#pragma unroll
  for (int p = 0; p < 3; ++p)
    op[p] = h0 * W3[k0 * 3 + p] + h1 * W3[(k0 + 1) * 3 + p];
  for (int off = 32; off; off >>= 1) {
#pragma unroll
    for (int p = 0; p < 3; ++p) op[p] += __shfl_xor(op[p], off);
  }
  if (lane == 0) {
#pragma unroll
    for (int p = 0; p < 3; ++p) out[(size_t)row * 3 + p] = op[p] + b3[p];
  }
}

// ---------------- bf16 MFMA GEMM, single-buffered, XCD-swizzled -------------
// (round-9 structure: 2-phase dbuf regressed occupancy — reverted)
template<int BM>
__global__ __launch_bounds__(256) void gemm_bf16(
    const u16* __restrict__ A, const u16* __restrict__ Bt,
    const float* __restrict__ bias, const float* __restrict__ res,
    float* __restrict__ Cf, u16* __restrict__ Cb,
    int N, int K, int act) {
  __shared__ __align__(16) u16 As[BM * 32];
  __shared__ __align__(16) u16 Bs[128 * 32];
  constexpr int MI = BM / 32;
  const int nwg = gridDim.x * gridDim.y;
  const int lin = blockIdx.y * gridDim.x + blockIdx.x;
  const int o = xswz(lin, nwg >> 3);
  const int bxi = o % gridDim.x, byi = o / gridDim.x;
  const int t = threadIdx.x, w = t >> 6, lane = t & 63;
  const int lg = lane >> 4, li = lane & 15;
  const int bm = byi * BM, bn = bxi * 128;
  const int wr = (w >> 1) * (BM / 2), wc = (w & 1) * 64;
  f4 acc[MI][4];
#pragma unroll
  for (int i = 0; i < MI; ++i)
#pragma unroll
    for (int j = 0; j < 4; ++j) acc[i][j] = f4{0.f, 0.f, 0.f, 0.f};
  const int rB = w * 32 + (lane >> 2);
  const int rA = (BM == 128) ? rB : (w * 16 + (lane >> 2));
  const int ps = lane & 3;
  for (int k0 = 0; k0 < K; k0 += 32) {
    if (BM == 128) {
#pragma unroll
      for (int j = 0; j < 2; ++j) {
        int r = rA + j * 16;
        int ls = ps ^ ((r >> 1) & 3);
        __builtin_amdgcn_global_load_lds(
            (const __attribute__((address_space(1))) void*)(A + (size_t)(bm + r) * K + k0 + ls * 8),
            (__attribute__((address_space(3))) void*)(As + (w * 32 + j * 16) * 32),
            16, 0, 0);
      }
    } else {
      int ls = ps ^ ((rA >> 1) & 3);
      __builtin_amdgcn_global_load_lds(
          (const __attribute__((address_space(1))) void*)(A + (size_t)(bm + rA) * K + k0 + ls * 8),
          (__attribute__((address_space(3))) void*)(As + (w * 16) * 32),
          16, 0, 0);
    }
#pragma unroll
    for (int j = 0; j < 2; ++j) {
      int r = rB + j * 16;
      int ls = ps ^ ((r >> 1) & 3);
      __builtin_amdgcn_global_load_lds(
          (const __attribute__((address_space(1))) void*)(Bt + (size_t)(bn + r) * K + k0 + ls * 8),
          (__attribute__((address_space(3))) void*)(Bs + (w * 32 + j * 16) * 32),
          16, 0, 0);
    }
    __syncthreads();
    s8v af[MI], bf[4];
#pragma unroll
    for (int f = 0; f < MI; ++f) {
      int ra = wr + f * 16 + li;
      af[f] = *(const s8v*)(As + ra * 32 + ((lg ^ ((ra >> 1) & 3)) * 8));
    }
#pragma unroll
    for (int f = 0; f < 4; ++f) {
      int rb = wc + f * 16 + li;
      bf[f] = *(const s8v*)(Bs + rb * 32 + ((lg ^ ((rb >> 1) & 3)) * 8));
    }
#pragma unroll
    for (int fi = 0; fi < MI; ++fi)
#pragma unroll
      for (int fj = 0; fj < 4; ++fj)
        acc[fi][fj] = __builtin_amdgcn_mfma_f32_16x16x32_bf16(af[fi], bf[fj], acc[fi][fj], 0, 0, 0);
    __syncthreads();
  }
#pragma unroll
  for (int fi = 0; fi < MI; ++fi)
#pragma unroll
    for (int fj = 0; fj < 4; ++fj)
#pragma unroll
      for (int r = 0; r < 4; ++r) {
        int row = bm + wr + fi * 16 + lg * 4 + r;
        int col = bn + wc + fj * 16 + li;
        float v = acc[fi][fj][r] + bias[col];
        if (res && row < ML_) v += res[(size_t)row * N + col];
        if (act == 1) v = gelu_tanh(v);
        if (Cf && row < ML_) Cf[(size_t)row * N + col] = v;
        if (Cb) Cb[(size_t)row * N + col] = f2b(v);
      }
}

// ---------------- layernorm: wave per row, vectorized -----------------------
__global__ __launch_bounds__(256) void layernorm_ip(float* __restrict__ Xb,
                                                    const float* __restrict__ g,
                                                    const float* __restrict__ bta,
                                                    u16* __restrict__ outb) {
  int row = blockIdx.x * 4 + (threadIdx.x >> 6);
  int lane = threadIdx.x & 63;
  float* x = Xb + (size_t)row * DM_;
  f4 a = *(f4*)(x + lane * 8);
  f4 b = *(f4*)(x + lane * 8 + 4);
  float s = a[0] + a[1] + a[2] + a[3] + b[0] + b[1] + b[2] + b[3];
  for (int off = 32; off; off >>= 1) s += __shfl_xor(s, off);
  float mu = s * (1.f / 512.f);
  float vs = 0.f;
#pragma unroll
  for (int i = 0; i < 4; ++i) { a[i] -= mu; b[i] -= mu; vs += a[i] * a[i] + b[i] * b[i]; }
  for (int off = 32; off; off >>= 1) vs += __shfl_xor(vs, off);
  float rs = rsqrtf(vs * (1.f / 512.f) + 1e-5f);
  f4 g0 = *(const f4*)(g + lane * 8), g1 = *(const f4*)(g + lane * 8 + 4);
  f4 c0 = *(const f4*)(bta + lane * 8), c1 = *(const f4*)(bta + lane * 8 + 4);
  u16 ob[8];
#pragma unroll
  for (int i = 0; i < 4; ++i) {
    float r1 = a[i] * rs * g0[i] + c0[i]; x[lane * 8 + i] = r1;     ob[i] = f2b(r1);
    float r2 = b[i] * rs * g1[i] + c1[i]; x[lane * 8 + 4 + i] = r2; ob[4 + i] = f2b(r2);
  }
  *(s8v*)(outb + (size_t)row * DM_ + lane * 8) = *(s8v*)ob;
}

// ---------------- ProbSparse sparsity measure M (bf16 qkv), swizzled --------
__global__ __launch_bounds__(256) void probM(const u16* __restrict__ qkv,
                                             const int* __restrict__ sidx,
                                             float* __restrict__ Mout) {
  int wid = threadIdx.x / 64, lane = threadIdx.x % 64;
  int o = xswz(blockIdx.x, (B_ * H_ * L_ / 4) >> 3);
  int g = o * 4 + wid;
  int l = g % L_;
  int bh = g / L_;
  int h = bh % H_, b = bh / H_;
  __shared__ float qs[4][64];
  qs[wid][lane] = b2f(qkv[((size_t)b * L_ + l) * 1536 + h * 64 + lane]);
  __syncthreads();
  float dot = 0.f;
  if (lane < SK_) {
    int ks = sidx[l * SK_ + lane];
    const u16* kr = qkv + ((size_t)b * L_ + ks) * 1536 + 512 + h * 64;
#pragma unroll
    for (int j = 0; j < 8; ++j) {
      s8v v = *(const s8v*)(kr + j * 8);
#pragma unroll
      for (int i = 0; i < 8; ++i) dot += qs[wid][j * 8 + i] * b2f((u16)v[i]);
    }
  }
  float vmax = (lane < SK_) ? dot : -INFINITY;
  float vsum = (lane < SK_) ? dot : 0.f;
  for (int off = 32; off; off >>= 1) {
    vmax = fmaxf(vmax, __shfl_xor(vmax, off));
    vsum += __shfl_xor(vsum, off);
  }
  if (lane == 0) Mout[g] = vmax - vsum / (float)L_;
}

// ---------------- radix-select top-40 (matches lax.top_k selection set) -----
__global__ __launch_bounds__(256) void radix_topk(const float* __restrict__ Mv,
                                                  int* __restrict__ top) {
  const int bh = blockIdx.x;
  const int t = threadIdx.x;
  const int base = t * 6;
  unsigned key[6];
#pragma unroll
  for (int i = 0; i < 6; ++i) {
    int ix = base + i;
    unsigned k = 0u;
    if (ix < L_) {
      union { float f; unsigned u; } c; c.f = Mv[(size_t)bh * L_ + ix];
      k = c.u ^ ((c.u & 0x80000000u) ? 0xFFFFFFFFu : 0x80000000u);
    }
    key[i] = k;
  }
  __shared__ int wred[4];
  __shared__ int s_a[256], s_b[256];
  unsigned prefix = 0u;
  for (int b = 31; b >= 0; --b) {
    unsigned cand = prefix | (1u << b);
    int c = 0;
#pragma unroll
    for (int i = 0; i < 6; ++i) c += (key[i] >= cand);
    for (int off = 32; off; off >>= 1) c += __shfl_xor(c, off);
    if ((t & 63) == 0) wred[t >> 6] = c;
    __syncthreads();
    int tot = wred[0] + wred[1] + wred[2] + wred[3];
    if (tot >= SK_) prefix = cand;
    __syncthreads();
  }
  const unsigned T = prefix;
  int gt = 0, tie = 0;
#pragma unroll
  for (int i = 0; i < 6; ++i) { gt += (key[i] > T); tie += (key[i] == T); }
  s_a[t] = gt; s_b[t] = tie;
  __syncthreads();
  for (int off = 1; off < 256; off <<= 1) {
    int va = (t >= off) ? s_a[t - off] : 0;
    int vb = (t >= off) ? s_b[t - off] : 0;
    __syncthreads();
    s_a[t] += va; s_b[t] += vb;
    __syncthreads();
  }
  const int n_strict = s_a[255];
  const int gt_base = s_a[t] - gt;
  const int tie_base = s_b[t] - tie;
  const int need = SK_ - n_strict;
  int lgt = 0, ltie = 0;
#pragma unroll
  for (int i = 0; i < 6; ++i) {
    int ix = base + i;
    if (key[i] > T) {
      top[bh * SK_ + gt_base + lgt] = ix; ++lgt;
    } else if (key[i] == T) {
      int r = tie_base + ltie; ++ltie;
      if (r < need) top[bh * SK_ + n_strict + r] = ix;
    }
  }
}

// ---------------- V^T build: VT[bh][64][LP_] from V columns, swizzled -------
__global__ __launch_bounds__(256) void transpose_v(const u16* __restrict__ src,
                                                   int stride, int voff0,
                                                   u16* __restrict__ VT) {
  int o = xswz(blockIdx.x, (B_ * H_ * 24) >> 3);
  int kt = o % 24, bh = o / 24;
  int h = bh & 7, b = bh >> 3;
  int kb = kt * 64;
  __shared__ u16 tile[64][72];
  int t = threadIdx.x;
#pragma unroll
  for (int rr = 0; rr < 2; ++rr) {
    int slot = rr * 256 + t;
    int key = slot >> 3, d = (slot & 7) * 8;
    int gk = kb + key; if (gk >= L_) gk = L_ - 1;
    s8v v = *(const s8v*)(src + (size_t)(b * L_ + gk) * stride + voff0 + h * 64 + d);
    *(s8v*)(&tile[key][d]) = v;
  }
  __syncthreads();
  int dim = t >> 2, k0 = (t & 3) * 16;
  u16 buf[16];
#pragma unroll
  for (int i = 0; i < 16; ++i) {
    int key = k0 + i;
    buf[i] = (kb + key < L_) ? tile[key][dim] : (u16)0;
  }
  *(s8v*)(VT + ((size_t)bh * 64 + dim) * LP_ + kb + k0) = *(s8v*)buf;
  *(s8v*)(VT + ((size_t)bh * 64 + dim) * LP_ + kb + k0 + 8) = *(s8v*)(buf + 8);
}

// ---------------- LDS-staged swapped-operand MFMA flash attention -----------
template<int MODE>
__global__ __launch_bounds__(256) void flash_attn(
    const u16* __restrict__ Qm, const u16* __restrict__ Kg,
    const u16* __restrict__ VT, const int* __restrict__ top,
    float* __restrict__ POf, u16* POa, u16* POb,
    float* __restrict__ PM, float* __restrict__ PL) {
  constexpr int QSTR = (MODE == 0) ? 512 : 1536;
  constexpr int KSTR = (MODE == 0) ? 512 : 1536;
  constexpr int TILES = (MODE == 0) ? 12 : 3;
  constexpr int NB = (MODE == 0) ? 48 : 8;
  __shared__ __align__(16) u16 Kt[64 * 64];        // [key][slot^(key&7)]
  __shared__ __align__(16) u16 Vt[64 * 64];        // [dim][slot^(dim&7)]
  __shared__ __align__(16) unsigned Xch[4][576];   // per-wave P exchange
  const int o = xswz(blockIdx.x, (B_ * H_ * NB) >> 3);
  int bh, sp, qb;
  if (MODE == 0) {
    bh = o / 48; int rem = o % 48; qb = rem >> 1; sp = rem & 1;
  } else {
    bh = o / 8; sp = o % 8; qb = 0;
  }
  const int h = bh & 7, b = bh >> 3;
  const int qoff = h * 64;
  const int koff = ((MODE == 0) ? 0 : 512) + h * 64;
  const int t = threadIdx.x, w = t >> 6, lane = t & 63;
  const int lg = lane >> 4, li = lane & 15;
  const u16* vtg = VT + (size_t)bh * 64 * LP_;
  unsigned* xw = Xch[w];
  u16* xw16 = (u16*)xw;

  int qrow;
  if (MODE == 0) {
    int q = qb * 64 + w * 16 + li;
    qrow = b * L_ + ((q < L_) ? q : (L_ - 1));
  } else {
    int u = w * 16 + li; if (u >= SK_) u = SK_ - 1;
    qrow = b * L_ + top[bh * SK_ + u];
  }
  s8v qf0 = *(const s8v*)(Qm + (size_t)qrow * QSTR + qoff + lg * 8);
  s8v qf1 = *(const s8v*)(Qm + (size_t)qrow * QSTR + qoff + 32 + lg * 8);

  f4 o4[4];                          // o4[n][r] = O^T[d=n*16+lg*4+r][q=li]
#pragma unroll
  for (int n = 0; n < 4; ++n) o4[n] = f4{0.f, 0.f, 0.f, 0.f};
  float m_run = -INFINITY, l_run = 0.f;   // per-lane (q=li)
  const int kt0 = sp * TILES;
  const int skey = lane >> 3;
  const int sslot = lane & 7;

#pragma unroll 1
  for (int ki = 0; ki < TILES; ++ki) {
    const int kb = (kt0 + ki) * 64;
#pragma unroll
    for (int j = 0; j < 2; ++j) {
      int row = w * 16 + j * 8 + skey;
      int gk = kb + row; if (gk >= L_) gk = L_ - 1;
      int ck = sslot ^ (row & 7);
      __builtin_amdgcn_global_load_lds(
          (const __attribute__((address_space(1))) void*)(Kg + (size_t)(b * L_ + gk) * KSTR + koff + ck * 8),
          (__attribute__((address_space(3))) void*)(Kt + (w * 16 + j * 8) * 64),
          16, 0, 0);
      int cv = sslot ^ (row & 7);
      __builtin_amdgcn_global_load_lds(
          (const __attribute__((address_space(1))) void*)(vtg + (size_t)row * LP_ + kb + cv * 8),
          (__attribute__((address_space(3))) void*)(Vt + (w * 16 + j * 8) * 64),
          16, 0, 0);
    }
    __syncthreads();
    f4 s[4];
#pragma unroll
    for (int c = 0; c < 4; ++c) {
      int key = c * 16 + li;
      s8v kf = *(const s8v*)(Kt + key * 64 + ((lg ^ (key & 7)) * 8));
      s8v kg2 = *(const s8v*)(Kt + key * 64 + (((lg + 4) ^ (key & 7)) * 8));
      f4 z = f4{0.f, 0.f, 0.f, 0.f};
      z = __builtin_amdgcn_mfma_f32_16x16x32_bf16(kf, qf0, z, 0, 0, 0);
      z = __builtin_amdgcn_mfma_f32_16x16x32_bf16(kg2, qf1, z, 0, 0, 0);
      s[c] = z * 0.125f;
    }
    if (kb + 64 > L_) {
#pragma unroll
      for (int c = 0; c < 4; ++c)
#pragma unroll
        for (int r = 0; r < 4; ++r)
          if (kb + c * 16 + lg * 4 + r >= L_) s[c][r] = -INFINITY;
    }
    float tm = -INFINITY;
#pragma unroll
    for (int c = 0; c < 4; ++c)
      tm = fmaxf(tm, fmaxf(fmaxf(s[c][0], s[c][1]), fmaxf(s[c][2], s[c][3])));
    tm = fmaxf(tm, __shfl_xor(tm, 16));
    tm = fmaxf(tm, __shfl_xor(tm, 32));
    float mn = fmaxf(m_run, tm);
    float sc = __expf(m_run - mn);
    float p[4][4];
    float rs = 0.f;
#pragma unroll
    for (int c = 0; c < 4; ++c)
#pragma unroll
      for (int r = 0; r < 4; ++r) { p[c][r] = __expf(s[c][r] - mn); rs += p[c][r]; }
    rs += __shfl_xor(rs, 16);
    rs += __shfl_xor(rs, 32);
    l_run = l_run * sc + rs;
    m_run = mn;
#pragma unroll
    for (int n = 0; n < 4; ++n) o4[n] *= sc;
#pragma unroll
    for (int c = 0; c < 4; ++c)
#pragma unroll
      for (int rp = 0; rp < 2; ++rp) {
        unsigned v = (unsigned)f2b(p[c][2 * rp]) | ((unsigned)f2b(p[c][2 * rp + 1]) << 16);
        xw[li * 36 + c * 8 + lg * 2 + rp] = v;
      }
    s8v pb0 = *(const s8v*)(xw + li * 36 + lg * 4);
    s8v pb1 = *(const s8v*)(xw + li * 36 + 16 + lg * 4);
#pragma unroll
    for (int n = 0; n < 4; ++n) {
      int dim = n * 16 + li;
      s8v vb0 = *(const s8v*)(Vt + dim * 64 + ((lg ^ (dim & 7)) * 8));
      o4[n] = __builtin_amdgcn_mfma_f32_16x16x32_bf16(vb0, pb0, o4[n], 0, 0, 0);
    }
#pragma unroll
    for (int n = 0; n < 4; ++n) {
      int dim = n * 16 + li;
      s8v vb1 = *(const s8v*)(Vt + dim * 64 + (((lg + 4) ^ (dim & 7)) * 8));
      o4[n] = __builtin_amdgcn_mfma_f32_16x16x32_bf16(vb1, pb1, o4[n], 0, 0, 0);
    }
    __syncthreads();
  }

  if (MODE == 0) {
#pragma unroll
    for (int n = 0; n < 4; ++n)
#pragma unroll
      for (int r = 0; r < 4; ++r)
        xw16[li * 72 + n * 16 + lg * 4 + r] = f2b(o4[n][r]);
    u16* PO = sp ? POb : POa;
    const int pid = (bh * 24 + qb) * 2 + sp;
    int q_local = lane >> 2, d0 = (lane & 3) * 16;
    int q = qb * 64 + w * 16 + q_local;
    s8v v0 = *(const s8v*)(xw16 + q_local * 72 + d0);
    s8v v1 = *(const s8v*)(xw16 + q_local * 72 + d0 + 8);
    if (q < L_) {
      u16* dst = PO + ((size_t)(b * L_ + q)) * DM_ + qoff + d0;
      *(s8v*)dst = v0;
      *(s8v*)(dst + 8) = v1;
    }
    if (lg == 0) {
      PM[pid * 64 + w * 16 + li] = m_run;
      PL[pid * 64 + w * 16 + li] = l_run;
    }
  } else {
    int base = (bh * 8 + sp) * 64 + w * 16 + li;
#pragma unroll
    for (int n = 0; n < 4; ++n)
#pragma unroll
      for (int r = 0; r < 4; ++r)
        POf[(size_t)base * 64 + n * 16 + lg * 4 + r] = o4[n][r];
    if (lg == 0) {
      PM[base] = m_run;
      PL[base] = l_run;
    }
  }
}

// ---------------- combine 2-way cross partials (POb == ctxb, in place) ------
__global__ __launch_bounds__(256) void combine_cross(const u16* __restrict__ PO0,
                                                     const float* __restrict__ PM,
                                                     const float* __restrict__ PL,
                                                     u16* ctxb) {
  int idx = blockIdx.x * 256 + threadIdx.x;
  int row = idx >> 9, col = idx & 511;
  int b = row / L_, q = row - b * L_;
  int h = col >> 6;
  int bh = b * 8 + h, qbk = q >> 6, qi = q & 63;
  int p0 = ((bh * 24 + qbk) * 2) * 64 + qi;
  float m0 = PM[p0], m1 = PM[p0 + 64];
  float l0 = PL[p0], l1 = PL[p0 + 64];
  float M = fmaxf(m0, m1);
  float w0 = __expf(m0 - M), w1 = __expf(m1 - M);
  float inv = 1.f / (w0 * l0 + w1 * l1);
  float o0 = b2f(PO0[idx]);
  float o1 = b2f(ctxb[idx]);
  ctxb[idx] = f2b((w0 * o0 + w1 * o1) * inv);
}

// ---------------- combine split-K partials -> ctt ----------------------------
__global__ __launch_bounds__(256) void combine_prob(const float* __restrict__ PO,
                                                    const float* __restrict__ PM,
                                                    const float* __restrict__ PL,
                                                    float* __restrict__ ctt) {
  int bh = blockIdx.x;
  int t = threadIdx.x;
  int u = t >> 2, dg = (t & 3) * 16;
  if (u >= SK_) return;
  float M = -INFINITY;
  for (int s = 0; s < 8; ++s) M = fmaxf(M, PM[(bh * 8 + s) * 64 + u]);
  float wgt[8];
  float den = 0.f;
  for (int s = 0; s < 8; ++s) {
    wgt[s] = __expf(PM[(bh * 8 + s) * 64 + u] - M);
    den += wgt[s] * PL[(bh * 8 + s) * 64 + u];
  }
  float inv = 1.f / den;
  for (int d = dg; d < dg + 16; ++d) {
    float acc = 0.f;
    for (int s = 0; s < 8; ++s) acc += wgt[s] * PO[(((size_t)bh * 8 + s) * 64 + u) * 64 + d];
    ctt[((size_t)bh * SK_ + u) * 64 + d] = acc * inv;
  }
}

// ---------------- V mean: 8-way partial + combine, swizzled -----------------
__global__ __launch_bounds__(256) void vmean_part(const u16* __restrict__ qkv,
                                                  float* __restrict__ part) {
  int g = xswz(blockIdx.x, (B_ * H_ * 8) >> 3);
  int bh = g >> 3, seg = g & 7;
  int h = bh & 7, b = bh >> 3;
  int lane = threadIdx.x & 63, grp = threadIdx.x >> 6;
  int k0 = seg * 190, k1 = k0 + 190;
  float acc = 0.f;
  for (int k = k0 + grp; k < k1; k += 4)
    acc += b2f(qkv[((size_t)b * L_ + k) * 1536 + 1024 + h * 64 + lane]);
  __shared__ float pv[4][64];
  pv[grp][lane] = acc;
  __syncthreads();
  if (threadIdx.x < 64)
    part[g * 64 + threadIdx.x] =
        pv[0][threadIdx.x] + pv[1][threadIdx.x] + pv[2][threadIdx.x] + pv[3][threadIdx.x];
}

__global__ __launch_bounds__(256) void vmean_comb(const float* __restrict__ part,
                                                  float* __restrict__ vmean) {
  int idx = blockIdx.x * 256 + threadIdx.x;
  int bh = idx >> 6, d = idx & 63;
  float s = 0.f;
#pragma unroll
  for (int seg = 0; seg < 8; ++seg) s += part[(bh * 8 + seg) * 64 + d];
  vmean[idx] = s / (float)L_;
}

// ---------------- ctx = broadcast vmean (bf16), then scatter top ------------
__global__ __launch_bounds__(256) void fill_ctx(const float* __restrict__ vmean,
                                                u16* __restrict__ ctxb) {
  int idx = blockIdx.x * 256 + threadIdx.x;
  int d = idx % 64;
  int h = (idx / 64) % H_;
  int b = idx / (L_ * DM_);
  ctxb[idx] = f2b(vmean[(b * H_ + h) * 64 + d]);
}

__global__ __launch_bounds__(256) void scatter_ctx(const float* __restrict__ ctt,
                                                   const int* __restrict__ top,
                                                   u16* __restrict__ ctxb) {
  int idx = blockIdx.x * 256 + threadIdx.x;
  int d = idx % 64;
  int u = (idx / 64) % SK_;
  int bh = idx / (64 * SK_);
  int h = bh % H_, b = bh / H_;
  int l = top[bh * SK_ + u];
  ctxb[((size_t)b * L_ + l) * DM_ + h * 64 + d] = f2b(ctt[idx]);
}

// ---------------- host side --------------------------------------------------
extern "C" void kernel_launch(void* const* d_in, const int* in_sizes, int n_in,
                              void* d_out, int out_size, void* d_ws, size_t ws_size,
                              hipStream_t stream) {
  const float* inflow   = (const float*)d_in[4];
  const float* W_emb_e  = (const float*)d_in[5];
  const float* b_emb_e  = (const float*)d_in[6];
  const float* W_emb_d  = (const float*)d_in[7];
  const float* b_emb_d  = (const float*)d_in[8];
  const float* enc_Wqkv = (const float*)d_in[9];
  const float* enc_bqkv = (const float*)d_in[10];
  const float* enc_Wo   = (const float*)d_in[11];
  const float* enc_bo   = (const float*)d_in[12];
  const float* enc_ln1g = (const float*)d_in[13];
  const float* enc_ln1b = (const float*)d_in[14];
  const float* enc_Wf1  = (const float*)d_in[15];
  const float* enc_bf1  = (const float*)d_in[16];
  const float* enc_Wf2  = (const float*)d_in[17];
  const float* enc_bf2  = (const float*)d_in[18];
  const float* enc_ln2g = (const float*)d_in[19];
  const float* enc_ln2b = (const float*)d_in[20];
  const float* enc_ng   = (const float*)d_in[21];
  const float* enc_nb   = (const float*)d_in[22];
  const float* dec_Wqkv = (const float*)d_in[23];
  const float* dec_bqkv = (const float*)d_in[24];
  const float* dec_Wo_s = (const float*)d_in[25];
  const float* dec_bo_s = (const float*)d_in[26];
  const float* dec_ln1g = (const float*)d_in[27];
  const float* dec_ln1b = (const float*)d_in[28];
  const float* dec_Wq_c = (const float*)d_in[29];
  const float* dec_bq_c = (const float*)d_in[30];
  const float* dec_Wkv  = (const float*)d_in[31];
  const float* dec_bkv  = (const float*)d_in[32];
  const float* dec_Wo_c = (const float*)d_in[33];
  const float* dec_bo_c = (const float*)d_in[34];
  const float* dec_ln2g = (const float*)d_in[35];
  const float* dec_ln2b = (const float*)d_in[36];
  const float* dec_Wf1  = (const float*)d_in[37];
  const float* dec_bf1  = (const float*)d_in[38];
  const float* dec_Wf2  = (const float*)d_in[39];
  const float* dec_bf2  = (const float*)d_in[40];
  const float* dec_ln3g = (const float*)d_in[41];
  const float* dec_ln3b = (const float*)d_in[42];
  const float* W_proj   = (const float*)d_in[43];
  const float* b_proj   = (const float*)d_in[44];
  const float* W1       = (const float*)d_in[45];
  const float* b1       = (const float*)d_in[46];
  const float* W3       = (const float*)d_in[47];
  const float* b3       = (const float*)d_in[48];
  const int*   samp     = (const int*)d_in[49];
  float* out = (float*)d_out;

  float* ws  = (float*)d_ws;
  float* PE  = ws;                       // 778240 f (dead after embeds -> PM/PL)
  float* X   = PE + 778240;              // 72960 f
  float* ACT = X + 72960;                // 3112960 f
  float* REG = ACT + 3112960;            // 6291456 f shared region
  float* MME = REG + 6291456;            // 48640 f (VME8 overlay after topk)
  float* CTT = MME + 48640;              // 81920 f
  float* VME = CTT + 81920;              // 2048 f
  int*   TOP = (int*)(VME + 2048);       // 1280 i
  float* TAIL = VME + 2048 + 1280;
  u16* ENCb = (u16*)TAIL;                       // 6144*512 u16
  u16* DECb = (u16*)(TAIL + 1572864);
  u16* CTXb = (u16*)(TAIL + 2 * 1572864);
  u16* WBF  = (u16*)(TAIL + 3 * 1572864);       // 10485760 u16

  // region overlays (prob phase)
  u16* QKVb = (u16*)REG;                 // [6144][1536]
  u16* FFb  = (u16*)REG;                 // [6144][2048]
  u16* VT   = (u16*)REG + 9437184;       // [32][64][1536] u16
  // region overlays (cross phase)
  u16* QCb  = (u16*)REG;                 // [6144][512]
  u16* Kc   = (u16*)REG + 3145728;       // [6144][512]
  u16* Vc   = (u16*)REG + 6291456;       // [6144][512]; becomes PO-split0 after transpose
  // prob split-K partials overlay CTXb (rebuilt by fill_ctx afterwards)
  float* POp = (float*)CTXb;             // 32*8*64*64 f
  float* PMp = POp + 1048576;
  float* PLp = PMp + 16384;
  // cross partial stats in dead PE region (32*24*2*64 = 98304 each)
  float* PMc = PE;
  float* PLc = PE + 98304;
  float* VME8 = MME;                     // 16384 f (after radix_topk)

  auto GB = [&](const u16* A, const u16* Bt, const float* bias, const float* res,
                float* Cf, u16* Cb, int N, int K, int act) {
    if (N <= 512) {
      dim3 g(N / 128, MP_ / 64);
      gemm_bf16<64><<<g, 256, 0, stream>>>(A, Bt, bias, res, Cf, Cb, N, K, act);
    } else {
      dim3 g(N / 128, MP_ / 128);
      gemm_bf16<128><<<g, 256, 0, stream>>>(A, Bt, bias, res, Cf, Cb, N, K, act);
    }
  };
  auto PROB = [&](const int* sidx) {
    probM<<<B_ * H_ * L_ / 4, 256, 0, stream>>>(QKVb, sidx, MME);
    radix_topk<<<B_ * H_, 256, 0, stream>>>(MME, TOP);
    transpose_v<<<B_ * H_ * 24, 256, 0, stream>>>(QKVb, 1536, 1024, VT);
    flash_attn<1><<<B_ * H_ * 8, 256, 0, stream>>>(QKVb, QKVb, VT, TOP, POp,
                                                   nullptr, nullptr, PMp, PLp);
    combine_prob<<<B_ * H_, 256, 0, stream>>>(POp, PMp, PLp, CTT);
    vmean_part<<<B_ * H_ * 8, 256, 0, stream>>>(QKVb, VME8);
    vmean_comb<<<8, 256, 0, stream>>>(VME8, VME);
    fill_ctx<<<ML_ * DM_ / 256, 256, 0, stream>>>(VME, CTXb);
    scatter_ctx<<<B_ * H_ * SK_ * 64 / 256, 256, 0, stream>>>(CTT, TOP, CTXb);
  };

  pe_kernel<<<(L_ * DM_ + 255) / 256, 256, 0, stream>>>(PE);
  extract_x<<<(ML_ * 12 + 255) / 256, 256, 0, stream>>>(inflow, X);

  // one fused weight-conversion dispatch (LDS tiled transpose)
  {
    CvtArgs a;
    const float* s[15] = {
      enc_Wqkv, enc_Wqkv + 512 * 1536, enc_Wo, enc_Wo + 512 * 512,
      enc_Wf1, enc_Wf1 + 512 * 2048, enc_Wf2, enc_Wf2 + 2048 * 512,
      dec_Wqkv, dec_Wo_s, dec_Wq_c, dec_Wkv, dec_Wo_c, dec_Wf1, dec_Wf2 };
    unsigned cumt[16] = { 0u, 768u, 1536u, 1792u, 2048u, 3072u,
                          4096u, 5120u, 6144u, 6912u, 7168u,
                          7424u, 7936u, 8192u, 9216u, 10240u };
    unsigned lk[15] = { 9, 9, 9, 9, 9, 9, 11, 11, 9, 9, 9, 9, 9, 9, 11 };
    for (int i = 0; i < 15; ++i) { a.src[i] = s[i]; a.lk[i] = lk[i]; }
    for (int i = 0; i < 16; ++i) a.cumt[i] = cumt[i];
    cvt_all<<<10240, 256, 0, stream>>>(a, WBF);
  }
  u16* Wt_qkv_e0 = WBF + 0;
  u16* Wt_qkv_e1 = WBF + 786432;
  u16* Wt_o_e0   = WBF + 1572864;
  u16* Wt_o_e1   = WBF + 1835008;
  u16* Wt_f1_e0  = WBF + 2097152;
  u16* Wt_f1_e1  = WBF + 3145728;
  u16* Wt_f2_e0  = WBF + 4194304;
  u16* Wt_f2_e1  = WBF + 5242880;
  u16* Wt_qkv_d  = WBF + 6291456;
  u16* Wt_o_s    = WBF + 7077888;
  u16* Wt_q_c    = WBF + 7340032;
  u16* Wt_kv_c   = WBF + 7602176;
  u16* Wt_o_c    = WBF + 8126464;
  u16* Wt_f1_d   = WBF + 8388608;
  u16* Wt_f2_d   = WBF + 9437184;

  // ---------------- encoder ----------------
  embed_fused<<<MP_ / 4, 256, 0, stream>>>(X, W_emb_e, b_emb_e, PE, ACT, ENCb);

  const u16* Wqkv_e[2] = {Wt_qkv_e0, Wt_qkv_e1};
  const u16* Wo_e[2]   = {Wt_o_e0, Wt_o_e1};
  const u16* Wf1_e[2]  = {Wt_f1_e0, Wt_f1_e1};
  const u16* Wf2_e[2]  = {Wt_f2_e0, Wt_f2_e1};
  for (int i = 0; i < 2; ++i) {
    GB(ENCb, Wqkv_e[i], enc_bqkv + i * 1536, nullptr, nullptr, QKVb, 1536, 512, 0);
    PROB(samp + (size_t)i * L_ * SK_);
    GB(CTXb, Wo_e[i], enc_bo + i * 512, ACT, ACT, nullptr, 512, 512, 0);
    layernorm_ip<<<ML_ / 4, 256, 0, stream>>>(ACT, enc_ln1g + i * 512, enc_ln1b + i * 512, ENCb);
    GB(ENCb, Wf1_e[i], enc_bf1 + i * 2048, nullptr, nullptr, FFb, 2048, 512, 1);
    GB(FFb, Wf2_e[i], enc_bf2 + i * 512, ACT, ACT, nullptr, 512, 2048, 0);
    layernorm_ip<<<ML_ / 4, 256, 0, stream>>>(ACT, enc_ln2g + i * 512, enc_ln2b + i * 512, ENCb);
  }
  layernorm_ip<<<ML_ / 4, 256, 0, stream>>>(ACT, enc_ng, enc_nb, ENCb);

  // ---------------- decoder ----------------
  embed_fused<<<MP_ / 4, 256, 0, stream>>>(X, W_emb_d, b_emb_d, PE, ACT, DECb);
  GB(DECb, Wt_qkv_d, dec_bqkv, nullptr, nullptr, QKVb, 1536, 512, 0);
  PROB(samp + (size_t)2 * L_ * SK_);
  GB(CTXb, Wt_o_s, dec_bo_s, ACT, ACT, nullptr, 512, 512, 0);
  layernorm_ip<<<ML_ / 4, 256, 0, stream>>>(ACT, dec_ln1g, dec_ln1b, DECb);

  // cross attention: Q, K, V as separate [*,512] GEMMs; V buffer becomes split-0
  GB(DECb, Wt_q_c, dec_bq_c, nullptr, nullptr, QCb, 512, 512, 0);
  GB(ENCb, Wt_kv_c, dec_bkv, nullptr, nullptr, Kc, 512, 512, 0);
  GB(ENCb, Wt_kv_c + 512 * 512, dec_bkv + 512, nullptr, nullptr, Vc, 512, 512, 0);
  transpose_v<<<B_ * H_ * 24, 256, 0, stream>>>(Vc, 512, 0, VT);
  flash_attn<0><<<B_ * H_ * 48, 256, 0, stream>>>(QCb, Kc, VT, nullptr, nullptr,
                                                  Vc, CTXb, PMc, PLc);
  combine_cross<<<ML_ * DM_ / 256, 256, 0, stream>>>(Vc, PMc, PLc, CTXb);
  GB(CTXb, Wt_o_c, dec_bo_c, ACT, ACT, nullptr, 512, 512, 0);
  layernorm_ip<<<ML_ / 4, 256, 0, stream>>>(ACT, dec_ln2g, dec_ln2b, DECb);

  GB(DECb, Wt_f1_d, dec_bf1, nullptr, nullptr, FFb, 2048, 512, 1);
  GB(FFb, Wt_f2_d, dec_bf2, ACT, ACT, nullptr, 512, 2048, 0);
  layernorm_ip<<<ML_ / 4, 256, 0, stream>>>(ACT, dec_ln3g, dec_ln3b, DECb);

  // fused head
  head_fused<<<ML_ / 4, 256, 0, stream>>>(ACT, X, W_proj, b_proj, W1, b1, W3, b3, out);
}

// Round 12
// 885.706 us; speedup vs baseline: 1.1800x; 1.0036x over previous
//
#include <hip/hip_runtime.h>
#include <math.h>

#define B_ 4
#define H_ 8
#define L_ 1520
#define DM_ 512
#define DFF_ 2048
#define SK_ 40
#define ML_ (B_*L_)   /* 6080 rows */
#define MP_ 6144      /* padded rows for MFMA GEMM */
#define LP_ 1536      /* padded key count for V^T */

typedef unsigned short u16;
typedef short s8v __attribute__((ext_vector_type(8)));
typedef float f4 __attribute__((ext_vector_type(4)));

__device__ __forceinline__ u16 f2b(float x) {
  union { float f; unsigned u; } c; c.f = x;
  unsigned r = c.u + 0x7FFFu + ((c.u >> 16) & 1u);
  return (u16)(r >> 16);
}
__device__ __forceinline__ float b2f(u16 h) {
  union { unsigned u; float f; } c; c.u = ((unsigned)h) << 16;
  return c.f;
}
__device__ __forceinline__ float gelu_tanh(float x) {
  float x3 = x * x * x;
  return 0.5f * x * (1.f + tanhf(0.79788456080286536f * (x + 0.044715f * x3)));
}
// XCD-chunked bijective swizzle; requires nwg % 8 == 0 (cpx = nwg/8).
__device__ __forceinline__ int xswz(int bid, int cpx) {
  return (bid & 7) * cpx + (bid >> 3);
}

// ---------------- positional encoding (double precision to match numpy) ----
__global__ __launch_bounds__(256) void pe_kernel(float* __restrict__ pe) {
  int idx = blockIdx.x * 256 + threadIdx.x;
  if (idx >= L_ * DM_) return;
  int pos = idx / DM_, i = idx % DM_;
  double expo = (double)(2 * (i / 2)) / (double)DM_;
  double ang = (double)pos / pow(10000.0, expo);
  pe[idx] = (i & 1) ? (float)cos(ang) : (float)sin(ang);
}

// ---------------- x = inflow[:,2:14].reshape (contiguous slice) -------------
__global__ __launch_bounds__(256) void extract_x(const float* __restrict__ inflow,
                                                 float* __restrict__ X) {
  int idx = blockIdx.x * 256 + threadIdx.x;
  if (idx >= ML_ * 12) return;
  int b = idx / (L_ * 12);
  int rem = idx - b * (L_ * 12);
  X[idx] = inflow[(size_t)b * 14 * L_ + 2 * L_ + rem];
}

// ---------------- fused weight convert+transpose (LDS tiled, coalesced) -----
struct CvtArgs {
  const float* src[15];
  unsigned cumt[16];   // cumulative 32x32-tile counts
  unsigned lk[15];     // log2(K) per segment
};
__global__ __launch_bounds__(256) void cvt_all(CvtArgs a, u16* __restrict__ dst) {
  __shared__ float tl[32][33];
  int bt = blockIdx.x;                 // grid exact: 10240 tiles
  int s = 0;
#pragma unroll
  for (int i = 1; i < 15; ++i) s += (bt >= (int)a.cumt[i]);
  int lt = bt - a.cumt[s];
  unsigned lk = a.lk[s];
  unsigned K = 1u << lk;
  unsigned N = ((a.cumt[s + 1] - a.cumt[s]) << 10) >> lk;
  unsigned tiles_n = N >> 5;
  unsigned k0 = (lt / tiles_n) * 32, n0 = (lt % tiles_n) * 32;
  const float* src = a.src[s];
  int r = threadIdx.x >> 5, c = threadIdx.x & 31;
#pragma unroll
  for (int i = 0; i < 4; ++i)
    tl[r + 8 * i][c] = src[(size_t)(k0 + r + 8 * i) * N + n0 + c];
  __syncthreads();
  u16* d = dst + ((size_t)a.cumt[s] << 10);
#pragma unroll
  for (int i = 0; i < 4; ++i)
    d[(size_t)(n0 + r + 8 * i) * K + k0 + c] = f2b(tl[c][r + 8 * i]);
}

// ---------------- fused embed: ACT = X@W + b + PE ; ACTb = bf16(ACT) --------
__global__ __launch_bounds__(256) void embed_fused(
    const float* __restrict__ X, const float* __restrict__ W,
    const float* __restrict__ bias, const float* __restrict__ PE,
    float* __restrict__ ACT, u16* __restrict__ ACTb) {
  int row = blockIdx.x * 4 + (threadIdx.x >> 6);
  int lane = threadIdx.x & 63;
  int d0 = lane * 8;
  if (row >= ML_) {
    s8v z = {0, 0, 0, 0, 0, 0, 0, 0};
    *(s8v*)(ACTb + (size_t)row * DM_ + d0) = z;
    return;
  }
  int prow = row % L_;
  f4 a0 = *(const f4*)(bias + d0);
  f4 a1 = *(const f4*)(bias + d0 + 4);
  a0 += *(const f4*)(PE + (size_t)prow * DM_ + d0);
  a1 += *(const f4*)(PE + (size_t)prow * DM_ + d0 + 4);
  const float* xr = X + (size_t)row * 12;
#pragma unroll
  for (int t = 0; t < 12; ++t) {
    float xv = xr[t];
    a0 += xv * *(const f4*)(W + (size_t)t * DM_ + d0);
    a1 += xv * *(const f4*)(W + (size_t)t * DM_ + d0 + 4);
  }
  float* dst = ACT + (size_t)row * DM_ + d0;
  *(f4*)dst = a0;
  *(f4*)(dst + 4) = a1;
  u16 ob[8];
#pragma unroll
  for (int i = 0; i < 4; ++i) { ob[i] = f2b(a0[i]); ob[4 + i] = f2b(a1[i]); }
  *(s8v*)(ACTb + (size_t)row * DM_ + d0) = *(s8v*)ob;
}

// ---------------- fused head: out = relu((DEC@Wp+bp+X)@W1+b1)@W3+b3 ---------
__global__ __launch_bounds__(256) void head_fused(
    const float* __restrict__ DEC, const float* __restrict__ X,
    const float* __restrict__ Wp, const float* __restrict__ bp,
    const float* __restrict__ W1, const float* __restrict__ b1,
    const float* __restrict__ W3, const float* __restrict__ b3,
    float* __restrict__ out) {
  int row = blockIdx.x * 4 + (threadIdx.x >> 6);
  int lane = threadIdx.x & 63;
  int d0 = lane * 8;
  const float* dec = DEC + (size_t)row * DM_ + d0;
  f4 v0 = *(const f4*)dec;
  f4 v1 = *(const f4*)(dec + 4);
  float pj[12];
#pragma unroll
  for (int j = 0; j < 12; ++j) pj[j] = 0.f;
#pragma unroll
  for (int i = 0; i < 8; ++i) {
    float dv = (i < 4) ? v0[i] : v1[i - 4];
    const float* wr = Wp + (size_t)(d0 + i) * 12;
#pragma unroll
    for (int j = 0; j < 12; ++j) pj[j] += dv * wr[j];
  }
  for (int off = 32; off; off >>= 1) {
#pragma unroll
    for (int j = 0; j < 12; ++j) pj[j] += __shfl_xor(pj[j], off);
  }
  float o12[12];
#pragma unroll
  for (int j = 0; j < 12; ++j) o12[j] = pj[j] + bp[j] + X[(size_t)row * 12 + j];
  int k0 = lane * 2;
  float h0 = b1[k0], h1 = b1[k0 + 1];
#pragma unroll
  for (int j = 0; j < 12; ++j) {
    h0 += o12[j] * W1[j * 128 + k0];
    h1 += o12[j] * W1[j * 128 + k0 + 1];
  }
  h0 = fmaxf(h0, 0.f);
  h1 = fmaxf(h1, 0.f);
  float op[3];
#pragma unroll
  for (int p = 0; p < 3; ++p)
    op[p] = h0 * W3[k0 * 3 + p] + h1 * W3[(k0 + 1) * 3 + p];
  for (int off = 32; off; off >>= 1) {
#pragma unroll
    for (int p = 0; p < 3; ++p) op[p] += __shfl_xor(op[p], off);
  }
  if (lane == 0) {
#pragma unroll
    for (int p = 0; p < 3; ++p) out[(size_t)row * 3 + p] = op[p] + b3[p];
  }
}

// ---------------- bf16 MFMA GEMM, single-buffered, XCD-swizzled -------------
// (round-9 structure: 2-phase dbuf regressed occupancy — reverted)
template<int BM>
__global__ __launch_bounds__(256) void gemm_bf16(
    const u16* __restrict__ A, const u16* __restrict__ Bt,
    const float* __restrict__ bias, const float* __restrict__ res,
    float* __restrict__ Cf, u16* __restrict__ Cb,
    int N, int K, int act) {
  __shared__ __align__(16) u16 As[BM * 32];
  __shared__ __align__(16) u16 Bs[128 * 32];
  constexpr int MI = BM / 32;
  const int nwg = gridDim.x * gridDim.y;
  const int lin = blockIdx.y * gridDim.x + blockIdx.x;
  const int o = xswz(lin, nwg >> 3);
  const int bxi = o % gridDim.x, byi = o / gridDim.x;
  const int t = threadIdx.x, w = t >> 6, lane = t & 63;
  const int lg = lane >> 4, li = lane & 15;
  const int bm = byi * BM, bn = bxi * 128;
  const int wr = (w >> 1) * (BM / 2), wc = (w & 1) * 64;
  f4 acc[MI][4];
#pragma unroll
  for (int i = 0; i < MI; ++i)
#pragma unroll
    for (int j = 0; j < 4; ++j) acc[i][j] = f4{0.f, 0.f, 0.f, 0.f};
  const int rB = w * 32 + (lane >> 2);
  const int rA = (BM == 128) ? rB : (w * 16 + (lane >> 2));
  const int ps = lane & 3;
  for (int k0 = 0; k0 < K; k0 += 32) {
    if (BM == 128) {
#pragma unroll
      for (int j = 0; j < 2; ++j) {
        int r = rA + j * 16;
        int ls = ps ^ ((r >> 1) & 3);
        __builtin_amdgcn_global_load_lds(
            (const __attribute__((address_space(1))) void*)(A + (size_t)(bm + r) * K + k0 + ls * 8),
            (__attribute__((address_space(3))) void*)(As + (w * 32 + j * 16) * 32),
            16, 0, 0);
      }
    } else {
      int ls = ps ^ ((rA >> 1) & 3);
      __builtin_amdgcn_global_load_lds(
          (const __attribute__((address_space(1))) void*)(A + (size_t)(bm + rA) * K + k0 + ls * 8),
          (__attribute__((address_space(3))) void*)(As + (w * 16) * 32),
          16, 0, 0);
    }
#pragma unroll
    for (int j = 0; j < 2; ++j) {
      int r = rB + j * 16;
      int ls = ps ^ ((r >> 1) & 3);
      __builtin_amdgcn_global_load_lds(
          (const __attribute__((address_space(1))) void*)(Bt + (size_t)(bn + r) * K + k0 + ls * 8),
          (__attribute__((address_space(3))) void*)(Bs + (w * 32 + j * 16) * 32),
          16, 0, 0);
    }
    __syncthreads();
    s8v af[MI], bf[4];
#pragma unroll
    for (int f = 0; f < MI; ++f) {
      int ra = wr + f * 16 + li;
      af[f] = *(const s8v*)(As + ra * 32 + ((lg ^ ((ra >> 1) & 3)) * 8));
    }
#pragma unroll
    for (int f = 0; f < 4; ++f) {
      int rb = wc + f * 16 + li;
      bf[f] = *(const s8v*)(Bs + rb * 32 + ((lg ^ ((rb >> 1) & 3)) * 8));
    }
#pragma unroll
    for (int fi = 0; fi < MI; ++fi)
#pragma unroll
      for (int fj = 0; fj < 4; ++fj)
        acc[fi][fj] = __builtin_amdgcn_mfma_f32_16x16x32_bf16(af[fi], bf[fj], acc[fi][fj], 0, 0, 0);
    __syncthreads();
  }
#pragma unroll
  for (int fi = 0; fi < MI; ++fi)
#pragma unroll
    for (int fj = 0; fj < 4; ++fj)
#pragma unroll
      for (int r = 0; r < 4; ++r) {
        int row = bm + wr + fi * 16 + lg * 4 + r;
        int col = bn + wc + fj * 16 + li;
        float v = acc[fi][fj][r] + bias[col];
        if (res && row < ML_) v += res[(size_t)row * N + col];
        if (act == 1) v = gelu_tanh(v);
        if (Cf && row < ML_) Cf[(size_t)row * N + col] = v;
        if (Cb) Cb[(size_t)row * N + col] = f2b(v);
      }
}

// ---------------- layernorm: wave per row, vectorized -----------------------
__global__ __launch_bounds__(256) void layernorm_ip(float* __restrict__ Xb,
                                                    const float* __restrict__ g,
                                                    const float* __restrict__ bta,
                                                    u16* __restrict__ outb) {
  int row = blockIdx.x * 4 + (threadIdx.x >> 6);
  int lane = threadIdx.x & 63;
  float* x = Xb + (size_t)row * DM_;
  f4 a = *(f4*)(x + lane * 8);
  f4 b = *(f4*)(x + lane * 8 + 4);
  float s = a[0] + a[1] + a[2] + a[3] + b[0] + b[1] + b[2] + b[3];
  for (int off = 32; off; off >>= 1) s += __shfl_xor(s, off);
  float mu = s * (1.f / 512.f);
  float vs = 0.f;
#pragma unroll
  for (int i = 0; i < 4; ++i) { a[i] -= mu; b[i] -= mu; vs += a[i] * a[i] + b[i] * b[i]; }
  for (int off = 32; off; off >>= 1) vs += __shfl_xor(vs, off);
  float rs = rsqrtf(vs * (1.f / 512.f) + 1e-5f);
  f4 g0 = *(const f4*)(g + lane * 8), g1 = *(const f4*)(g + lane * 8 + 4);
  f4 c0 = *(const f4*)(bta + lane * 8), c1 = *(const f4*)(bta + lane * 8 + 4);
  u16 ob[8];
#pragma unroll
  for (int i = 0; i < 4; ++i) {
    float r1 = a[i] * rs * g0[i] + c0[i]; x[lane * 8 + i] = r1;     ob[i] = f2b(r1);
    float r2 = b[i] * rs * g1[i] + c1[i]; x[lane * 8 + 4 + i] = r2; ob[4 + i] = f2b(r2);
  }
  *(s8v*)(outb + (size_t)row * DM_ + lane * 8) = *(s8v*)ob;
}

// ---------------- ProbSparse sparsity measure M (bf16 qkv), swizzled --------
__global__ __launch_bounds__(256) void probM(const u16* __restrict__ qkv,
                                             const int* __restrict__ sidx,
                                             float* __restrict__ Mout) {
  int wid = threadIdx.x / 64, lane = threadIdx.x % 64;
  int o = xswz(blockIdx.x, (B_ * H_ * L_ / 4) >> 3);
  int g = o * 4 + wid;
  int l = g % L_;
  int bh = g / L_;
  int h = bh % H_, b = bh / H_;
  __shared__ float qs[4][64];
  qs[wid][lane] = b2f(qkv[((size_t)b * L_ + l) * 1536 + h * 64 + lane]);
  __syncthreads();
  float dot = 0.f;
  if (lane < SK_) {
    int ks = sidx[l * SK_ + lane];
    const u16* kr = qkv + ((size_t)b * L_ + ks) * 1536 + 512 + h * 64;
#pragma unroll
    for (int j = 0; j < 8; ++j) {
      s8v v = *(const s8v*)(kr + j * 8);
#pragma unroll
      for (int i = 0; i < 8; ++i) dot += qs[wid][j * 8 + i] * b2f((u16)v[i]);
    }
  }
  float vmax = (lane < SK_) ? dot : -INFINITY;
  float vsum = (lane < SK_) ? dot : 0.f;
  for (int off = 32; off; off >>= 1) {
    vmax = fmaxf(vmax, __shfl_xor(vmax, off));
    vsum += __shfl_xor(vsum, off);
  }
  if (lane == 0) Mout[g] = vmax - vsum / (float)L_;
}

// ---------------- radix-select top-40 (matches lax.top_k selection set) -----
__global__ __launch_bounds__(256) void radix_topk(const float* __restrict__ Mv,
                                                  int* __restrict__ top) {
  const int bh = blockIdx.x;
  const int t = threadIdx.x;
  const int base = t * 6;
  unsigned key[6];
#pragma unroll
  for (int i = 0; i < 6; ++i) {
    int ix = base + i;
    unsigned k = 0u;
    if (ix < L_) {
      union { float f; unsigned u; } c; c.f = Mv[(size_t)bh * L_ + ix];
      k = c.u ^ ((c.u & 0x80000000u) ? 0xFFFFFFFFu : 0x80000000u);
    }
    key[i] = k;
  }
  __shared__ int wred[4];
  __shared__ int s_a[256], s_b[256];
  unsigned prefix = 0u;
  for (int b = 31; b >= 0; --b) {
    unsigned cand = prefix | (1u << b);
    int c = 0;
#pragma unroll
    for (int i = 0; i < 6; ++i) c += (key[i] >= cand);
    for (int off = 32; off; off >>= 1) c += __shfl_xor(c, off);
    if ((t & 63) == 0) wred[t >> 6] = c;
    __syncthreads();
    int tot = wred[0] + wred[1] + wred[2] + wred[3];
    if (tot >= SK_) prefix = cand;
    __syncthreads();
  }
  const unsigned T = prefix;
  int gt = 0, tie = 0;
#pragma unroll
  for (int i = 0; i < 6; ++i) { gt += (key[i] > T); tie += (key[i] == T); }
  s_a[t] = gt; s_b[t] = tie;
  __syncthreads();
  for (int off = 1; off < 256; off <<= 1) {
    int va = (t >= off) ? s_a[t - off] : 0;
    int vb = (t >= off) ? s_b[t - off] : 0;
    __syncthreads();
    s_a[t] += va; s_b[t] += vb;
    __syncthreads();
  }
  const int n_strict = s_a[255];
  const int gt_base = s_a[t] - gt;
  const int tie_base = s_b[t] - tie;
  const int need = SK_ - n_strict;
  int lgt = 0, ltie = 0;
#pragma unroll
  for (int i = 0; i < 6; ++i) {
    int ix = base + i;
    if (key[i] > T) {
      top[bh * SK_ + gt_base + lgt] = ix; ++lgt;
    } else if (key[i] == T) {
      int r = tie_base + ltie; ++ltie;
      if (r < need) top[bh * SK_ + n_strict + r] = ix;
    }
  }
}

// ---------------- V^T build: VT[bh][64][LP_] from V columns, swizzled -------
__global__ __launch_bounds__(256) void transpose_v(const u16* __restrict__ src,
                                                   int stride, int voff0,
                                                   u16* __restrict__ VT) {
  int o = xswz(blockIdx.x, (B_ * H_ * 24) >> 3);
  int kt = o % 24, bh = o / 24;
  int h = bh & 7, b = bh >> 3;
  int kb = kt * 64;
  __shared__ u16 tile[64][72];
  int t = threadIdx.x;
#pragma unroll
  for (int rr = 0; rr < 2; ++rr) {
    int slot = rr * 256 + t;
    int key = slot >> 3, d = (slot & 7) * 8;
    int gk = kb + key; if (gk >= L_) gk = L_ - 1;
    s8v v = *(const s8v*)(src + (size_t)(b * L_ + gk) * stride + voff0 + h * 64 + d);
    *(s8v*)(&tile[key][d]) = v;
  }
  __syncthreads();
  int dim = t >> 2, k0 = (t & 3) * 16;
  u16 buf[16];
#pragma unroll
  for (int i = 0; i < 16; ++i) {
    int key = k0 + i;
    buf[i] = (kb + key < L_) ? tile[key][dim] : (u16)0;
  }
  *(s8v*)(VT + ((size_t)bh * 64 + dim) * LP_ + kb + k0) = *(s8v*)buf;
  *(s8v*)(VT + ((size_t)bh * 64 + dim) * LP_ + kb + k0 + 8) = *(s8v*)(buf + 8);
}

// ---------------- LDS-staged swapped-operand MFMA flash attention -----------
template<int MODE>
__global__ __launch_bounds__(256) void flash_attn(
    const u16* __restrict__ Qm, const u16* __restrict__ Kg,
    const u16* __restrict__ VT, const int* __restrict__ top,
    float* __restrict__ POf, u16* POa, u16* POb,
    float* __restrict__ PM, float* __restrict__ PL) {
  constexpr int QSTR = (MODE == 0) ? 512 : 1536;
  constexpr int KSTR = (MODE == 0) ? 512 : 1536;
  constexpr int TILES = (MODE == 0) ? 12 : 3;
  constexpr int NB = (MODE == 0) ? 48 : 8;
  __shared__ __align__(16) u16 Kt[64 * 64];        // [key][slot^(key&7)]
  __shared__ __align__(16) u16 Vt[64 * 64];        // [dim][slot^(dim&7)]
  __shared__ __align__(16) unsigned Xch[4][576];   // per-wave P exchange
  const int o = xswz(blockIdx.x, (B_ * H_ * NB) >> 3);
  int bh, sp, qb;
  if (MODE == 0) {
    bh = o / 48; int rem = o % 48; qb = rem >> 1; sp = rem & 1;
  } else {
    bh = o / 8; sp = o % 8; qb = 0;
  }
  const int h = bh & 7, b = bh >> 3;
  const int qoff = h * 64;
  const int koff = ((MODE == 0) ? 0 : 512) + h * 64;
  const int t = threadIdx.x, w = t >> 6, lane = t & 63;
  const int lg = lane >> 4, li = lane & 15;
  const u16* vtg = VT + (size_t)bh * 64 * LP_;
  unsigned* xw = Xch[w];
  u16* xw16 = (u16*)xw;

  int qrow;
  if (MODE == 0) {
    int q = qb * 64 + w * 16 + li;
    qrow = b * L_ + ((q < L_) ? q : (L_ - 1));
  } else {
    int u = w * 16 + li; if (u >= SK_) u = SK_ - 1;
    qrow = b * L_ + top[bh * SK_ + u];
  }
  s8v qf0 = *(const s8v*)(Qm + (size_t)qrow * QSTR + qoff + lg * 8);
  s8v qf1 = *(const s8v*)(Qm + (size_t)qrow * QSTR + qoff + 32 + lg * 8);

  f4 o4[4];                          // o4[n][r] = O^T[d=n*16+lg*4+r][q=li]
#pragma unroll
  for (int n = 0; n < 4; ++n) o4[n] = f4{0.f, 0.f, 0.f, 0.f};
  float m_run = -INFINITY, l_run = 0.f;   // per-lane (q=li)
  const int kt0 = sp * TILES;
  const int skey = lane >> 3;
  const int sslot = lane & 7;

#pragma unroll 1
  for (int ki = 0; ki < TILES; ++ki) {
    const int kb = (kt0 + ki) * 64;
#pragma unroll
    for (int j = 0; j < 2; ++j) {
      int row = w * 16 + j * 8 + skey;
      int gk = kb + row; if (gk >= L_) gk = L_ - 1;
      int ck = sslot ^ (row & 7);
      __builtin_amdgcn_global_load_lds(
          (const __attribute__((address_space(1))) void*)(Kg + (size_t)(b * L_ + gk) * KSTR + koff + ck * 8),
          (__attribute__((address_space(3))) void*)(Kt + (w * 16 + j * 8) * 64),
          16, 0, 0);
      int cv = sslot ^ (row & 7);
      __builtin_amdgcn_global_load_lds(
          (const __attribute__((address_space(1))) void*)(vtg + (size_t)row * LP_ + kb + cv * 8),
          (__attribute__((address_space(3))) void*)(Vt + (w * 16 + j * 8) * 64),
          16, 0, 0);
    }
    __syncthreads();
    f4 s[4];
#pragma unroll
    for (int c = 0; c < 4; ++c) {
      int key = c * 16 + li;
      s8v kf = *(const s8v*)(Kt + key * 64 + ((lg ^ (key & 7)) * 8));
      s8v kg2 = *(const s8v*)(Kt + key * 64 + (((lg + 4) ^ (key & 7)) * 8));
      f4 z = f4{0.f, 0.f, 0.f, 0.f};
      z = __builtin_amdgcn_mfma_f32_16x16x32_bf16(kf, qf0, z, 0, 0, 0);
      z = __builtin_amdgcn_mfma_f32_16x16x32_bf16(kg2, qf1, z, 0, 0, 0);
      s[c] = z * 0.125f;
    }
    if (kb + 64 > L_) {
#pragma unroll
      for (int c = 0; c < 4; ++c)
#pragma unroll
        for (int r = 0; r < 4; ++r)
          if (kb + c * 16 + lg * 4 + r >= L_) s[c][r] = -INFINITY;
    }
    float tm = -INFINITY;
#pragma unroll
    for (int c = 0; c < 4; ++c)
      tm = fmaxf(tm, fmaxf(fmaxf(s[c][0], s[c][1]), fmaxf(s[c][2], s[c][3])));
    tm = fmaxf(tm, __shfl_xor(tm, 16));
    tm = fmaxf(tm, __shfl_xor(tm, 32));
    float mn = fmaxf(m_run, tm);
    float sc = __expf(m_run - mn);
    float p[4][4];
    float rs = 0.f;
#pragma unroll
    for (int c = 0; c < 4; ++c)
#pragma unroll
      for (int r = 0; r < 4; ++r) { p[c][r] = __expf(s[c][r] - mn); rs += p[c][r]; }
    rs += __shfl_xor(rs, 16);
    rs += __shfl_xor(rs, 32);
    l_run = l_run * sc + rs;
    m_run = mn;
#pragma unroll
    for (int n = 0; n < 4; ++n) o4[n] *= sc;
#pragma unroll
    for (int c = 0; c < 4; ++c)
#pragma unroll
      for (int rp = 0; rp < 2; ++rp) {
        unsigned v = (unsigned)f2b(p[c][2 * rp]) | ((unsigned)f2b(p[c][2 * rp + 1]) << 16);
        xw[li * 36 + c * 8 + lg * 2 + rp] = v;
      }
    s8v pb0 = *(const s8v*)(xw + li * 36 + lg * 4);
    s8v pb1 = *(const s8v*)(xw + li * 36 + 16 + lg * 4);
#pragma unroll
    for (int n = 0; n < 4; ++n) {
      int dim = n * 16 + li;
      s8v vb0 = *(const s8v*)(Vt + dim * 64 + ((lg ^ (dim & 7)) * 8));
      o4[n] = __builtin_amdgcn_mfma_f32_16x16x32_bf16(vb0, pb0, o4[n], 0, 0, 0);
    }
#pragma unroll
    for (int n = 0; n < 4; ++n) {
      int dim = n * 16 + li;
      s8v vb1 = *(const s8v*)(Vt + dim * 64 + (((lg + 4) ^ (dim & 7)) * 8));
      o4[n] = __builtin_amdgcn_mfma_f32_16x16x32_bf16(vb1, pb1, o4[n], 0, 0, 0);
    }
    __syncthreads();
  }

  if (MODE == 0) {
#pragma unroll
    for (int n = 0; n < 4; ++n)
#pragma unroll
      for (int r = 0; r < 4; ++r)
        xw16[li * 72 + n * 16 + lg * 4 + r] = f2b(o4[n][r]);
    u16* PO = sp ? POb : POa;
    const int pid = (bh * 24 + qb) * 2 + sp;
    int q_local = lane >> 2, d0 = (lane & 3) * 16;
    int q = qb * 64 + w * 16 + q_local;
    s8v v0 = *(const s8v*)(xw16 + q_local * 72 + d0);
    s8v v1 = *(const s8v*)(xw16 + q_local * 72 + d0 + 8);
    if (q < L_) {
      u16* dst = PO + ((size_t)(b * L_ + q)) * DM_ + qoff + d0;
      *(s8v*)dst = v0;
      *(s8v*)(dst + 8) = v1;
    }
    if (lg == 0) {
      PM[pid * 64 + w * 16 + li] = m_run;
      PL[pid * 64 + w * 16 + li] = l_run;
    }
  } else {
    int base = (bh * 8 + sp) * 64 + w * 16 + li;
#pragma unroll
    for (int n = 0; n < 4; ++n)
#pragma unroll
      for (int r = 0; r < 4; ++r)
        POf[(size_t)base * 64 + n * 16 + lg * 4 + r] = o4[n][r];
    if (lg == 0) {
      PM[base] = m_run;
      PL[base] = l_run;
    }
  }
}

// ---------------- combine 2-way cross partials (POb == ctxb, in place) ------
__global__ __launch_bounds__(256) void combine_cross(const u16* __restrict__ PO0,
                                                     const float* __restrict__ PM,
                                                     const float* __restrict__ PL,
                                                     u16* ctxb) {
  int idx = blockIdx.x * 256 + threadIdx.x;
  int row = idx >> 9, col = idx & 511;
  int b = row / L_, q = row - b * L_;
  int h = col >> 6;
  int bh = b * 8 + h, qbk = q >> 6, qi = q & 63;
  int p0 = ((bh * 24 + qbk) * 2) * 64 + qi;
  float m0 = PM[p0], m1 = PM[p0 + 64];
  float l0 = PL[p0], l1 = PL[p0 + 64];
  float M = fmaxf(m0, m1);
  float w0 = __expf(m0 - M), w1 = __expf(m1 - M);
  float inv = 1.f / (w0 * l0 + w1 * l1);
  float o0 = b2f(PO0[idx]);
  float o1 = b2f(ctxb[idx]);
  ctxb[idx] = f2b((w0 * o0 + w1 * o1) * inv);
}

// ---------------- combine split-K partials -> ctt ----------------------------
__global__ __launch_bounds__(256) void combine_prob(const float* __restrict__ PO,
                                                    const float* __restrict__ PM,
                                                    const float* __restrict__ PL,
                                                    float* __restrict__ ctt) {
  int bh = blockIdx.x;
  int t = threadIdx.x;
  int u = t >> 2, dg = (t & 3) * 16;
  if (u >= SK_) return;
  float M = -INFINITY;
  for (int s = 0; s < 8; ++s) M = fmaxf(M, PM[(bh * 8 + s) * 64 + u]);
  float wgt[8];
  float den = 0.f;
  for (int s = 0; s < 8; ++s) {
    wgt[s] = __expf(PM[(bh * 8 + s) * 64 + u] - M);
    den += wgt[s] * PL[(bh * 8 + s) * 64 + u];
  }
  float inv = 1.f / den;
  for (int d = dg; d < dg + 16; ++d) {
    float acc = 0.f;
    for (int s = 0; s < 8; ++s) acc += wgt[s] * PO[(((size_t)bh * 8 + s) * 64 + u) * 64 + d];
    ctt[((size_t)bh * SK_ + u) * 64 + d] = acc * inv;
  }
}

// ---------------- V mean: 8-way partial + combine, swizzled -----------------
__global__ __launch_bounds__(256) void vmean_part(const u16* __restrict__ qkv,
                                                  float* __restrict__ part) {
  int g = xswz(blockIdx.x, (B_ * H_ * 8) >> 3);
  int bh = g >> 3, seg = g & 7;
  int h = bh & 7, b = bh >> 3;
  int lane = threadIdx.x & 63, grp = threadIdx.x >> 6;
  int k0 = seg * 190, k1 = k0 + 190;
  float acc = 0.f;
  for (int k = k0 + grp; k < k1; k += 4)
    acc += b2f(qkv[((size_t)b * L_ + k) * 1536 + 1024 + h * 64 + lane]);
  __shared__ float pv[4][64];
  pv[grp][lane] = acc;
  __syncthreads();
  if (threadIdx.x < 64)
    part[g * 64 + threadIdx.x] =
        pv[0][threadIdx.x] + pv[1][threadIdx.x] + pv[2][threadIdx.x] + pv[3][threadIdx.x];
}

__global__ __launch_bounds__(256) void vmean_comb(const float* __restrict__ part,
                                                  float* __restrict__ vmean) {
  int idx = blockIdx.x * 256 + threadIdx.x;
  int bh = idx >> 6, d = idx & 63;
  float s = 0.f;
#pragma unroll
  for (int seg = 0; seg < 8; ++seg) s += part[(bh * 8 + seg) * 64 + d];
  vmean[idx] = s / (float)L_;
}

// ---------------- ctx = broadcast vmean (bf16), then scatter top ------------
__global__ __launch_bounds__(256) void fill_ctx(const float* __restrict__ vmean,
                                                u16* __restrict__ ctxb) {
  int idx = blockIdx.x * 256 + threadIdx.x;
  int d = idx % 64;
  int h = (idx / 64) % H_;
  int b = idx / (L_ * DM_);
  ctxb[idx] = f2b(vmean[(b * H_ + h) * 64 + d]);
}

__global__ __launch_bounds__(256) void scatter_ctx(const float* __restrict__ ctt,
                                                   const int* __restrict__ top,
                                                   u16* __restrict__ ctxb) {
  int idx = blockIdx.x * 256 + threadIdx.x;
  int d = idx % 64;
  int u = (idx / 64) % SK_;
  int bh = idx / (64 * SK_);
  int h = bh % H_, b = bh / H_;
  int l = top[bh * SK_ + u];
  ctxb[((size_t)b * L_ + l) * DM_ + h * 64 + d] = f2b(ctt[idx]);
}

// ---------------- host side --------------------------------------------------
extern "C" void kernel_launch(void* const* d_in, const int* in_sizes, int n_in,
                              void* d_out, int out_size, void* d_ws, size_t ws_size,
                              hipStream_t stream) {
  const float* inflow   = (const float*)d_in[4];
  const float* W_emb_e  = (const float*)d_in[5];
  const float* b_emb_e  = (const float*)d_in[6];
  const float* W_emb_d  = (const float*)d_in[7];
  const float* b_emb_d  = (const float*)d_in[8];
  const float* enc_Wqkv = (const float*)d_in[9];
  const float* enc_bqkv = (const float*)d_in[10];
  const float* enc_Wo   = (const float*)d_in[11];
  const float* enc_bo   = (const float*)d_in[12];
  const float* enc_ln1g = (const float*)d_in[13];
  const float* enc_ln1b = (const float*)d_in[14];
  const float* enc_Wf1  = (const float*)d_in[15];
  const float* enc_bf1  = (const float*)d_in[16];
  const float* enc_Wf2  = (const float*)d_in[17];
  const float* enc_bf2  = (const float*)d_in[18];
  const float* enc_ln2g = (const float*)d_in[19];
  const float* enc_ln2b = (const float*)d_in[20];
  const float* enc_ng   = (const float*)d_in[21];
  const float* enc_nb   = (const float*)d_in[22];
  const float* dec_Wqkv = (const float*)d_in[23];
  const float* dec_bqkv = (const float*)d_in[24];
  const float* dec_Wo_s = (const float*)d_in[25];
  const float* dec_bo_s = (const float*)d_in[26];
  const float* dec_ln1g = (const float*)d_in[27];
  const float* dec_ln1b = (const float*)d_in[28];
  const float* dec_Wq_c = (const float*)d_in[29];
  const float* dec_bq_c = (const float*)d_in[30];
  const float* dec_Wkv  = (const float*)d_in[31];
  const float* dec_bkv  = (const float*)d_in[32];
  const float* dec_Wo_c = (const float*)d_in[33];
  const float* dec_bo_c = (const float*)d_in[34];
  const float* dec_ln2g = (const float*)d_in[35];
  const float* dec_ln2b = (const float*)d_in[36];
  const float* dec_Wf1  = (const float*)d_in[37];
  const float* dec_bf1  = (const float*)d_in[38];
  const float* dec_Wf2  = (const float*)d_in[39];
  const float* dec_bf2  = (const float*)d_in[40];
  const float* dec_ln3g = (const float*)d_in[41];
  const float* dec_ln3b = (const float*)d_in[42];
  const float* W_proj   = (const float*)d_in[43];
  const float* b_proj   = (const float*)d_in[44];
  const float* W1       = (const float*)d_in[45];
  const float* b1       = (const float*)d_in[46];
  const float* W3       = (const float*)d_in[47];
  const float* b3       = (const float*)d_in[48];
  const int*   samp     = (const int*)d_in[49];
  float* out = (float*)d_out;

  float* ws  = (float*)d_ws;
  float* PE  = ws;                       // 778240 f (dead after embeds -> PM/PL)
  float* X   = PE + 778240;              // 72960 f
  float* ACT = X + 72960;                // 3112960 f
  float* REG = ACT + 3112960;            // 6291456 f shared region
  float* MME = REG + 6291456;            // 48640 f (VME8 overlay after topk)
  float* CTT = MME + 48640;              // 81920 f
  float* VME = CTT + 81920;              // 2048 f
  int*   TOP = (int*)(VME + 2048);       // 1280 i
  float* TAIL = VME + 2048 + 1280;
  u16* ENCb = (u16*)TAIL;                       // 6144*512 u16
  u16* DECb = (u16*)(TAIL + 1572864);
  u16* CTXb = (u16*)(TAIL + 2 * 1572864);
  u16* WBF  = (u16*)(TAIL + 3 * 1572864);       // 10485760 u16

  // region overlays (prob phase)
  u16* QKVb = (u16*)REG;                 // [6144][1536]
  u16* FFb  = (u16*)REG;                 // [6144][2048]
  u16* VT   = (u16*)REG + 9437184;       // [32][64][1536] u16
  // region overlays (cross phase)
  u16* QCb  = (u16*)REG;                 // [6144][512]
  u16* Kc   = (u16*)REG + 3145728;       // [6144][512]
  u16* Vc   = (u16*)REG + 6291456;       // [6144][512]; becomes PO-split0 after transpose
  // prob split-K partials overlay CTXb (rebuilt by fill_ctx afterwards)
  float* POp = (float*)CTXb;             // 32*8*64*64 f
  float* PMp = POp + 1048576;
  float* PLp = PMp + 16384;
  // cross partial stats in dead PE region (32*24*2*64 = 98304 each)
  float* PMc = PE;
  float* PLc = PE + 98304;
  float* VME8 = MME;                     // 16384 f (after radix_topk)

  auto GB = [&](const u16* A, const u16* Bt, const float* bias, const float* res,
                float* Cf, u16* Cb, int N, int K, int act) {
    if (N <= 512) {
      dim3 g(N / 128, MP_ / 64);
      gemm_bf16<64><<<g, 256, 0, stream>>>(A, Bt, bias, res, Cf, Cb, N, K, act);
    } else {
      dim3 g(N / 128, MP_ / 128);
      gemm_bf16<128><<<g, 256, 0, stream>>>(A, Bt, bias, res, Cf, Cb, N, K, act);
    }
  };
  auto PROB = [&](const int* sidx) {
    probM<<<B_ * H_ * L_ / 4, 256, 0, stream>>>(QKVb, sidx, MME);
    radix_topk<<<B_ * H_, 256, 0, stream>>>(MME, TOP);
    transpose_v<<<B_ * H_ * 24, 256, 0, stream>>>(QKVb, 1536, 1024, VT);
    flash_attn<1><<<B_ * H_ * 8, 256, 0, stream>>>(QKVb, QKVb, VT, TOP, POp,
                                                   nullptr, nullptr, PMp, PLp);
    combine_prob<<<B_ * H_, 256, 0, stream>>>(POp, PMp, PLp, CTT);
    vmean_part<<<B_ * H_ * 8, 256, 0, stream>>>(QKVb, VME8);
    vmean_comb<<<8, 256, 0, stream>>>(VME8, VME);
    fill_ctx<<<ML_ * DM_ / 256, 256, 0, stream>>>(VME, CTXb);
    scatter_ctx<<<B_ * H_ * SK_ * 64 / 256, 256, 0, stream>>>(CTT, TOP, CTXb);
  };

  pe_kernel<<<(L_ * DM_ + 255) / 256, 256, 0, stream>>>(PE);
  extract_x<<<(ML_ * 12 + 255) / 256, 256, 0, stream>>>(inflow, X);

  // one fused weight-conversion dispatch (LDS tiled transpose)
  {
    CvtArgs a;
    const float* s[15] = {
      enc_Wqkv, enc_Wqkv + 512 * 1536, enc_Wo, enc_Wo + 512 * 512,
      enc_Wf1, enc_Wf1 + 512 * 2048, enc_Wf2, enc_Wf2 + 2048 * 512,
      dec_Wqkv, dec_Wo_s, dec_Wq_c, dec_Wkv, dec_Wo_c, dec_Wf1, dec_Wf2 };
    unsigned cumt[16] = { 0u, 768u, 1536u, 1792u, 2048u, 3072u,
                          4096u, 5120u, 6144u, 6912u, 7168u,
                          7424u, 7936u, 8192u, 9216u, 10240u };
    unsigned lk[15] = { 9, 9, 9, 9, 9, 9, 11, 11, 9, 9, 9, 9, 9, 9, 11 };
    for (int i = 0; i < 15; ++i) { a.src[i] = s[i]; a.lk[i] = lk[i]; }
    for (int i = 0; i < 16; ++i) a.cumt[i] = cumt[i];
    cvt_all<<<10240, 256, 0, stream>>>(a, WBF);
  }
  u16* Wt_qkv_e0 = WBF + 0;
  u16* Wt_qkv_e1 = WBF + 786432;
  u16* Wt_o_e0   = WBF + 1572864;
  u16* Wt_o_e1   = WBF + 1835008;
  u16* Wt_f1_e0  = WBF + 2097152;
  u16* Wt_f1_e1  = WBF + 3145728;
  u16* Wt_f2_e0  = WBF + 4194304;
  u16* Wt_f2_e1  = WBF + 5242880;
  u16* Wt_qkv_d  = WBF + 6291456;
  u16* Wt_o_s    = WBF + 7077888;
  u16* Wt_q_c    = WBF + 7340032;
  u16* Wt_kv_c   = WBF + 7602176;
  u16* Wt_o_c    = WBF + 8126464;
  u16* Wt_f1_d   = WBF + 8388608;
  u16* Wt_f2_d   = WBF + 9437184;

  // ---------------- encoder ----------------
  embed_fused<<<MP_ / 4, 256, 0, stream>>>(X, W_emb_e, b_emb_e, PE, ACT, ENCb);

  const u16* Wqkv_e[2] = {Wt_qkv_e0, Wt_qkv_e1};
  const u16* Wo_e[2]   = {Wt_o_e0, Wt_o_e1};
  const u16* Wf1_e[2]  = {Wt_f1_e0, Wt_f1_e1};
  const u16* Wf2_e[2]  = {Wt_f2_e0, Wt_f2_e1};
  for (int i = 0; i < 2; ++i) {
    GB(ENCb, Wqkv_e[i], enc_bqkv + i * 1536, nullptr, nullptr, QKVb, 1536, 512, 0);
    PROB(samp + (size_t)i * L_ * SK_);
    GB(CTXb, Wo_e[i], enc_bo + i * 512, ACT, ACT, nullptr, 512, 512, 0);
    layernorm_ip<<<ML_ / 4, 256, 0, stream>>>(ACT, enc_ln1g + i * 512, enc_ln1b + i * 512, ENCb);
    GB(ENCb, Wf1_e[i], enc_bf1 + i * 2048, nullptr, nullptr, FFb, 2048, 512, 1);
    GB(FFb, Wf2_e[i], enc_bf2 + i * 512, ACT, ACT, nullptr, 512, 2048, 0);
    layernorm_ip<<<ML_ / 4, 256, 0, stream>>>(ACT, enc_ln2g + i * 512, enc_ln2b + i * 512, ENCb);
  }
  layernorm_ip<<<ML_ / 4, 256, 0, stream>>>(ACT, enc_ng, enc_nb, ENCb);

  // ---------------- decoder ----------------
  embed_fused<<<MP_ / 4, 256, 0, stream>>>(X, W_emb_d, b_emb_d, PE, ACT, DECb);
  GB(DECb, Wt_qkv_d, dec_bqkv, nullptr, nullptr, QKVb, 1536, 512, 0);
  PROB(samp + (size_t)2 * L_ * SK_);
  GB(CTXb, Wt_o_s, dec_bo_s, ACT, ACT, nullptr, 512, 512, 0);
  layernorm_ip<<<ML_ / 4, 256, 0, stream>>>(ACT, dec_ln1g, dec_ln1b, DECb);

  // cross attention: Q, K, V as separate [*,512] GEMMs; V buffer becomes split-0
  GB(DECb, Wt_q_c, dec_bq_c, nullptr, nullptr, QCb, 512, 512, 0);
  GB(ENCb, Wt_kv_c, dec_bkv, nullptr, nullptr, Kc, 512, 512, 0);
  GB(ENCb, Wt_kv_c + 512 * 512, dec_bkv + 512, nullptr, nullptr, Vc, 512, 512, 0);
  transpose_v<<<B_ * H_ * 24, 256, 0, stream>>>(Vc, 512, 0, VT);
  flash_attn<0><<<B_ * H_ * 48, 256, 0, stream>>>(QCb, Kc, VT, nullptr, nullptr,
                                                  Vc, CTXb, PMc, PLc);
  combine_cross<<<ML_ * DM_ / 256, 256, 0, stream>>>(Vc, PMc, PLc, CTXb);
  GB(CTXb, Wt_o_c, dec_bo_c, ACT, ACT, nullptr, 512, 512, 0);
  layernorm_ip<<<ML_ / 4, 256, 0, stream>>>(ACT, dec_ln2g, dec_ln2b, DECb);

  GB(DECb, Wt_f1_d, dec_bf1, nullptr, nullptr, FFb, 2048, 512, 1);
  GB(FFb, Wt_f2_d, dec_bf2, ACT, ACT, nullptr, 512, 2048, 0);
  layernorm_ip<<<ML_ / 4, 256, 0, stream>>>(ACT, dec_ln3g, dec_ln3b, DECb);

  // fused head
  head_fused<<<ML_ / 4, 256, 0, stream>>>(ACT, X, W_proj, b_proj, W1, b1, W3, b3, out);
}

// Round 14
// 869.353 us; speedup vs baseline: 1.2022x; 1.0188x over previous
//
#include <hip/hip_runtime.h>
#include <math.h>

#define B_ 4
#define H_ 8
#define L_ 1520
#define DM_ 512
#define DFF_ 2048
#define SK_ 40
#define ML_ (B_*L_)   /* 6080 rows */
#define MP_ 6144      /* padded rows for MFMA GEMM */
#define LP_ 1536      /* padded key count for V^T */

typedef unsigned short u16;
typedef short s8v __attribute__((ext_vector_type(8)));
typedef float f4 __attribute__((ext_vector_type(4)));

__device__ __forceinline__ u16 f2b(float x) {
  union { float f; unsigned u; } c; c.f = x;
  unsigned r = c.u + 0x7FFFu + ((c.u >> 16) & 1u);
  return (u16)(r >> 16);
}
__device__ __forceinline__ float b2f(u16 h) {
  union { unsigned u; float f; } c; c.u = ((unsigned)h) << 16;
  return c.f;
}
// packed f32 pair -> 2x bf16 in one u32 (lo = a, hi = b); single VALU op
__device__ __forceinline__ unsigned cvt_pk(float a, float b) {
  unsigned r;
  asm volatile("v_cvt_pk_bf16_f32 %0, %1, %2" : "=v"(r) : "v"(a), "v"(b));
  return r;
}
__device__ __forceinline__ float gelu_tanh(float x) {
  float x3 = x * x * x;
  return 0.5f * x * (1.f + tanhf(0.79788456080286536f * (x + 0.044715f * x3)));
}
// XCD-chunked bijective swizzle; requires nwg % 8 == 0 (cpx = nwg/8).
__device__ __forceinline__ int xswz(int bid, int cpx) {
  return (bid & 7) * cpx + (bid >> 3);
}

// ---------------- positional encoding (double precision to match numpy) ----
__global__ __launch_bounds__(256) void pe_kernel(float* __restrict__ pe) {
  int idx = blockIdx.x * 256 + threadIdx.x;
  if (idx >= L_ * DM_) return;
  int pos = idx / DM_, i = idx % DM_;
  double expo = (double)(2 * (i / 2)) / (double)DM_;
  double ang = (double)pos / pow(10000.0, expo);
  pe[idx] = (i & 1) ? (float)cos(ang) : (float)sin(ang);
}

// ---------------- x = inflow[:,2:14].reshape (contiguous slice) -------------
__global__ __launch_bounds__(256) void extract_x(const float* __restrict__ inflow,
                                                 float* __restrict__ X) {
  int idx = blockIdx.x * 256 + threadIdx.x;
  if (idx >= ML_ * 12) return;
  int b = idx / (L_ * 12);
  int rem = idx - b * (L_ * 12);
  X[idx] = inflow[(size_t)b * 14 * L_ + 2 * L_ + rem];
}

// ---------------- fused weight convert+transpose (LDS tiled, coalesced) -----
struct CvtArgs {
  const float* src[15];
  unsigned cumt[16];   // cumulative 32x32-tile counts
  unsigned lk[15];     // log2(K) per segment
};
__global__ __launch_bounds__(256) void cvt_all(CvtArgs a, u16* __restrict__ dst) {
  __shared__ float tl[32][33];
  int bt = blockIdx.x;                 // grid exact: 10240 tiles
  int s = 0;
#pragma unroll
  for (int i = 1; i < 15; ++i) s += (bt >= (int)a.cumt[i]);
  int lt = bt - a.cumt[s];
  unsigned lk = a.lk[s];
  unsigned K = 1u << lk;
  unsigned N = ((a.cumt[s + 1] - a.cumt[s]) << 10) >> lk;
  unsigned tiles_n = N >> 5;
  unsigned k0 = (lt / tiles_n) * 32, n0 = (lt % tiles_n) * 32;
  const float* src = a.src[s];
  int r = threadIdx.x >> 5, c = threadIdx.x & 31;
#pragma unroll
  for (int i = 0; i < 4; ++i)
    tl[r + 8 * i][c] = src[(size_t)(k0 + r + 8 * i) * N + n0 + c];
  __syncthreads();
  u16* d = dst + ((size_t)a.cumt[s] << 10);
#pragma unroll
  for (int i = 0; i < 4; ++i)
    d[(size_t)(n0 + r + 8 * i) * K + k0 + c] = f2b(tl[c][r + 8 * i]);
}

// ---------------- fused embed: ACT = X@W + b + PE ; ACTb = bf16(ACT) --------
__global__ __launch_bounds__(256) void embed_fused(
    const float* __restrict__ X, const float* __restrict__ W,
    const float* __restrict__ bias, const float* __restrict__ PE,
    float* __restrict__ ACT, u16* __restrict__ ACTb) {
  int row = blockIdx.x * 4 + (threadIdx.x >> 6);
  int lane = threadIdx.x & 63;
  int d0 = lane * 8;
  if (row >= ML_) {
    s8v z = {0, 0, 0, 0, 0, 0, 0, 0};
    *(s8v*)(ACTb + (size_t)row * DM_ + d0) = z;
    return;
  }
  int prow = row % L_;
  f4 a0 = *(const f4*)(bias + d0);
  f4 a1 = *(const f4*)(bias + d0 + 4);
  a0 += *(const f4*)(PE + (size_t)prow * DM_ + d0);
  a1 += *(const f4*)(PE + (size_t)prow * DM_ + d0 + 4);
  const float* xr = X + (size_t)row * 12;
#pragma unroll
  for (int t = 0; t < 12; ++t) {
    float xv = xr[t];
    a0 += xv * *(const f4*)(W + (size_t)t * DM_ + d0);
    a1 += xv * *(const f4*)(W + (size_t)t * DM_ + d0 + 4);
  }
  float* dst = ACT + (size_t)row * DM_ + d0;
  *(f4*)dst = a0;
  *(f4*)(dst + 4) = a1;
  unsigned ob[4];
  ob[0] = cvt_pk(a0[0], a0[1]); ob[1] = cvt_pk(a0[2], a0[3]);
  ob[2] = cvt_pk(a1[0], a1[1]); ob[3] = cvt_pk(a1[2], a1[3]);
  *(s8v*)(ACTb + (size_t)row * DM_ + d0) = *(s8v*)ob;
}

// ---------------- fused head: out = relu((DEC@Wp+bp+X)@W1+b1)@W3+b3 ---------
__global__ __launch_bounds__(256) void head_fused(
    const float* __restrict__ DEC, const float* __restrict__ X,
    const float* __restrict__ Wp, const float* __restrict__ bp,
    const float* __restrict__ W1, const float* __restrict__ b1,
    const float* __restrict__ W3, const float* __restrict__ b3,
    float* __restrict__ out) {
  int row = blockIdx.x * 4 + (threadIdx.x >> 6);
  int lane = threadIdx.x & 63;
  int d0 = lane * 8;
  const float* dec = DEC + (size_t)row * DM_ + d0;
  f4 v0 = *(const f4*)dec;
  f4 v1 = *(const f4*)(dec + 4);
  float pj[12];
#pragma unroll
  for (int j = 0; j < 12; ++j) pj[j] = 0.f;
#pragma unroll
  for (int i = 0; i < 8; ++i) {
    float dv = (i < 4) ? v0[i] : v1[i - 4];
    const float* wr = Wp + (size_t)(d0 + i) * 12;
#pragma unroll
    for (int j = 0; j < 12; ++j) pj[j] += dv * wr[j];
  }
  for (int off = 32; off; off >>= 1) {
#pragma unroll
    for (int j = 0; j < 12; ++j) pj[j] += __shfl_xor(pj[j], off);
  }
  float o12[12];
#pragma unroll
  for (int j = 0; j < 12; ++j) o12[j] = pj[j] + bp[j] + X[(size_t)row * 12 + j];
  int k0 = lane * 2;
  float h0 = b1[k0], h1 = b1[k0 + 1];
#pragma unroll
  for (int j = 0; j < 12; ++j) {
    h0 += o12[j] * W1[j * 128 + k0];
    h1 += o12[j] * W1[j * 128 + k0 + 1];
  }
  h0 = fmaxf(h0, 0.f);
  h1 = fmaxf(h1, 0.f);
  float op[3];
#pragma unroll
  for (int p = 0; p < 3; ++p)
    op[p] = h0 * W3[k0 * 3 + p] + h1 * W3[(k0 + 1) * 3 + p];
  for (int off = 32; off; off >>= 1) {
#pragma unroll
    for (int p = 0; p < 3; ++p) op[p] += __shfl_xor(op[p], off);
  }
  if (lane == 0) {
#pragma unroll
    for (int p = 0; p < 3; ++p) out[(size_t)row * 3 + p] = op[p] + b3[p];
  }
}

// ---------------- bf16 MFMA GEMM, single-buffered, XCD-swizzled -------------
template<int BM>
__global__ __launch_bounds__(256) void gemm_bf16(
    const u16* __restrict__ A, const u16* __restrict__ Bt,
    const float* __restrict__ bias, const float* __restrict__ res,
    float* __restrict__ Cf, u16* __restrict__ Cb,
    int N, int K, int act) {
  __shared__ __align__(16) u16 As[BM * 32];
  __shared__ __align__(16) u16 Bs[128 * 32];
  constexpr int MI = BM / 32;
  const int nwg = gridDim.x * gridDim.y;
  const int lin = blockIdx.y * gridDim.x + blockIdx.x;
  const int o = xswz(lin, nwg >> 3);
  const int bxi = o % gridDim.x, byi = o / gridDim.x;
  const int t = threadIdx.x, w = t >> 6, lane = t & 63;
  const int lg = lane >> 4, li = lane & 15;
  const int bm = byi * BM, bn = bxi * 128;
  const int wr = (w >> 1) * (BM / 2), wc = (w & 1) * 64;
  f4 acc[MI][4];
#pragma unroll
  for (int i = 0; i < MI; ++i)
#pragma unroll
    for (int j = 0; j < 4; ++j) acc[i][j] = f4{0.f, 0.f, 0.f, 0.f};
  const int rB = w * 32 + (lane >> 2);
  const int rA = (BM == 128) ? rB : (w * 16 + (lane >> 2));
  const int ps = lane & 3;
  for (int k0 = 0; k0 < K; k0 += 32) {
    if (BM == 128) {
#pragma unroll
      for (int j = 0; j < 2; ++j) {
        int r = rA + j * 16;
        int ls = ps ^ ((r >> 1) & 3);
        __builtin_amdgcn_global_load_lds(
            (const __attribute__((address_space(1))) void*)(A + (size_t)(bm + r) * K + k0 + ls * 8),
            (__attribute__((address_space(3))) void*)(As + (w * 32 + j * 16) * 32),
            16, 0, 0);
      }
    } else {
      int ls = ps ^ ((rA >> 1) & 3);
      __builtin_amdgcn_global_load_lds(
          (const __attribute__((address_space(1))) void*)(A + (size_t)(bm + rA) * K + k0 + ls * 8),
          (__attribute__((address_space(3))) void*)(As + (w * 16) * 32),
          16, 0, 0);
    }
#pragma unroll
    for (int j = 0; j < 2; ++j) {
      int r = rB + j * 16;
      int ls = ps ^ ((r >> 1) & 3);
      __builtin_amdgcn_global_load_lds(
          (const __attribute__((address_space(1))) void*)(Bt + (size_t)(bn + r) * K + k0 + ls * 8),
          (__attribute__((address_space(3))) void*)(Bs + (w * 32 + j * 16) * 32),
          16, 0, 0);
    }
    __syncthreads();
    s8v af[MI], bf[4];
#pragma unroll
    for (int f = 0; f < MI; ++f) {
      int ra = wr + f * 16 + li;
      af[f] = *(const s8v*)(As + ra * 32 + ((lg ^ ((ra >> 1) & 3)) * 8));
    }
#pragma unroll
    for (int f = 0; f < 4; ++f) {
      int rb = wc + f * 16 + li;
      bf[f] = *(const s8v*)(Bs + rb * 32 + ((lg ^ ((rb >> 1) & 3)) * 8));
    }
#pragma unroll
    for (int fi = 0; fi < MI; ++fi)
#pragma unroll
      for (int fj = 0; fj < 4; ++fj)
        acc[fi][fj] = __builtin_amdgcn_mfma_f32_16x16x32_bf16(af[fi], bf[fj], acc[fi][fj], 0, 0, 0);
    __syncthreads();
  }
#pragma unroll
  for (int fi = 0; fi < MI; ++fi)
#pragma unroll
    for (int fj = 0; fj < 4; ++fj)
#pragma unroll
      for (int r = 0; r < 4; ++r) {
        int row = bm + wr + fi * 16 + lg * 4 + r;
        int col = bn + wc + fj * 16 + li;
        float v = acc[fi][fj][r] + bias[col];
        if (res && row < ML_) v += res[(size_t)row * N + col];
        if (act == 1) v = gelu_tanh(v);
        if (Cf && row < ML_) Cf[(size_t)row * N + col] = v;
        if (Cb) Cb[(size_t)row * N + col] = f2b(v);
      }
}

// ---------------- layernorm: wave per row, vectorized -----------------------
__global__ __launch_bounds__(256) void layernorm_ip(float* __restrict__ Xb,
                                                    const float* __restrict__ g,
                                                    const float* __restrict__ bta,
                                                    u16* __restrict__ outb) {
  int row = blockIdx.x * 4 + (threadIdx.x >> 6);
  int lane = threadIdx.x & 63;
  float* x = Xb + (size_t)row * DM_;
  f4 a = *(f4*)(x + lane * 8);
  f4 b = *(f4*)(x + lane * 8 + 4);
  float s = a[0] + a[1] + a[2] + a[3] + b[0] + b[1] + b[2] + b[3];
  for (int off = 32; off; off >>= 1) s += __shfl_xor(s, off);
  float mu = s * (1.f / 512.f);
  float vs = 0.f;
#pragma unroll
  for (int i = 0; i < 4; ++i) { a[i] -= mu; b[i] -= mu; vs += a[i] * a[i] + b[i] * b[i]; }
  for (int off = 32; off; off >>= 1) vs += __shfl_xor(vs, off);
  float rs = rsqrtf(vs * (1.f / 512.f) + 1e-5f);
  f4 g0 = *(const f4*)(g + lane * 8), g1 = *(const f4*)(g + lane * 8 + 4);
  f4 c0 = *(const f4*)(bta + lane * 8), c1 = *(const f4*)(bta + lane * 8 + 4);
  float r0 = a[0] * rs * g0[0] + c0[0];
  float r1 = a[1] * rs * g0[1] + c0[1];
  float r2 = a[2] * rs * g0[2] + c0[2];
  float r3 = a[3] * rs * g0[3] + c0[3];
  float r4 = b[0] * rs * g1[0] + c1[0];
  float r5 = b[1] * rs * g1[1] + c1[1];
  float r6 = b[2] * rs * g1[2] + c1[2];
  float r7 = b[3] * rs * g1[3] + c1[3];
  x[lane * 8 + 0] = r0; x[lane * 8 + 1] = r1; x[lane * 8 + 2] = r2; x[lane * 8 + 3] = r3;
  x[lane * 8 + 4] = r4; x[lane * 8 + 5] = r5; x[lane * 8 + 6] = r6; x[lane * 8 + 7] = r7;
  unsigned ob[4];
  ob[0] = cvt_pk(r0, r1); ob[1] = cvt_pk(r2, r3);
  ob[2] = cvt_pk(r4, r5); ob[3] = cvt_pk(r6, r7);
  *(s8v*)(outb + (size_t)row * DM_ + lane * 8) = *(s8v*)ob;
}

// ---------------- ProbSparse sparsity measure M (bf16 qkv), swizzled --------
__global__ __launch_bounds__(256) void probM(const u16* __restrict__ qkv,
                                             const int* __restrict__ sidx,
                                             float* __restrict__ Mout) {
  int wid = threadIdx.x / 64, lane = threadIdx.x % 64;
  int o = xswz(blockIdx.x, (B_ * H_ * L_ / 4) >> 3);
  int g = o * 4 + wid;
  int l = g % L_;
  int bh = g / L_;
  int h = bh % H_, b = bh / H_;
  __shared__ float qs[4][64];
  qs[wid][lane] = b2f(qkv[((size_t)b * L_ + l) * 1536 + h * 64 + lane]);
  __syncthreads();
  float dot = 0.f;
  if (lane < SK_) {
    int ks = sidx[l * SK_ + lane];
    const u16* kr = qkv + ((size_t)b * L_ + ks) * 1536 + 512 + h * 64;
#pragma unroll
    for (int j = 0; j < 8; ++j) {
      s8v v = *(const s8v*)(kr + j * 8);
#pragma unroll
      for (int i = 0; i < 8; ++i) dot += qs[wid][j * 8 + i] * b2f((u16)v[i]);
    }
  }
  float vmax = (lane < SK_) ? dot : -INFINITY;
  float vsum = (lane < SK_) ? dot : 0.f;
  for (int off = 32; off; off >>= 1) {
    vmax = fmaxf(vmax, __shfl_xor(vmax, off));
    vsum += __shfl_xor(vsum, off);
  }
  if (lane == 0) Mout[g] = vmax - vsum / (float)L_;
}

// ---------------- radix-select top-40 (matches lax.top_k selection set) -----
__global__ __launch_bounds__(256) void radix_topk(const float* __restrict__ Mv,
                                                  int* __restrict__ top) {
  const int bh = blockIdx.x;
  const int t = threadIdx.x;
  const int base = t * 6;
  unsigned key[6];
#pragma unroll
  for (int i = 0; i < 6; ++i) {
    int ix = base + i;
    unsigned k = 0u;
    if (ix < L_) {
      union { float f; unsigned u; } c; c.f = Mv[(size_t)bh * L_ + ix];
      k = c.u ^ ((c.u & 0x80000000u) ? 0xFFFFFFFFu : 0x80000000u);
    }
    key[i] = k;
  }
  __shared__ int wred[4];
  __shared__ int s_a[256], s_b[256];
  unsigned prefix = 0u;
  for (int b = 31; b >= 0; --b) {
    unsigned cand = prefix | (1u << b);
    int c = 0;
#pragma unroll
    for (int i = 0; i < 6; ++i) c += (key[i] >= cand);
    for (int off = 32; off; off >>= 1) c += __shfl_xor(c, off);
    if ((t & 63) == 0) wred[t >> 6] = c;
    __syncthreads();
    int tot = wred[0] + wred[1] + wred[2] + wred[3];
    if (tot >= SK_) prefix = cand;
    __syncthreads();
  }
  const unsigned T = prefix;
  int gt = 0, tie = 0;
#pragma unroll
  for (int i = 0; i < 6; ++i) { gt += (key[i] > T); tie += (key[i] == T); }
  s_a[t] = gt; s_b[t] = tie;
  __syncthreads();
  for (int off = 1; off < 256; off <<= 1) {
    int va = (t >= off) ? s_a[t - off] : 0;
    int vb = (t >= off) ? s_b[t - off] : 0;
    __syncthreads();
    s_a[t] += va; s_b[t] += vb;
    __syncthreads();
  }
  const int n_strict = s_a[255];
  const int gt_base = s_a[t] - gt;
  const int tie_base = s_b[t] - tie;
  const int need = SK_ - n_strict;
  int lgt = 0, ltie = 0;
#pragma unroll
  for (int i = 0; i < 6; ++i) {
    int ix = base + i;
    if (key[i] > T) {
      top[bh * SK_ + gt_base + lgt] = ix; ++lgt;
    } else if (key[i] == T) {
      int r = tie_base + ltie; ++ltie;
      if (r < need) top[bh * SK_ + n_strict + r] = ix;
    }
  }
}

// ---------------- V^T build: VT[bh][64][LP_] from V columns, swizzled -------
__global__ __launch_bounds__(256) void transpose_v(const u16* __restrict__ src,
                                                   int stride, int voff0,
                                                   u16* __restrict__ VT) {
  int o = xswz(blockIdx.x, (B_ * H_ * 24) >> 3);
  int kt = o % 24, bh = o / 24;
  int h = bh & 7, b = bh >> 3;
  int kb = kt * 64;
  __shared__ u16 tile[64][72];
  int t = threadIdx.x;
#pragma unroll
  for (int rr = 0; rr < 2; ++rr) {
    int slot = rr * 256 + t;
    int key = slot >> 3, d = (slot & 7) * 8;
    int gk = kb + key; if (gk >= L_) gk = L_ - 1;
    s8v v = *(const s8v*)(src + (size_t)(b * L_ + gk) * stride + voff0 + h * 64 + d);
    *(s8v*)(&tile[key][d]) = v;
  }
  __syncthreads();
  int dim = t >> 2, k0 = (t & 3) * 16;
  u16 buf[16];
#pragma unroll
  for (int i = 0; i < 16; ++i) {
    int key = k0 + i;
    buf[i] = (kb + key < L_) ? tile[key][dim] : (u16)0;
  }
  *(s8v*)(VT + ((size_t)bh * 64 + dim) * LP_ + kb + k0) = *(s8v*)buf;
  *(s8v*)(VT + ((size_t)bh * 64 + dim) * LP_ + kb + k0 + 8) = *(s8v*)(buf + 8);
}

// ---------------- LDS-staged swapped-operand MFMA flash attention -----------
template<int MODE>
__global__ __launch_bounds__(256) void flash_attn(
    const u16* __restrict__ Qm, const u16* __restrict__ Kg,
    const u16* __restrict__ VT, const int* __restrict__ top,
    float* __restrict__ POf, u16* POa, u16* POb,
    float* __restrict__ PM, float* __restrict__ PL) {
  constexpr int QSTR = (MODE == 0) ? 512 : 1536;
  constexpr int KSTR = (MODE == 0) ? 512 : 1536;
  constexpr int TILES = (MODE == 0) ? 12 : 3;
  constexpr int NB = (MODE == 0) ? 48 : 8;
  __shared__ __align__(16) u16 Kt[64 * 64];        // [key][slot^(key&7)]
  __shared__ __align__(16) u16 Vt[64 * 64];        // [dim][slot^(dim&7)]
  __shared__ __align__(16) unsigned Xch[4][576];   // per-wave P exchange
  const int o = xswz(blockIdx.x, (B_ * H_ * NB) >> 3);
  int bh, sp, qb;
  if (MODE == 0) {
    bh = o / 48; int rem = o % 48; qb = rem >> 1; sp = rem & 1;
  } else {
    bh = o / 8; sp = o % 8; qb = 0;
  }
  const int h = bh & 7, b = bh >> 3;
  const int qoff = h * 64;
  const int koff = ((MODE == 0) ? 0 : 512) + h * 64;
  const int t = threadIdx.x, w = t >> 6, lane = t & 63;
  const int lg = lane >> 4, li = lane & 15;
  const u16* vtg = VT + (size_t)bh * 64 * LP_;
  unsigned* xw = Xch[w];
  u16* xw16 = (u16*)xw;

  int qrow;
  if (MODE == 0) {
    int q = qb * 64 + w * 16 + li;
    qrow = b * L_ + ((q < L_) ? q : (L_ - 1));
  } else {
    int u = w * 16 + li; if (u >= SK_) u = SK_ - 1;
    qrow = b * L_ + top[bh * SK_ + u];
  }
  s8v qf0 = *(const s8v*)(Qm + (size_t)qrow * QSTR + qoff + lg * 8);
  s8v qf1 = *(const s8v*)(Qm + (size_t)qrow * QSTR + qoff + 32 + lg * 8);

  f4 o4[4];                          // o4[n][r] = O^T[d=n*16+lg*4+r][q=li]
#pragma unroll
  for (int n = 0; n < 4; ++n) o4[n] = f4{0.f, 0.f, 0.f, 0.f};
  float m_run = -INFINITY, l_run = 0.f;   // per-lane (q=li)
  const int kt0 = sp * TILES;
  const int skey = lane >> 3;
  const int sslot = lane & 7;

#pragma unroll 1
  for (int ki = 0; ki < TILES; ++ki) {
    const int kb = (kt0 + ki) * 64;
#pragma unroll
    for (int j = 0; j < 2; ++j) {
      int row = w * 16 + j * 8 + skey;
      int gk = kb + row; if (gk >= L_) gk = L_ - 1;
      int ck = sslot ^ (row & 7);
      __builtin_amdgcn_global_load_lds(
          (const __attribute__((address_space(1))) void*)(Kg + (size_t)(b * L_ + gk) * KSTR + koff + ck * 8),
          (__attribute__((address_space(3))) void*)(Kt + (w * 16 + j * 8) * 64),
          16, 0, 0);
      int cv = sslot ^ (row & 7);
      __builtin_amdgcn_global_load_lds(
          (const __attribute__((address_space(1))) void*)(vtg + (size_t)row * LP_ + kb + cv * 8),
          (__attribute__((address_space(3))) void*)(Vt + (w * 16 + j * 8) * 64),
          16, 0, 0);
    }
    __syncthreads();
    f4 s[4];
#pragma unroll
    for (int c = 0; c < 4; ++c) {
      int key = c * 16 + li;
      s8v kf = *(const s8v*)(Kt + key * 64 + ((lg ^ (key & 7)) * 8));
      s8v kg2 = *(const s8v*)(Kt + key * 64 + (((lg + 4) ^ (key & 7)) * 8));
      f4 z = f4{0.f, 0.f, 0.f, 0.f};
      z = __builtin_amdgcn_mfma_f32_16x16x32_bf16(kf, qf0, z, 0, 0, 0);
      z = __builtin_amdgcn_mfma_f32_16x16x32_bf16(kg2, qf1, z, 0, 0, 0);
      s[c] = z * 0.125f;
    }
    if (kb + 64 > L_) {
#pragma unroll
      for (int c = 0; c < 4; ++c)
#pragma unroll
        for (int r = 0; r < 4; ++r)
          if (kb + c * 16 + lg * 4 + r >= L_) s[c][r] = -INFINITY;
    }
    float tm = -INFINITY;
#pragma unroll
    for (int c = 0; c < 4; ++c)
      tm = fmaxf(tm, fmaxf(fmaxf(s[c][0], s[c][1]), fmaxf(s[c][2], s[c][3])));
    tm = fmaxf(tm, __shfl_xor(tm, 16));
    tm = fmaxf(tm, __shfl_xor(tm, 32));
    float mn = fmaxf(m_run, tm);
    float sc = __expf(m_run - mn);
    float p[4][4];
    float rs = 0.f;
#pragma unroll
    for (int c = 0; c < 4; ++c)
#pragma unroll
      for (int r = 0; r < 4; ++r) { p[c][r] = __expf(s[c][r] - mn); rs += p[c][r]; }
    rs += __shfl_xor(rs, 16);
    rs += __shfl_xor(rs, 32);
    l_run = l_run * sc + rs;
    m_run = mn;
#pragma unroll
    for (int n = 0; n < 4; ++n) o4[n] *= sc;
    // pack P via v_cvt_pk_bf16_f32 (1 VALU op per pair vs ~9 manual)
#pragma unroll
    for (int c = 0; c < 4; ++c)
#pragma unroll
      for (int rp = 0; rp < 2; ++rp)
        xw[li * 36 + c * 8 + lg * 2 + rp] = cvt_pk(p[c][2 * rp], p[c][2 * rp + 1]);
    s8v pb0 = *(const s8v*)(xw + li * 36 + lg * 4);
    s8v pb1 = *(const s8v*)(xw + li * 36 + 16 + lg * 4);
#pragma unroll
    for (int n = 0; n < 4; ++n) {
      int dim = n * 16 + li;
      s8v vb0 = *(const s8v*)(Vt + dim * 64 + ((lg ^ (dim & 7)) * 8));
      o4[n] = __builtin_amdgcn_mfma_f32_16x16x32_bf16(vb0, pb0, o4[n], 0, 0, 0);
    }
#pragma unroll
    for (int n = 0; n < 4; ++n) {
      int dim = n * 16 + li;
      s8v vb1 = *(const s8v*)(Vt + dim * 64 + (((lg + 4) ^ (dim & 7)) * 8));
      o4[n] = __builtin_amdgcn_mfma_f32_16x16x32_bf16(vb1, pb1, o4[n], 0, 0, 0);
    }
    __syncthreads();
  }

  if (MODE == 0) {
    // per-wave LDS transpose [q][d] (packed stores), coalesced bf16 out
#pragma unroll
    for (int n = 0; n < 4; ++n)
#pragma unroll
      for (int rp = 0; rp < 2; ++rp)
        xw[li * 36 + n * 8 + lg * 2 + rp] = cvt_pk(o4[n][2 * rp], o4[n][2 * rp + 1]);
    u16* PO = sp ? POb : POa;
    const int pid = (bh * 24 + qb) * 2 + sp;
    int q_local = lane >> 2, d0 = (lane & 3) * 16;
    int q = qb * 64 + w * 16 + q_local;
    s8v v0 = *(const s8v*)(xw16 + q_local * 72 + d0);
    s8v v1 = *(const s8v*)(xw16 + q_local * 72 + d0 + 8);
    if (q < L_) {
      u16* dst = PO + ((size_t)(b * L_ + q)) * DM_ + qoff + d0;
      *(s8v*)dst = v0;
      *(s8v*)(dst + 8) = v1;
    }
    if (lg == 0) {
      PM[pid * 64 + w * 16 + li] = m_run;
      PL[pid * 64 + w * 16 + li] = l_run;
    }
  } else {
    int base = (bh * 8 + sp) * 64 + w * 16 + li;
#pragma unroll
    for (int n = 0; n < 4; ++n)
#pragma unroll
      for (int r = 0; r < 4; ++r)
        POf[(size_t)base * 64 + n * 16 + lg * 4 + r] = o4[n][r];
    if (lg == 0) {
      PM[base] = m_run;
      PL[base] = l_run;
    }
  }
}

// ---------------- combine 2-way cross partials (POb == ctxb, in place) ------
__global__ __launch_bounds__(256) void combine_cross(const u16* __restrict__ PO0,
                                                     const float* __restrict__ PM,
                                                     const float* __restrict__ PL,
                                                     u16* ctxb) {
  int idx = blockIdx.x * 256 + threadIdx.x;
  int row = idx >> 9, col = idx & 511;
  int b = row / L_, q = row - b * L_;
  int h = col >> 6;
  int bh = b * 8 + h, qbk = q >> 6, qi = q & 63;
  int p0 = ((bh * 24 + qbk) * 2) * 64 + qi;
  float m0 = PM[p0], m1 = PM[p0 + 64];
  float l0 = PL[p0], l1 = PL[p0 + 64];
  float M = fmaxf(m0, m1);
  float w0 = __expf(m0 - M), w1 = __expf(m1 - M);
  float inv = 1.f / (w0 * l0 + w1 * l1);
  float o0 = b2f(PO0[idx]);
  float o1 = b2f(ctxb[idx]);
  ctxb[idx] = f2b((w0 * o0 + w1 * o1) * inv);
}

// ---------------- fused combine split-K partials + scatter into ctxb --------
__global__ __launch_bounds__(256) void combine_prob_scatter(
    const float* __restrict__ PO, const float* __restrict__ PM,
    const float* __restrict__ PL, const int* __restrict__ top,
    u16* __restrict__ ctxb) {
  int bh = blockIdx.x;
  int t = threadIdx.x;
  int u = t >> 2, dg = (t & 3) * 16;
  if (u >= SK_) return;
  float M = -INFINITY;
  for (int s = 0; s < 8; ++s) M = fmaxf(M, PM[(bh * 8 + s) * 64 + u]);
  float wgt[8];
  float den = 0.f;
  for (int s = 0; s < 8; ++s) {
    wgt[s] = __expf(PM[(bh * 8 + s) * 64 + u] - M);
    den += wgt[s] * PL[(bh * 8 + s) * 64 + u];
  }
  float inv = 1.f / den;
  int h = bh & 7, b = bh >> 3;
  int l = top[bh * SK_ + u];
  u16* dst = ctxb + ((size_t)(b * L_ + l)) * DM_ + h * 64;
  for (int d = dg; d < dg + 16; ++d) {
    float acc = 0.f;
    for (int s = 0; s < 8; ++s) acc += wgt[s] * PO[(((size_t)bh * 8 + s) * 64 + u) * 64 + d];
    dst[d] = f2b(acc * inv);
  }
}

// ---------------- V mean partials (8 per bh), swizzled ----------------------
__global__ __launch_bounds__(256) void vmean_part(const u16* __restrict__ qkv,
                                                  float* __restrict__ part) {
  int g = xswz(blockIdx.x, (B_ * H_ * 8) >> 3);
  int bh = g >> 3, seg = g & 7;
  int h = bh & 7, b = bh >> 3;
  int lane = threadIdx.x & 63, grp = threadIdx.x >> 6;
  int k0 = seg * 190, k1 = k0 + 190;
  float acc = 0.f;
  for (int k = k0 + grp; k < k1; k += 4)
    acc += b2f(qkv[((size_t)b * L_ + k) * 1536 + 1024 + h * 64 + lane]);
  __shared__ float pv[4][64];
  pv[grp][lane] = acc;
  __syncthreads();
  if (threadIdx.x < 64)
    part[g * 64 + threadIdx.x] =
        pv[0][threadIdx.x] + pv[1][threadIdx.x] + pv[2][threadIdx.x] + pv[3][threadIdx.x];
}

// ---------------- ctx = broadcast vmean (combines partials inline) ----------
__global__ __launch_bounds__(256) void fill_ctx(const float* __restrict__ part,
                                                u16* __restrict__ ctxb) {
  int idx = blockIdx.x * 256 + threadIdx.x;
  int d = idx % 64;
  int h = (idx / 64) % H_;
  int b = idx / (L_ * DM_);
  int bh = b * 8 + h;
  float s = 0.f;
#pragma unroll
  for (int seg = 0; seg < 8; ++seg) s += part[(bh * 8 + seg) * 64 + d];
  ctxb[idx] = f2b(s * (1.f / (float)L_));
}

// ---------------- host side --------------------------------------------------
extern "C" void kernel_launch(void* const* d_in, const int* in_sizes, int n_in,
                              void* d_out, int out_size, void* d_ws, size_t ws_size,
                              hipStream_t stream) {
  const float* inflow   = (const float*)d_in[4];
  const float* W_emb_e  = (const float*)d_in[5];
  const float* b_emb_e  = (const float*)d_in[6];
  const float* W_emb_d  = (const float*)d_in[7];
  const float* b_emb_d  = (const float*)d_in[8];
  const float* enc_Wqkv = (const float*)d_in[9];
  const float* enc_bqkv = (const float*)d_in[10];
  const float* enc_Wo   = (const float*)d_in[11];
  const float* enc_bo   = (const float*)d_in[12];
  const float* enc_ln1g = (const float*)d_in[13];
  const float* enc_ln1b = (const float*)d_in[14];
  const float* enc_Wf1  = (const float*)d_in[15];
  const float* enc_bf1  = (const float*)d_in[16];
  const float* enc_Wf2  = (const float*)d_in[17];
  const float* enc_bf2  = (const float*)d_in[18];
  const float* enc_ln2g = (const float*)d_in[19];
  const float* enc_ln2b = (const float*)d_in[20];
  const float* enc_ng   = (const float*)d_in[21];
  const float* enc_nb   = (const float*)d_in[22];
  const float* dec_Wqkv = (const float*)d_in[23];
  const float* dec_bqkv = (const float*)d_in[24];
  const float* dec_Wo_s = (const float*)d_in[25];
  const float* dec_bo_s = (const float*)d_in[26];
  const float* dec_ln1g = (const float*)d_in[27];
  const float* dec_ln1b = (const float*)d_in[28];
  const float* dec_Wq_c = (const float*)d_in[29];
  const float* dec_bq_c = (const float*)d_in[30];
  const float* dec_Wkv  = (const float*)d_in[31];
  const float* dec_bkv  = (const float*)d_in[32];
  const float* dec_Wo_c = (const float*)d_in[33];
  const float* dec_bo_c = (const float*)d_in[34];
  const float* dec_ln2g = (const float*)d_in[35];
  const float* dec_ln2b = (const float*)d_in[36];
  const float* dec_Wf1  = (const float*)d_in[37];
  const float* dec_bf1  = (const float*)d_in[38];
  const float* dec_Wf2  = (const float*)d_in[39];
  const float* dec_bf2  = (const float*)d_in[40];
  const float* dec_ln3g = (const float*)d_in[41];
  const float* dec_ln3b = (const float*)d_in[42];
  const float* W_proj   = (const float*)d_in[43];
  const float* b_proj   = (const float*)d_in[44];
  const float* W1       = (const float*)d_in[45];
  const float* b1       = (const float*)d_in[46];
  const float* W3       = (const float*)d_in[47];
  const float* b3       = (const float*)d_in[48];
  const int*   samp     = (const int*)d_in[49];
  float* out = (float*)d_out;

  float* ws  = (float*)d_ws;
  float* PE  = ws;                       // 778240 f (dead after embeds -> PMc/PLc)
  float* X   = PE + 778240;              // 72960 f
  float* ACT = X + 72960;                // 3112960 f
  float* REG = ACT + 3112960;            // 6291456 f shared region
  float* MME = REG + 6291456;            // 48640 f (VME8 overlay after topk)
  float* CTT = MME + 48640;              // 81920 f (unused scratch)
  float* VME = CTT + 81920;              // 2048 f (unused)
  int*   TOP = (int*)(VME + 2048);       // 1280 i
  float* TAIL = VME + 2048 + 1280;
  u16* ENCb = (u16*)TAIL;                       // 6144*512 u16
  u16* DECb = (u16*)(TAIL + 1572864);
  u16* CTXb = (u16*)(TAIL + 2 * 1572864);
  u16* WBF  = (u16*)(TAIL + 3 * 1572864);       // 10485760 u16
  // prob split-K partials: FRESH memory after WBF (NO overlap with CTXb —
  // fill_ctx runs before combine_prob_scatter and would clobber an overlay)
  float* POp = (float*)(WBF + 10485760);        // 1048576 f
  float* PMp = POp + 1048576;                   // 16384 f
  float* PLp = PMp + 16384;                     // 16384 f

  // region overlays (prob phase)
  u16* QKVb = (u16*)REG;                 // [6144][1536]
  u16* FFb  = (u16*)REG;                 // [6144][2048]
  u16* VT   = (u16*)REG + 9437184;       // [32][64][1536] u16
  // region overlays (cross phase)
  u16* QCb  = (u16*)REG;                 // [6144][512]
  u16* Kc   = (u16*)REG + 3145728;       // [6144][512]
  u16* Vc   = (u16*)REG + 6291456;       // [6144][512]; becomes PO-split0 after transpose
  // cross partial stats in dead PE region (32*24*2*64 = 98304 each)
  float* PMc = PE;
  float* PLc = PE + 98304;
  float* VME8 = MME;                     // 16384 f (after radix_topk)

  auto GB = [&](const u16* A, const u16* Bt, const float* bias, const float* res,
                float* Cf, u16* Cb, int N, int K, int act) {
    if (N <= 512) {
      dim3 g(N / 128, MP_ / 64);
      gemm_bf16<64><<<g, 256, 0, stream>>>(A, Bt, bias, res, Cf, Cb, N, K, act);
    } else {
      dim3 g(N / 128, MP_ / 128);
      gemm_bf16<128><<<g, 256, 0, stream>>>(A, Bt, bias, res, Cf, Cb, N, K, act);
    }
  };
  auto PROB = [&](const int* sidx) {
    probM<<<B_ * H_ * L_ / 4, 256, 0, stream>>>(QKVb, sidx, MME);
    radix_topk<<<B_ * H_, 256, 0, stream>>>(MME, TOP);
    transpose_v<<<B_ * H_ * 24, 256, 0, stream>>>(QKVb, 1536, 1024, VT);
    flash_attn<1><<<B_ * H_ * 8, 256, 0, stream>>>(QKVb, QKVb, VT, TOP, POp,
                                                   nullptr, nullptr, PMp, PLp);
    vmean_part<<<B_ * H_ * 8, 256, 0, stream>>>(QKVb, VME8);
    fill_ctx<<<ML_ * DM_ / 256, 256, 0, stream>>>(VME8, CTXb);
    combine_prob_scatter<<<B_ * H_, 256, 0, stream>>>(POp, PMp, PLp, TOP, CTXb);
  };

  pe_kernel<<<(L_ * DM_ + 255) / 256, 256, 0, stream>>>(PE);
  extract_x<<<(ML_ * 12 + 255) / 256, 256, 0, stream>>>(inflow, X);

  // one fused weight-conversion dispatch (LDS tiled transpose)
  {
    CvtArgs a;
    const float* s[15] = {
      enc_Wqkv, enc_Wqkv + 512 * 1536, enc_Wo, enc_Wo + 512 * 512,
      enc_Wf1, enc_Wf1 + 512 * 2048, enc_Wf2, enc_Wf2 + 2048 * 512,
      dec_Wqkv, dec_Wo_s, dec_Wq_c, dec_Wkv, dec_Wo_c, dec_Wf1, dec_Wf2 };
    unsigned cumt[16] = { 0u, 768u, 1536u, 1792u, 2048u, 3072u,
                          4096u, 5120u, 6144u, 6912u, 7168u,
                          7424u, 7936u, 8192u, 9216u, 10240u };
    unsigned lk[15] = { 9, 9, 9, 9, 9, 9, 11, 11, 9, 9, 9, 9, 9, 9, 11 };
    for (int i = 0; i < 15; ++i) { a.src[i] = s[i]; a.lk[i] = lk[i]; }
    for (int i = 0; i < 16; ++i) a.cumt[i] = cumt[i];
    cvt_all<<<10240, 256, 0, stream>>>(a, WBF);
  }
  u16* Wt_qkv_e0 = WBF + 0;
  u16* Wt_qkv_e1 = WBF + 786432;
  u16* Wt_o_e0   = WBF + 1572864;
  u16* Wt_o_e1   = WBF + 1835008;
  u16* Wt_f1_e0  = WBF + 2097152;
  u16* Wt_f1_e1  = WBF + 3145728;
  u16* Wt_f2_e0  = WBF + 4194304;
  u16* Wt_f2_e1  = WBF + 5242880;
  u16* Wt_qkv_d  = WBF + 6291456;
  u16* Wt_o_s    = WBF + 7077888;
  u16* Wt_q_c    = WBF + 7340032;
  u16* Wt_kv_c   = WBF + 7602176;
  u16* Wt_o_c    = WBF + 8126464;
  u16* Wt_f1_d   = WBF + 8388608;
  u16* Wt_f2_d   = WBF + 9437184;

  // ---------------- encoder ----------------
  embed_fused<<<MP_ / 4, 256, 0, stream>>>(X, W_emb_e, b_emb_e, PE, ACT, ENCb);

  const u16* Wqkv_e[2] = {Wt_qkv_e0, Wt_qkv_e1};
  const u16* Wo_e[2]   = {Wt_o_e0, Wt_o_e1};
  const u16* Wf1_e[2]  = {Wt_f1_e0, Wt_f1_e1};
  const u16* Wf2_e[2]  = {Wt_f2_e0, Wt_f2_e1};
  for (int i = 0; i < 2; ++i) {
    GB(ENCb, Wqkv_e[i], enc_bqkv + i * 1536, nullptr, nullptr, QKVb, 1536, 512, 0);
    PROB(samp + (size_t)i * L_ * SK_);
    GB(CTXb, Wo_e[i], enc_bo + i * 512, ACT, ACT, nullptr, 512, 512, 0);
    layernorm_ip<<<ML_ / 4, 256, 0, stream>>>(ACT, enc_ln1g + i * 512, enc_ln1b + i * 512, ENCb);
    GB(ENCb, Wf1_e[i], enc_bf1 + i * 2048, nullptr, nullptr, FFb, 2048, 512, 1);
    GB(FFb, Wf2_e[i], enc_bf2 + i * 512, ACT, ACT, nullptr, 512, 2048, 0);
    layernorm_ip<<<ML_ / 4, 256, 0, stream>>>(ACT, enc_ln2g + i * 512, enc_ln2b + i * 512, ENCb);
  }
  layernorm_ip<<<ML_ / 4, 256, 0, stream>>>(ACT, enc_ng, enc_nb, ENCb);

  // ---------------- decoder ----------------
  embed_fused<<<MP_ / 4, 256, 0, stream>>>(X, W_emb_d, b_emb_d, PE, ACT, DECb);
  GB(DECb, Wt_qkv_d, dec_bqkv, nullptr, nullptr, QKVb, 1536, 512, 0);
  PROB(samp + (size_t)2 * L_ * SK_);
  GB(CTXb, Wt_o_s, dec_bo_s, ACT, ACT, nullptr, 512, 512, 0);
  layernorm_ip<<<ML_ / 4, 256, 0, stream>>>(ACT, dec_ln1g, dec_ln1b, DECb);

  // cross attention: Q, K, V as separate [*,512] GEMMs; V buffer becomes split-0
  GB(DECb, Wt_q_c, dec_bq_c, nullptr, nullptr, QCb, 512, 512, 0);
  GB(ENCb, Wt_kv_c, dec_bkv, nullptr, nullptr, Kc, 512, 512, 0);
  GB(ENCb, Wt_kv_c + 512 * 512, dec_bkv + 512, nullptr, nullptr, Vc, 512, 512, 0);
  transpose_v<<<B_ * H_ * 24, 256, 0, stream>>>(Vc, 512, 0, VT);
  flash_attn<0><<<B_ * H_ * 48, 256, 0, stream>>>(QCb, Kc, VT, nullptr, nullptr,
                                                  Vc, CTXb, PMc, PLc);
  combine_cross<<<ML_ * DM_ / 256, 256, 0, stream>>>(Vc, PMc, PLc, CTXb);
  GB(CTXb, Wt_o_c, dec_bo_c, ACT, ACT, nullptr, 512, 512, 0);
  layernorm_ip<<<ML_ / 4, 256, 0, stream>>>(ACT, dec_ln2g, dec_ln2b, DECb);

  GB(DECb, Wt_f1_d, dec_bf1, nullptr, nullptr, FFb, 2048, 512, 1);
  GB(FFb, Wt_f2_d, dec_bf2, ACT, ACT, nullptr, 512, 2048, 0);
  layernorm_ip<<<ML_ / 4, 256, 0, stream>>>(ACT, dec_ln3g, dec_ln3b, DECb);

  // fused head
  head_fused<<<ML_ / 4, 256, 0, stream>>>(ACT, X, W_proj, b_proj, W1, b1, W3, b3, out);
}

// Round 15
// 859.753 us; speedup vs baseline: 1.2156x; 1.0112x over previous
//
#include <hip/hip_runtime.h>
#include <math.h>

#define B_ 4
#define H_ 8
#define L_ 1520
#define DM_ 512
#define DFF_ 2048
#define SK_ 40
#define ML_ (B_*L_)   /* 6080 rows */
#define MP_ 6144      /* padded rows for MFMA GEMM */
#define LP_ 1536      /* padded key count for V^T */

typedef unsigned short u16;
typedef short s8v __attribute__((ext_vector_type(8)));
typedef float f4 __attribute__((ext_vector_type(4)));

__device__ __forceinline__ u16 f2b(float x) {
  union { float f; unsigned u; } c; c.f = x;
  unsigned r = c.u + 0x7FFFu + ((c.u >> 16) & 1u);
  return (u16)(r >> 16);
}
__device__ __forceinline__ float b2f(u16 h) {
  union { unsigned u; float f; } c; c.u = ((unsigned)h) << 16;
  return c.f;
}
// packed f32 pair -> 2x bf16 in one u32 (lo = a, hi = b); single VALU op
__device__ __forceinline__ unsigned cvt_pk(float a, float b) {
  unsigned r;
  asm volatile("v_cvt_pk_bf16_f32 %0, %1, %2" : "=v"(r) : "v"(a), "v"(b));
  return r;
}
__device__ __forceinline__ float gelu_tanh(float x) {
  float x3 = x * x * x;
  return 0.5f * x * (1.f + tanhf(0.79788456080286536f * (x + 0.044715f * x3)));
}
// XCD-chunked bijective swizzle; requires nwg % 8 == 0 (cpx = nwg/8).
__device__ __forceinline__ int xswz(int bid, int cpx) {
  return (bid & 7) * cpx + (bid >> 3);
}

// ---------------- positional encoding (double precision to match numpy) ----
__global__ __launch_bounds__(256) void pe_kernel(float* __restrict__ pe) {
  int idx = blockIdx.x * 256 + threadIdx.x;
  if (idx >= L_ * DM_) return;
  int pos = idx / DM_, i = idx % DM_;
  double expo = (double)(2 * (i / 2)) / (double)DM_;
  double ang = (double)pos / pow(10000.0, expo);
  pe[idx] = (i & 1) ? (float)cos(ang) : (float)sin(ang);
}

// ---------------- x = inflow[:,2:14].reshape (contiguous slice) -------------
__global__ __launch_bounds__(256) void extract_x(const float* __restrict__ inflow,
                                                 float* __restrict__ X) {
  int idx = blockIdx.x * 256 + threadIdx.x;
  if (idx >= ML_ * 12) return;
  int b = idx / (L_ * 12);
  int rem = idx - b * (L_ * 12);
  X[idx] = inflow[(size_t)b * 14 * L_ + 2 * L_ + rem];
}

// ---------------- fused weight convert+transpose (LDS tiled, coalesced) -----
struct CvtArgs {
  const float* src[15];
  unsigned cumt[16];   // cumulative 32x32-tile counts
  unsigned lk[15];     // log2(K) per segment
};
__global__ __launch_bounds__(256) void cvt_all(CvtArgs a, u16* __restrict__ dst) {
  __shared__ float tl[32][33];
  int bt = blockIdx.x;                 // grid exact: 10240 tiles
  int s = 0;
#pragma unroll
  for (int i = 1; i < 15; ++i) s += (bt >= (int)a.cumt[i]);
  int lt = bt - a.cumt[s];
  unsigned lk = a.lk[s];
  unsigned K = 1u << lk;
  unsigned N = ((a.cumt[s + 1] - a.cumt[s]) << 10) >> lk;
  unsigned tiles_n = N >> 5;
  unsigned k0 = (lt / tiles_n) * 32, n0 = (lt % tiles_n) * 32;
  const float* src = a.src[s];
  int r = threadIdx.x >> 5, c = threadIdx.x & 31;
#pragma unroll
  for (int i = 0; i < 4; ++i)
    tl[r + 8 * i][c] = src[(size_t)(k0 + r + 8 * i) * N + n0 + c];
  __syncthreads();
  u16* d = dst + ((size_t)a.cumt[s] << 10);
#pragma unroll
  for (int i = 0; i < 4; ++i)
    d[(size_t)(n0 + r + 8 * i) * K + k0 + c] = f2b(tl[c][r + 8 * i]);
}

// ---------------- fused embed: ACT = X@W + b + PE ; ACTb = bf16(ACT) --------
__global__ __launch_bounds__(256) void embed_fused(
    const float* __restrict__ X, const float* __restrict__ W,
    const float* __restrict__ bias, const float* __restrict__ PE,
    float* __restrict__ ACT, u16* __restrict__ ACTb) {
  int row = blockIdx.x * 4 + (threadIdx.x >> 6);
  int lane = threadIdx.x & 63;
  int d0 = lane * 8;
  if (row >= ML_) {
    s8v z = {0, 0, 0, 0, 0, 0, 0, 0};
    *(s8v*)(ACTb + (size_t)row * DM_ + d0) = z;
    return;
  }
  int prow = row % L_;
  f4 a0 = *(const f4*)(bias + d0);
  f4 a1 = *(const f4*)(bias + d0 + 4);
  a0 += *(const f4*)(PE + (size_t)prow * DM_ + d0);
  a1 += *(const f4*)(PE + (size_t)prow * DM_ + d0 + 4);
  const float* xr = X + (size_t)row * 12;
#pragma unroll
  for (int t = 0; t < 12; ++t) {
    float xv = xr[t];
    a0 += xv * *(const f4*)(W + (size_t)t * DM_ + d0);
    a1 += xv * *(const f4*)(W + (size_t)t * DM_ + d0 + 4);
  }
  float* dst = ACT + (size_t)row * DM_ + d0;
  *(f4*)dst = a0;
  *(f4*)(dst + 4) = a1;
  unsigned ob[4];
  ob[0] = cvt_pk(a0[0], a0[1]); ob[1] = cvt_pk(a0[2], a0[3]);
  ob[2] = cvt_pk(a1[0], a1[1]); ob[3] = cvt_pk(a1[2], a1[3]);
  *(s8v*)(ACTb + (size_t)row * DM_ + d0) = *(s8v*)ob;
}

// ---------------- fused head: out = relu((DEC@Wp+bp+X)@W1+b1)@W3+b3 ---------
__global__ __launch_bounds__(256) void head_fused(
    const float* __restrict__ DEC, const float* __restrict__ X,
    const float* __restrict__ Wp, const float* __restrict__ bp,
    const float* __restrict__ W1, const float* __restrict__ b1,
    const float* __restrict__ W3, const float* __restrict__ b3,
    float* __restrict__ out) {
  int row = blockIdx.x * 4 + (threadIdx.x >> 6);
  int lane = threadIdx.x & 63;
  int d0 = lane * 8;
  const float* dec = DEC + (size_t)row * DM_ + d0;
  f4 v0 = *(const f4*)dec;
  f4 v1 = *(const f4*)(dec + 4);
  float pj[12];
#pragma unroll
  for (int j = 0; j < 12; ++j) pj[j] = 0.f;
#pragma unroll
  for (int i = 0; i < 8; ++i) {
    float dv = (i < 4) ? v0[i] : v1[i - 4];
    const float* wr = Wp + (size_t)(d0 + i) * 12;
#pragma unroll
    for (int j = 0; j < 12; ++j) pj[j] += dv * wr[j];
  }
  for (int off = 32; off; off >>= 1) {
#pragma unroll
    for (int j = 0; j < 12; ++j) pj[j] += __shfl_xor(pj[j], off);
  }
  float o12[12];
#pragma unroll
  for (int j = 0; j < 12; ++j) o12[j] = pj[j] + bp[j] + X[(size_t)row * 12 + j];
  int k0 = lane * 2;
  float h0 = b1[k0], h1 = b1[k0 + 1];
#pragma unroll
  for (int j = 0; j < 12; ++j) {
    h0 += o12[j] * W1[j * 128 + k0];
    h1 += o12[j] * W1[j * 128 + k0 + 1];
  }
  h0 = fmaxf(h0, 0.f);
  h1 = fmaxf(h1, 0.f);
  float op[3];
#pragma unroll
  for (int p = 0; p < 3; ++p)
    op[p] = h0 * W3[k0 * 3 + p] + h1 * W3[(k0 + 1) * 3 + p];
  for (int off = 32; off; off >>= 1) {
#pragma unroll
    for (int p = 0; p < 3; ++p) op[p] += __shfl_xor(op[p], off);
  }
  if (lane == 0) {
#pragma unroll
    for (int p = 0; p < 3; ++p) out[(size_t)row * 3 + p] = op[p] + b3[p];
  }
}

// ---------------- bf16 MFMA GEMM, single-buffered, XCD-swizzled -------------
template<int BM>
__global__ __launch_bounds__(256) void gemm_bf16(
    const u16* __restrict__ A, const u16* __restrict__ Bt,
    const float* __restrict__ bias, const float* __restrict__ res,
    float* __restrict__ Cf, u16* __restrict__ Cb,
    int N, int K, int act) {
  __shared__ __align__(16) u16 As[BM * 32];
  __shared__ __align__(16) u16 Bs[128 * 32];
  constexpr int MI = BM / 32;
  const int nwg = gridDim.x * gridDim.y;
  const int lin = blockIdx.y * gridDim.x + blockIdx.x;
  const int o = xswz(lin, nwg >> 3);
  const int bxi = o % gridDim.x, byi = o / gridDim.x;
  const int t = threadIdx.x, w = t >> 6, lane = t & 63;
  const int lg = lane >> 4, li = lane & 15;
  const int bm = byi * BM, bn = bxi * 128;
  const int wr = (w >> 1) * (BM / 2), wc = (w & 1) * 64;
  f4 acc[MI][4];
#pragma unroll
  for (int i = 0; i < MI; ++i)
#pragma unroll
    for (int j = 0; j < 4; ++j) acc[i][j] = f4{0.f, 0.f, 0.f, 0.f};
  const int rB = w * 32 + (lane >> 2);
  const int rA = (BM == 128) ? rB : (w * 16 + (lane >> 2));
  const int ps = lane & 3;
  for (int k0 = 0; k0 < K; k0 += 32) {
    if (BM == 128) {
#pragma unroll
      for (int j = 0; j < 2; ++j) {
        int r = rA + j * 16;
        int ls = ps ^ ((r >> 1) & 3);
        __builtin_amdgcn_global_load_lds(
            (const __attribute__((address_space(1))) void*)(A + (size_t)(bm + r) * K + k0 + ls * 8),
            (__attribute__((address_space(3))) void*)(As + (w * 32 + j * 16) * 32),
            16, 0, 0);
      }
    } else {
      int ls = ps ^ ((rA >> 1) & 3);
      __builtin_amdgcn_global_load_lds(
          (const __attribute__((address_space(1))) void*)(A + (size_t)(bm + rA) * K + k0 + ls * 8),
          (__attribute__((address_space(3))) void*)(As + (w * 16) * 32),
          16, 0, 0);
    }
#pragma unroll
    for (int j = 0; j < 2; ++j) {
      int r = rB + j * 16;
      int ls = ps ^ ((r >> 1) & 3);
      __builtin_amdgcn_global_load_lds(
          (const __attribute__((address_space(1))) void*)(Bt + (size_t)(bn + r) * K + k0 + ls * 8),
          (__attribute__((address_space(3))) void*)(Bs + (w * 32 + j * 16) * 32),
          16, 0, 0);
    }
    __syncthreads();
    s8v af[MI], bf[4];
#pragma unroll
    for (int f = 0; f < MI; ++f) {
      int ra = wr + f * 16 + li;
      af[f] = *(const s8v*)(As + ra * 32 + ((lg ^ ((ra >> 1) & 3)) * 8));
    }
#pragma unroll
    for (int f = 0; f < 4; ++f) {
      int rb = wc + f * 16 + li;
      bf[f] = *(const s8v*)(Bs + rb * 32 + ((lg ^ ((rb >> 1) & 3)) * 8));
    }
#pragma unroll
    for (int fi = 0; fi < MI; ++fi)
#pragma unroll
      for (int fj = 0; fj < 4; ++fj)
        acc[fi][fj] = __builtin_amdgcn_mfma_f32_16x16x32_bf16(af[fi], bf[fj], acc[fi][fj], 0, 0, 0);
    __syncthreads();
  }
#pragma unroll
  for (int fi = 0; fi < MI; ++fi)
#pragma unroll
    for (int fj = 0; fj < 4; ++fj)
#pragma unroll
      for (int r = 0; r < 4; ++r) {
        int row = bm + wr + fi * 16 + lg * 4 + r;
        int col = bn + wc + fj * 16 + li;
        float v = acc[fi][fj][r] + bias[col];
        if (res && row < ML_) v += res[(size_t)row * N + col];
        if (act == 1) v = gelu_tanh(v);
        if (Cf && row < ML_) Cf[(size_t)row * N + col] = v;
        if (Cb) Cb[(size_t)row * N + col] = f2b(v);
      }
}

// ---------------- layernorm: wave per row, vectorized -----------------------
__global__ __launch_bounds__(256) void layernorm_ip(float* __restrict__ Xb,
                                                    const float* __restrict__ g,
                                                    const float* __restrict__ bta,
                                                    u16* __restrict__ outb) {
  int row = blockIdx.x * 4 + (threadIdx.x >> 6);
  int lane = threadIdx.x & 63;
  float* x = Xb + (size_t)row * DM_;
  f4 a = *(f4*)(x + lane * 8);
  f4 b = *(f4*)(x + lane * 8 + 4);
  float s = a[0] + a[1] + a[2] + a[3] + b[0] + b[1] + b[2] + b[3];
  for (int off = 32; off; off >>= 1) s += __shfl_xor(s, off);
  float mu = s * (1.f / 512.f);
  float vs = 0.f;
#pragma unroll
  for (int i = 0; i < 4; ++i) { a[i] -= mu; b[i] -= mu; vs += a[i] * a[i] + b[i] * b[i]; }
  for (int off = 32; off; off >>= 1) vs += __shfl_xor(vs, off);
  float rs = rsqrtf(vs * (1.f / 512.f) + 1e-5f);
  f4 g0 = *(const f4*)(g + lane * 8), g1 = *(const f4*)(g + lane * 8 + 4);
  f4 c0 = *(const f4*)(bta + lane * 8), c1 = *(const f4*)(bta + lane * 8 + 4);
  float r0 = a[0] * rs * g0[0] + c0[0];
  float r1 = a[1] * rs * g0[1] + c0[1];
  float r2 = a[2] * rs * g0[2] + c0[2];
  float r3 = a[3] * rs * g0[3] + c0[3];
  float r4 = b[0] * rs * g1[0] + c1[0];
  float r5 = b[1] * rs * g1[1] + c1[1];
  float r6 = b[2] * rs * g1[2] + c1[2];
  float r7 = b[3] * rs * g1[3] + c1[3];
  x[lane * 8 + 0] = r0; x[lane * 8 + 1] = r1; x[lane * 8 + 2] = r2; x[lane * 8 + 3] = r3;
  x[lane * 8 + 4] = r4; x[lane * 8 + 5] = r5; x[lane * 8 + 6] = r6; x[lane * 8 + 7] = r7;
  unsigned ob[4];
  ob[0] = cvt_pk(r0, r1); ob[1] = cvt_pk(r2, r3);
  ob[2] = cvt_pk(r4, r5); ob[3] = cvt_pk(r6, r7);
  *(s8v*)(outb + (size_t)row * DM_ + lane * 8) = *(s8v*)ob;
}

// ---------------- ProbSparse sparsity measure M (bf16 qkv), swizzled --------
__global__ __launch_bounds__(256) void probM(const u16* __restrict__ qkv,
                                             const int* __restrict__ sidx,
                                             float* __restrict__ Mout) {
  int wid = threadIdx.x / 64, lane = threadIdx.x % 64;
  int o = xswz(blockIdx.x, (B_ * H_ * L_ / 4) >> 3);
  int g = o * 4 + wid;
  int l = g % L_;
  int bh = g / L_;
  int h = bh % H_, b = bh / H_;
  __shared__ float qs[4][64];
  qs[wid][lane] = b2f(qkv[((size_t)b * L_ + l) * 1536 + h * 64 + lane]);
  __syncthreads();
  float dot = 0.f;
  if (lane < SK_) {
    int ks = sidx[l * SK_ + lane];
    const u16* kr = qkv + ((size_t)b * L_ + ks) * 1536 + 512 + h * 64;
#pragma unroll
    for (int j = 0; j < 8; ++j) {
      s8v v = *(const s8v*)(kr + j * 8);
#pragma unroll
      for (int i = 0; i < 8; ++i) dot += qs[wid][j * 8 + i] * b2f((u16)v[i]);
    }
  }
  float vmax = (lane < SK_) ? dot : -INFINITY;
  float vsum = (lane < SK_) ? dot : 0.f;
  for (int off = 32; off; off >>= 1) {
    vmax = fmaxf(vmax, __shfl_xor(vmax, off));
    vsum += __shfl_xor(vsum, off);
  }
  if (lane == 0) Mout[g] = vmax - vsum / (float)L_;
}

// ---------------- radix-select top-40 (matches lax.top_k selection set) -----
__global__ __launch_bounds__(256) void radix_topk(const float* __restrict__ Mv,
                                                  int* __restrict__ top) {
  const int bh = blockIdx.x;
  const int t = threadIdx.x;
  const int base = t * 6;
  unsigned key[6];
#pragma unroll
  for (int i = 0; i < 6; ++i) {
    int ix = base + i;
    unsigned k = 0u;
    if (ix < L_) {
      union { float f; unsigned u; } c; c.f = Mv[(size_t)bh * L_ + ix];
      k = c.u ^ ((c.u & 0x80000000u) ? 0xFFFFFFFFu : 0x80000000u);
    }
    key[i] = k;
  }
  __shared__ int wred[4];
  __shared__ int s_a[256], s_b[256];
  unsigned prefix = 0u;
  for (int b = 31; b >= 0; --b) {
    unsigned cand = prefix | (1u << b);
    int c = 0;
#pragma unroll
    for (int i = 0; i < 6; ++i) c += (key[i] >= cand);
    for (int off = 32; off; off >>= 1) c += __shfl_xor(c, off);
    if ((t & 63) == 0) wred[t >> 6] = c;
    __syncthreads();
    int tot = wred[0] + wred[1] + wred[2] + wred[3];
    if (tot >= SK_) prefix = cand;
    __syncthreads();
  }
  const unsigned T = prefix;
  int gt = 0, tie = 0;
#pragma unroll
  for (int i = 0; i < 6; ++i) { gt += (key[i] > T); tie += (key[i] == T); }
  s_a[t] = gt; s_b[t] = tie;
  __syncthreads();
  for (int off = 1; off < 256; off <<= 1) {
    int va = (t >= off) ? s_a[t - off] : 0;
    int vb = (t >= off) ? s_b[t - off] : 0;
    __syncthreads();
    s_a[t] += va; s_b[t] += vb;
    __syncthreads();
  }
  const int n_strict = s_a[255];
  const int gt_base = s_a[t] - gt;
  const int tie_base = s_b[t] - tie;
  const int need = SK_ - n_strict;
  int lgt = 0, ltie = 0;
#pragma unroll
  for (int i = 0; i < 6; ++i) {
    int ix = base + i;
    if (key[i] > T) {
      top[bh * SK_ + gt_base + lgt] = ix; ++lgt;
    } else if (key[i] == T) {
      int r = tie_base + ltie; ++ltie;
      if (r < need) top[bh * SK_ + n_strict + r] = ix;
    }
  }
}

// ---------------- V^T build + fused per-tile V column sums ------------------
// VT[bh][64][LP_]; vpart[bh][24][64] partial sums over this tile's keys
// (vpart may be nullptr for the cross path).
__global__ __launch_bounds__(256) void transpose_v(const u16* __restrict__ src,
                                                   int stride, int voff0,
                                                   u16* __restrict__ VT,
                                                   float* __restrict__ vpart) {
  int o = xswz(blockIdx.x, (B_ * H_ * 24) >> 3);
  int kt = o % 24, bh = o / 24;
  int h = bh & 7, b = bh >> 3;
  int kb = kt * 64;
  __shared__ u16 tile[64][72];
  int t = threadIdx.x;
#pragma unroll
  for (int rr = 0; rr < 2; ++rr) {
    int slot = rr * 256 + t;
    int key = slot >> 3, d = (slot & 7) * 8;
    int gk = kb + key; if (gk >= L_) gk = L_ - 1;
    s8v v = *(const s8v*)(src + (size_t)(b * L_ + gk) * stride + voff0 + h * 64 + d);
    *(s8v*)(&tile[key][d]) = v;
  }
  __syncthreads();
  int dim = t >> 2, k0 = (t & 3) * 16;
  u16 buf[16];
  float psum = 0.f;
#pragma unroll
  for (int i = 0; i < 16; ++i) {
    int key = k0 + i;
    buf[i] = (kb + key < L_) ? tile[key][dim] : (u16)0;
    psum += b2f(buf[i]);
  }
  *(s8v*)(VT + ((size_t)bh * 64 + dim) * LP_ + kb + k0) = *(s8v*)buf;
  *(s8v*)(VT + ((size_t)bh * 64 + dim) * LP_ + kb + k0 + 8) = *(s8v*)(buf + 8);
  if (vpart) {
    psum += __shfl_xor(psum, 1);
    psum += __shfl_xor(psum, 2);
    if ((t & 3) == 0) vpart[((size_t)bh * 24 + kt) * 64 + dim] = psum;
  }
}

// ---------------- LDS-staged swapped-operand MFMA flash attention -----------
template<int MODE>
__global__ __launch_bounds__(256) void flash_attn(
    const u16* __restrict__ Qm, const u16* __restrict__ Kg,
    const u16* __restrict__ VT, const int* __restrict__ top,
    float* __restrict__ POf, u16* POa, u16* POb,
    float* __restrict__ PM, float* __restrict__ PL) {
  constexpr int QSTR = (MODE == 0) ? 512 : 1536;
  constexpr int KSTR = (MODE == 0) ? 1024 : 1536;
  constexpr int TILES = (MODE == 0) ? 12 : 3;
  constexpr int NB = (MODE == 0) ? 48 : 8;
  __shared__ __align__(16) u16 Kt[64 * 64];        // [key][slot^(key&7)]
  __shared__ __align__(16) u16 Vt[64 * 64];        // [dim][slot^(dim&7)]
  __shared__ __align__(16) unsigned Xch[4][576];   // per-wave P exchange
  const int o = xswz(blockIdx.x, (B_ * H_ * NB) >> 3);
  int bh, sp, qb;
  if (MODE == 0) {
    bh = o / 48; int rem = o % 48; qb = rem >> 1; sp = rem & 1;
  } else {
    bh = o / 8; sp = o % 8; qb = 0;
  }
  const int h = bh & 7, b = bh >> 3;
  const int qoff = h * 64;
  const int koff = ((MODE == 0) ? 0 : 512) + h * 64;
  const int t = threadIdx.x, w = t >> 6, lane = t & 63;
  const int lg = lane >> 4, li = lane & 15;
  const u16* vtg = VT + (size_t)bh * 64 * LP_;
  unsigned* xw = Xch[w];
  u16* xw16 = (u16*)xw;

  int qrow;
  if (MODE == 0) {
    int q = qb * 64 + w * 16 + li;
    qrow = b * L_ + ((q < L_) ? q : (L_ - 1));
  } else {
    int u = w * 16 + li; if (u >= SK_) u = SK_ - 1;
    qrow = b * L_ + top[bh * SK_ + u];
  }
  s8v qf0 = *(const s8v*)(Qm + (size_t)qrow * QSTR + qoff + lg * 8);
  s8v qf1 = *(const s8v*)(Qm + (size_t)qrow * QSTR + qoff + 32 + lg * 8);

  f4 o4[4];                          // o4[n][r] = O^T[d=n*16+lg*4+r][q=li]
#pragma unroll
  for (int n = 0; n < 4; ++n) o4[n] = f4{0.f, 0.f, 0.f, 0.f};
  float m_run = -INFINITY, l_run = 0.f;   // per-lane (q=li)
  const int kt0 = sp * TILES;
  const int skey = lane >> 3;
  const int sslot = lane & 7;

#pragma unroll 1
  for (int ki = 0; ki < TILES; ++ki) {
    const int kb = (kt0 + ki) * 64;
#pragma unroll
    for (int j = 0; j < 2; ++j) {
      int row = w * 16 + j * 8 + skey;
      int gk = kb + row; if (gk >= L_) gk = L_ - 1;
      int ck = sslot ^ (row & 7);
      __builtin_amdgcn_global_load_lds(
          (const __attribute__((address_space(1))) void*)(Kg + (size_t)(b * L_ + gk) * KSTR + koff + ck * 8),
          (__attribute__((address_space(3))) void*)(Kt + (w * 16 + j * 8) * 64),
          16, 0, 0);
      int cv = sslot ^ (row & 7);
      __builtin_amdgcn_global_load_lds(
          (const __attribute__((address_space(1))) void*)(vtg + (size_t)row * LP_ + kb + cv * 8),
          (__attribute__((address_space(3))) void*)(Vt + (w * 16 + j * 8) * 64),
          16, 0, 0);
    }
    __syncthreads();
    f4 s[4];
#pragma unroll
    for (int c = 0; c < 4; ++c) {
      int key = c * 16 + li;
      s8v kf = *(const s8v*)(Kt + key * 64 + ((lg ^ (key & 7)) * 8));
      s8v kg2 = *(const s8v*)(Kt + key * 64 + (((lg + 4) ^ (key & 7)) * 8));
      f4 z = f4{0.f, 0.f, 0.f, 0.f};
      z = __builtin_amdgcn_mfma_f32_16x16x32_bf16(kf, qf0, z, 0, 0, 0);
      z = __builtin_amdgcn_mfma_f32_16x16x32_bf16(kg2, qf1, z, 0, 0, 0);
      s[c] = z * 0.125f;
    }
    if (kb + 64 > L_) {
#pragma unroll
      for (int c = 0; c < 4; ++c)
#pragma unroll
        for (int r = 0; r < 4; ++r)
          if (kb + c * 16 + lg * 4 + r >= L_) s[c][r] = -INFINITY;
    }
    float tm = -INFINITY;
#pragma unroll
    for (int c = 0; c < 4; ++c)
      tm = fmaxf(tm, fmaxf(fmaxf(s[c][0], s[c][1]), fmaxf(s[c][2], s[c][3])));
    tm = fmaxf(tm, __shfl_xor(tm, 16));
    tm = fmaxf(tm, __shfl_xor(tm, 32));
    // T13 defer-max: only rescale when some lane's max grew past threshold.
    if (!__all(tm <= m_run + 8.f)) {
      float mn = fmaxf(m_run, tm);
      float sc = __expf(m_run - mn);
      l_run *= sc;
      m_run = mn;
#pragma unroll
      for (int n = 0; n < 4; ++n) o4[n] *= sc;
    }
    float p[4][4];
    float rs = 0.f;
#pragma unroll
    for (int c = 0; c < 4; ++c)
#pragma unroll
      for (int r = 0; r < 4; ++r) { p[c][r] = __expf(s[c][r] - m_run); rs += p[c][r]; }
    rs += __shfl_xor(rs, 16);
    rs += __shfl_xor(rs, 32);
    l_run += rs;
    // pack P via v_cvt_pk_bf16_f32 (1 VALU op per pair vs ~9 manual)
#pragma unroll
    for (int c = 0; c < 4; ++c)
#pragma unroll
      for (int rp = 0; rp < 2; ++rp)
        xw[li * 36 + c * 8 + lg * 2 + rp] = cvt_pk(p[c][2 * rp], p[c][2 * rp + 1]);
    s8v pb0 = *(const s8v*)(xw + li * 36 + lg * 4);
    s8v pb1 = *(const s8v*)(xw + li * 36 + 16 + lg * 4);
#pragma unroll
    for (int n = 0; n < 4; ++n) {
      int dim = n * 16 + li;
      s8v vb0 = *(const s8v*)(Vt + dim * 64 + ((lg ^ (dim & 7)) * 8));
      o4[n] = __builtin_amdgcn_mfma_f32_16x16x32_bf16(vb0, pb0, o4[n], 0, 0, 0);
    }
#pragma unroll
    for (int n = 0; n < 4; ++n) {
      int dim = n * 16 + li;
      s8v vb1 = *(const s8v*)(Vt + dim * 64 + (((lg + 4) ^ (dim & 7)) * 8));
      o4[n] = __builtin_amdgcn_mfma_f32_16x16x32_bf16(vb1, pb1, o4[n], 0, 0, 0);
    }
    __syncthreads();
  }

  if (MODE == 0) {
    // per-wave LDS transpose [q][d] (packed stores), coalesced bf16 out
#pragma unroll
    for (int n = 0; n < 4; ++n)
#pragma unroll
      for (int rp = 0; rp < 2; ++rp)
        xw[li * 36 + n * 8 + lg * 2 + rp] = cvt_pk(o4[n][2 * rp], o4[n][2 * rp + 1]);
    u16* PO = sp ? POb : POa;
    const int pid = (bh * 24 + qb) * 2 + sp;
    int q_local = lane >> 2, d0 = (lane & 3) * 16;
    int q = qb * 64 + w * 16 + q_local;
    s8v v0 = *(const s8v*)(xw16 + q_local * 72 + d0);
    s8v v1 = *(const s8v*)(xw16 + q_local * 72 + d0 + 8);
    if (q < L_) {
      u16* dst = PO + ((size_t)(b * L_ + q)) * DM_ + qoff + d0;
      *(s8v*)dst = v0;
      *(s8v*)(dst + 8) = v1;
    }
    if (lg == 0) {
      PM[pid * 64 + w * 16 + li] = m_run;
      PL[pid * 64 + w * 16 + li] = l_run;
    }
  } else {
    int base = (bh * 8 + sp) * 64 + w * 16 + li;
#pragma unroll
    for (int n = 0; n < 4; ++n)
#pragma unroll
      for (int r = 0; r < 4; ++r)
        POf[(size_t)base * 64 + n * 16 + lg * 4 + r] = o4[n][r];
    if (lg == 0) {
      PM[base] = m_run;
      PL[base] = l_run;
    }
  }
}

// ---------------- combine 2-way cross partials (POb == ctxb, in place) ------
__global__ __launch_bounds__(256) void combine_cross(const u16* __restrict__ PO0,
                                                     const float* __restrict__ PM,
                                                     const float* __restrict__ PL,
                                                     u16* ctxb) {
  int idx = blockIdx.x * 256 + threadIdx.x;
  int row = idx >> 9, col = idx & 511;
  int b = row / L_, q = row - b * L_;
  int h = col >> 6;
  int bh = b * 8 + h, qbk = q >> 6, qi = q & 63;
  int p0 = ((bh * 24 + qbk) * 2) * 64 + qi;
  float m0 = PM[p0], m1 = PM[p0 + 64];
  float l0 = PL[p0], l1 = PL[p0 + 64];
  float M = fmaxf(m0, m1);
  float w0 = __expf(m0 - M), w1 = __expf(m1 - M);
  float inv = 1.f / (w0 * l0 + w1 * l1);
  float o0 = b2f(PO0[idx]);
  float o1 = b2f(ctxb[idx]);
  ctxb[idx] = f2b((w0 * o0 + w1 * o1) * inv);
}

// ---------------- fused combine split-K partials + scatter into ctxb --------
__global__ __launch_bounds__(256) void combine_prob_scatter(
    const float* __restrict__ PO, const float* __restrict__ PM,
    const float* __restrict__ PL, const int* __restrict__ top,
    u16* __restrict__ ctxb) {
  int bh = blockIdx.x;
  int t = threadIdx.x;
  int u = t >> 2, dg = (t & 3) * 16;
  if (u >= SK_) return;
  float M = -INFINITY;
  for (int s = 0; s < 8; ++s) M = fmaxf(M, PM[(bh * 8 + s) * 64 + u]);
  float wgt[8];
  float den = 0.f;
  for (int s = 0; s < 8; ++s) {
    wgt[s] = __expf(PM[(bh * 8 + s) * 64 + u] - M);
    den += wgt[s] * PL[(bh * 8 + s) * 64 + u];
  }
  float inv = 1.f / den;
  int h = bh & 7, b = bh >> 3;
  int l = top[bh * SK_ + u];
  u16* dst = ctxb + ((size_t)(b * L_ + l)) * DM_ + h * 64;
  for (int d = dg; d < dg + 16; ++d) {
    float acc = 0.f;
    for (int s = 0; s < 8; ++s) acc += wgt[s] * PO[(((size_t)bh * 8 + s) * 64 + u) * 64 + d];
    dst[d] = f2b(acc * inv);
  }
}

// ---------------- ctx = broadcast vmean (24 tile-partials inline) -----------
__global__ __launch_bounds__(256) void fill_ctx(const float* __restrict__ part,
                                                u16* __restrict__ ctxb) {
  int idx = blockIdx.x * 256 + threadIdx.x;
  int d = idx % 64;
  int h = (idx / 64) % H_;
  int b = idx / (L_ * DM_);
  int bh = b * 8 + h;
  float s = 0.f;
#pragma unroll
  for (int seg = 0; seg < 24; ++seg) s += part[((size_t)bh * 24 + seg) * 64 + d];
  ctxb[idx] = f2b(s * (1.f / (float)L_));
}

// ---------------- host side --------------------------------------------------
extern "C" void kernel_launch(void* const* d_in, const int* in_sizes, int n_in,
                              void* d_out, int out_size, void* d_ws, size_t ws_size,
                              hipStream_t stream) {
  const float* inflow   = (const float*)d_in[4];
  const float* W_emb_e  = (const float*)d_in[5];
  const float* b_emb_e  = (const float*)d_in[6];
  const float* W_emb_d  = (const float*)d_in[7];
  const float* b_emb_d  = (const float*)d_in[8];
  const float* enc_Wqkv = (const float*)d_in[9];
  const float* enc_bqkv = (const float*)d_in[10];
  const float* enc_Wo   = (const float*)d_in[11];
  const float* enc_bo   = (const float*)d_in[12];
  const float* enc_ln1g = (const float*)d_in[13];
  const float* enc_ln1b = (const float*)d_in[14];
  const float* enc_Wf1  = (const float*)d_in[15];
  const float* enc_bf1  = (const float*)d_in[16];
  const float* enc_Wf2  = (const float*)d_in[17];
  const float* enc_bf2  = (const float*)d_in[18];
  const float* enc_ln2g = (const float*)d_in[19];
  const float* enc_ln2b = (const float*)d_in[20];
  const float* enc_ng   = (const float*)d_in[21];
  const float* enc_nb   = (const float*)d_in[22];
  const float* dec_Wqkv = (const float*)d_in[23];
  const float* dec_bqkv = (const float*)d_in[24];
  const float* dec_Wo_s = (const float*)d_in[25];
  const float* dec_bo_s = (const float*)d_in[26];
  const float* dec_ln1g = (const float*)d_in[27];
  const float* dec_ln1b = (const float*)d_in[28];
  const float* dec_Wq_c = (const float*)d_in[29];
  const float* dec_bq_c = (const float*)d_in[30];
  const float* dec_Wkv  = (const float*)d_in[31];
  const float* dec_bkv  = (const float*)d_in[32];
  const float* dec_Wo_c = (const float*)d_in[33];
  const float* dec_bo_c = (const float*)d_in[34];
  const float* dec_ln2g = (const float*)d_in[35];
  const float* dec_ln2b = (const float*)d_in[36];
  const float* dec_Wf1  = (const float*)d_in[37];
  const float* dec_bf1  = (const float*)d_in[38];
  const float* dec_Wf2  = (const float*)d_in[39];
  const float* dec_bf2  = (const float*)d_in[40];
  const float* dec_ln3g = (const float*)d_in[41];
  const float* dec_ln3b = (const float*)d_in[42];
  const float* W_proj   = (const float*)d_in[43];
  const float* b_proj   = (const float*)d_in[44];
  const float* W1       = (const float*)d_in[45];
  const float* b1       = (const float*)d_in[46];
  const float* W3       = (const float*)d_in[47];
  const float* b3       = (const float*)d_in[48];
  const int*   samp     = (const int*)d_in[49];
  float* out = (float*)d_out;

  float* ws  = (float*)d_ws;
  float* PE  = ws;                       // 778240 f (dead after embeds -> PMc/PLc)
  float* X   = PE + 778240;              // 72960 f
  float* ACT = X + 72960;                // 3112960 f
  float* REG = ACT + 3112960;            // 6291456 f shared region
  float* MME = REG + 6291456;            // 48640 f
  float* CTT = MME + 48640;              // 81920 f (VME24: 49152 f)
  float* VME = CTT + 81920;              // 2048 f (unused)
  int*   TOP = (int*)(VME + 2048);       // 1280 i
  float* TAIL = VME + 2048 + 1280;
  u16* ENCb = (u16*)TAIL;                       // 6144*512 u16
  u16* DECb = (u16*)(TAIL + 1572864);
  u16* CTXb = (u16*)(TAIL + 2 * 1572864);
  u16* WBF  = (u16*)(TAIL + 3 * 1572864);       // 10485760 u16
  // prob split-K partials: FRESH memory after WBF (no CTXb overlay)
  float* POp = (float*)(WBF + 10485760);        // 1048576 f
  float* PMp = POp + 1048576;                   // 16384 f
  float* PLp = PMp + 16384;                     // 16384 f
  u16*   PO0 = (u16*)(PLp + 16384);             // cross split-0 partials [6144][512]

  // region overlays (prob phase)
  u16* QKVb = (u16*)REG;                 // [6144][1536]
  u16* FFb  = (u16*)REG;                 // [6144][2048]
  u16* VT   = (u16*)REG + 9437184;       // [32][64][1536] u16
  // region overlays (cross phase)
  u16* QCb  = (u16*)REG;                 // [6144][512]
  u16* KVCb = (u16*)REG + 3145728;       // [6144][1024] (K at +0, V at +512)
  // cross partial stats in dead PE region (32*24*2*64 = 98304 each)
  float* PMc = PE;
  float* PLc = PE + 98304;
  float* VME24 = CTT;                    // 32*24*64 = 49152 f

  auto GB = [&](const u16* A, const u16* Bt, const float* bias, const float* res,
                float* Cf, u16* Cb, int N, int K, int act) {
    if (N <= 512) {
      dim3 g(N / 128, MP_ / 64);
      gemm_bf16<64><<<g, 256, 0, stream>>>(A, Bt, bias, res, Cf, Cb, N, K, act);
    } else {
      dim3 g(N / 128, MP_ / 128);
      gemm_bf16<128><<<g, 256, 0, stream>>>(A, Bt, bias, res, Cf, Cb, N, K, act);
    }
  };
  auto PROB = [&](const int* sidx) {
    probM<<<B_ * H_ * L_ / 4, 256, 0, stream>>>(QKVb, sidx, MME);
    radix_topk<<<B_ * H_, 256, 0, stream>>>(MME, TOP);
    transpose_v<<<B_ * H_ * 24, 256, 0, stream>>>(QKVb, 1536, 1024, VT, VME24);
    flash_attn<1><<<B_ * H_ * 8, 256, 0, stream>>>(QKVb, QKVb, VT, TOP, POp,
                                                   nullptr, nullptr, PMp, PLp);
    fill_ctx<<<ML_ * DM_ / 256, 256, 0, stream>>>(VME24, CTXb);
    combine_prob_scatter<<<B_ * H_, 256, 0, stream>>>(POp, PMp, PLp, TOP, CTXb);
  };

  pe_kernel<<<(L_ * DM_ + 255) / 256, 256, 0, stream>>>(PE);
  extract_x<<<(ML_ * 12 + 255) / 256, 256, 0, stream>>>(inflow, X);

  // one fused weight-conversion dispatch (LDS tiled transpose)
  {
    CvtArgs a;
    const float* s[15] = {
      enc_Wqkv, enc_Wqkv + 512 * 1536, enc_Wo, enc_Wo + 512 * 512,
      enc_Wf1, enc_Wf1 + 512 * 2048, enc_Wf2, enc_Wf2 + 2048 * 512,
      dec_Wqkv, dec_Wo_s, dec_Wq_c, dec_Wkv, dec_Wo_c, dec_Wf1, dec_Wf2 };
    unsigned cumt[16] = { 0u, 768u, 1536u, 1792u, 2048u, 3072u,
                          4096u, 5120u, 6144u, 6912u, 7168u,
                          7424u, 7936u, 8192u, 9216u, 10240u };
    unsigned lk[15] = { 9, 9, 9, 9, 9, 9, 11, 11, 9, 9, 9, 9, 9, 9, 11 };
    for (int i = 0; i < 15; ++i) { a.src[i] = s[i]; a.lk[i] = lk[i]; }
    for (int i = 0; i < 16; ++i) a.cumt[i] = cumt[i];
    cvt_all<<<10240, 256, 0, stream>>>(a, WBF);
  }
  u16* Wt_qkv_e0 = WBF + 0;
  u16* Wt_qkv_e1 = WBF + 786432;
  u16* Wt_o_e0   = WBF + 1572864;
  u16* Wt_o_e1   = WBF + 1835008;
  u16* Wt_f1_e0  = WBF + 2097152;
  u16* Wt_f1_e1  = WBF + 3145728;
  u16* Wt_f2_e0  = WBF + 4194304;
  u16* Wt_f2_e1  = WBF + 5242880;
  u16* Wt_qkv_d  = WBF + 6291456;
  u16* Wt_o_s    = WBF + 7077888;
  u16* Wt_q_c    = WBF + 7340032;
  u16* Wt_kv_c   = WBF + 7602176;
  u16* Wt_o_c    = WBF + 8126464;
  u16* Wt_f1_d   = WBF + 8388608;
  u16* Wt_f2_d   = WBF + 9437184;

  // ---------------- encoder ----------------
  embed_fused<<<MP_ / 4, 256, 0, stream>>>(X, W_emb_e, b_emb_e, PE, ACT, ENCb);

  const u16* Wqkv_e[2] = {Wt_qkv_e0, Wt_qkv_e1};
  const u16* Wo_e[2]   = {Wt_o_e0, Wt_o_e1};
  const u16* Wf1_e[2]  = {Wt_f1_e0, Wt_f1_e1};
  const u16* Wf2_e[2]  = {Wt_f2_e0, Wt_f2_e1};
  for (int i = 0; i < 2; ++i) {
    GB(ENCb, Wqkv_e[i], enc_bqkv + i * 1536, nullptr, nullptr, QKVb, 1536, 512, 0);
    PROB(samp + (size_t)i * L_ * SK_);
    GB(CTXb, Wo_e[i], enc_bo + i * 512, ACT, ACT, nullptr, 512, 512, 0);
    layernorm_ip<<<ML_ / 4, 256, 0, stream>>>(ACT, enc_ln1g + i * 512, enc_ln1b + i * 512, ENCb);
    GB(ENCb, Wf1_e[i], enc_bf1 + i * 2048, nullptr, nullptr, FFb, 2048, 512, 1);
    GB(FFb, Wf2_e[i], enc_bf2 + i * 512, ACT, ACT, nullptr, 512, 2048, 0);
    layernorm_ip<<<ML_ / 4, 256, 0, stream>>>(ACT, enc_ln2g + i * 512, enc_ln2b + i * 512, ENCb);
  }
  layernorm_ip<<<ML_ / 4, 256, 0, stream>>>(ACT, enc_ng, enc_nb, ENCb);

  // ---------------- decoder ----------------
  embed_fused<<<MP_ / 4, 256, 0, stream>>>(X, W_emb_d, b_emb_d, PE, ACT, DECb);
  GB(DECb, Wt_qkv_d, dec_bqkv, nullptr, nullptr, QKVb, 1536, 512, 0);
  PROB(samp + (size_t)2 * L_ * SK_);
  GB(CTXb, Wt_o_s, dec_bo_s, ACT, ACT, nullptr, 512, 512, 0);
  layernorm_ip<<<ML_ / 4, 256, 0, stream>>>(ACT, dec_ln1g, dec_ln1b, DECb);

  // cross attention: Q GEMM + merged K/V GEMM (N=1024, KVC layout)
  GB(DECb, Wt_q_c, dec_bq_c, nullptr, nullptr, QCb, 512, 512, 0);
  GB(ENCb, Wt_kv_c, dec_bkv, nullptr, nullptr, KVCb, 1024, 512, 0);
  transpose_v<<<B_ * H_ * 24, 256, 0, stream>>>(KVCb, 1024, 512, VT, nullptr);
  flash_attn<0><<<B_ * H_ * 48, 256, 0, stream>>>(QCb, KVCb, VT, nullptr, nullptr,
                                                  PO0, CTXb, PMc, PLc);
  combine_cross<<<ML_ * DM_ / 256, 256, 0, stream>>>(PO0, PMc, PLc, CTXb);
  GB(CTXb, Wt_o_c, dec_bo_c, ACT, ACT, nullptr, 512, 512, 0);
  layernorm_ip<<<ML_ / 4, 256, 0, stream>>>(ACT, dec_ln2g, dec_ln2b, DECb);

  GB(DECb, Wt_f1_d, dec_bf1, nullptr, nullptr, FFb, 2048, 512, 1);
  GB(FFb, Wt_f2_d, dec_bf2, ACT, ACT, nullptr, 512, 2048, 0);
  layernorm_ip<<<ML_ / 4, 256, 0, stream>>>(ACT, dec_ln3g, dec_ln3b, DECb);

  // fused head
  head_fused<<<ML_ / 4, 256, 0, stream>>>(ACT, X, W_proj, b_proj, W1, b1, W3, b3, out);
}

// Round 16
// 842.597 us; speedup vs baseline: 1.2403x; 1.0204x over previous
//
#include <hip/hip_runtime.h>
#include <math.h>

#define B_ 4
#define H_ 8
#define L_ 1520
#define DM_ 512
#define DFF_ 2048
#define SK_ 40
#define ML_ (B_*L_)   /* 6080 rows */
#define MP_ 6144      /* padded rows for MFMA GEMM */
#define LP_ 1536      /* padded key count for V^T */

typedef unsigned short u16;
typedef short s8v __attribute__((ext_vector_type(8)));
typedef float f4 __attribute__((ext_vector_type(4)));

__device__ __forceinline__ u16 f2b(float x) {
  union { float f; unsigned u; } c; c.f = x;
  unsigned r = c.u + 0x7FFFu + ((c.u >> 16) & 1u);
  return (u16)(r >> 16);
}
__device__ __forceinline__ float b2f(u16 h) {
  union { unsigned u; float f; } c; c.u = ((unsigned)h) << 16;
  return c.f;
}
// packed f32 pair -> 2x bf16 in one u32 (lo = a, hi = b); single VALU op
__device__ __forceinline__ unsigned cvt_pk(float a, float b) {
  unsigned r;
  asm volatile("v_cvt_pk_bf16_f32 %0, %1, %2" : "=v"(r) : "v"(a), "v"(b));
  return r;
}
__device__ __forceinline__ float gelu_tanh(float x) {
  float x3 = x * x * x;
  return 0.5f * x * (1.f + tanhf(0.79788456080286536f * (x + 0.044715f * x3)));
}
// XCD-chunked bijective swizzle; requires nwg % 8 == 0 (cpx = nwg/8).
__device__ __forceinline__ int xswz(int bid, int cpx) {
  return (bid & 7) * cpx + (bid >> 3);
}

// ---------------- positional encoding (double precision to match numpy) ----
__global__ __launch_bounds__(256) void pe_kernel(float* __restrict__ pe) {
  int idx = blockIdx.x * 256 + threadIdx.x;
  if (idx >= L_ * DM_) return;
  int pos = idx / DM_, i = idx % DM_;
  double expo = (double)(2 * (i / 2)) / (double)DM_;
  double ang = (double)pos / pow(10000.0, expo);
  pe[idx] = (i & 1) ? (float)cos(ang) : (float)sin(ang);
}

// ---------------- x = inflow[:,2:14].reshape (contiguous slice) -------------
__global__ __launch_bounds__(256) void extract_x(const float* __restrict__ inflow,
                                                 float* __restrict__ X) {
  int idx = blockIdx.x * 256 + threadIdx.x;
  if (idx >= ML_ * 12) return;
  int b = idx / (L_ * 12);
  int rem = idx - b * (L_ * 12);
  X[idx] = inflow[(size_t)b * 14 * L_ + 2 * L_ + rem];
}

// ---------------- fused weight convert+transpose (LDS tiled, coalesced) -----
struct CvtArgs {
  const float* src[15];
  unsigned cumt[16];   // cumulative 32x32-tile counts
  unsigned lk[15];     // log2(K) per segment
};
__global__ __launch_bounds__(256) void cvt_all(CvtArgs a, u16* __restrict__ dst) {
  __shared__ float tl[32][33];
  int bt = blockIdx.x;                 // grid exact: 10240 tiles
  int s = 0;
#pragma unroll
  for (int i = 1; i < 15; ++i) s += (bt >= (int)a.cumt[i]);
  int lt = bt - a.cumt[s];
  unsigned lk = a.lk[s];
  unsigned K = 1u << lk;
  unsigned N = ((a.cumt[s + 1] - a.cumt[s]) << 10) >> lk;
  unsigned tiles_n = N >> 5;
  unsigned k0 = (lt / tiles_n) * 32, n0 = (lt % tiles_n) * 32;
  const float* src = a.src[s];
  int r = threadIdx.x >> 5, c = threadIdx.x & 31;
#pragma unroll
  for (int i = 0; i < 4; ++i)
    tl[r + 8 * i][c] = src[(size_t)(k0 + r + 8 * i) * N + n0 + c];
  __syncthreads();
  u16* d = dst + ((size_t)a.cumt[s] << 10);
#pragma unroll
  for (int i = 0; i < 4; ++i)
    d[(size_t)(n0 + r + 8 * i) * K + k0 + c] = f2b(tl[c][r + 8 * i]);
}

// ---------------- fused embed: ACT = X@W + b + PE ; ACTb = bf16(ACT) --------
__global__ __launch_bounds__(256) void embed_fused(
    const float* __restrict__ X, const float* __restrict__ W,
    const float* __restrict__ bias, const float* __restrict__ PE,
    float* __restrict__ ACT, u16* __restrict__ ACTb) {
  int row = blockIdx.x * 4 + (threadIdx.x >> 6);
  int lane = threadIdx.x & 63;
  int d0 = lane * 8;
  if (row >= ML_) {
    s8v z = {0, 0, 0, 0, 0, 0, 0, 0};
    *(s8v*)(ACTb + (size_t)row * DM_ + d0) = z;
    return;
  }
  int prow = row % L_;
  f4 a0 = *(const f4*)(bias + d0);
  f4 a1 = *(const f4*)(bias + d0 + 4);
  a0 += *(const f4*)(PE + (size_t)prow * DM_ + d0);
  a1 += *(const f4*)(PE + (size_t)prow * DM_ + d0 + 4);
  const float* xr = X + (size_t)row * 12;
#pragma unroll
  for (int t = 0; t < 12; ++t) {
    float xv = xr[t];
    a0 += xv * *(const f4*)(W + (size_t)t * DM_ + d0);
    a1 += xv * *(const f4*)(W + (size_t)t * DM_ + d0 + 4);
  }
  float* dst = ACT + (size_t)row * DM_ + d0;
  *(f4*)dst = a0;
  *(f4*)(dst + 4) = a1;
  unsigned ob[4];
  ob[0] = cvt_pk(a0[0], a0[1]); ob[1] = cvt_pk(a0[2], a0[3]);
  ob[2] = cvt_pk(a1[0], a1[1]); ob[3] = cvt_pk(a1[2], a1[3]);
  *(s8v*)(ACTb + (size_t)row * DM_ + d0) = *(s8v*)ob;
}

// ---------------- fused head: out = relu((DEC@Wp+bp+X)@W1+b1)@W3+b3 ---------
__global__ __launch_bounds__(256) void head_fused(
    const float* __restrict__ DEC, const float* __restrict__ X,
    const float* __restrict__ Wp, const float* __restrict__ bp,
    const float* __restrict__ W1, const float* __restrict__ b1,
    const float* __restrict__ W3, const float* __restrict__ b3,
    float* __restrict__ out) {
  int row = blockIdx.x * 4 + (threadIdx.x >> 6);
  int lane = threadIdx.x & 63;
  int d0 = lane * 8;
  const float* dec = DEC + (size_t)row * DM_ + d0;
  f4 v0 = *(const f4*)dec;
  f4 v1 = *(const f4*)(dec + 4);
  float pj[12];
#pragma unroll
  for (int j = 0; j < 12; ++j) pj[j] = 0.f;
#pragma unroll
  for (int i = 0; i < 8; ++i) {
    float dv = (i < 4) ? v0[i] : v1[i - 4];
    const float* wr = Wp + (size_t)(d0 + i) * 12;
#pragma unroll
    for (int j = 0; j < 12; ++j) pj[j] += dv * wr[j];
  }
  for (int off = 32; off; off >>= 1) {
#pragma unroll
    for (int j = 0; j < 12; ++j) pj[j] += __shfl_xor(pj[j], off);
  }
  float o12[12];
#pragma unroll
  for (int j = 0; j < 12; ++j) o12[j] = pj[j] + bp[j] + X[(size_t)row * 12 + j];
  int k0 = lane * 2;
  float h0 = b1[k0], h1 = b1[k0 + 1];
#pragma unroll
  for (int j = 0; j < 12; ++j) {
    h0 += o12[j] * W1[j * 128 + k0];
    h1 += o12[j] * W1[j * 128 + k0 + 1];
  }
  h0 = fmaxf(h0, 0.f);
  h1 = fmaxf(h1, 0.f);
  float op[3];
#pragma unroll
  for (int p = 0; p < 3; ++p)
    op[p] = h0 * W3[k0 * 3 + p] + h1 * W3[(k0 + 1) * 3 + p];
  for (int off = 32; off; off >>= 1) {
#pragma unroll
    for (int p = 0; p < 3; ++p) op[p] += __shfl_xor(op[p], off);
  }
  if (lane == 0) {
#pragma unroll
    for (int p = 0; p < 3; ++p) out[(size_t)row * 3 + p] = op[p] + b3[p];
  }
}

// ---------------- bf16 MFMA GEMM, BM=128/BK=32, single-buffered -------------
__global__ __launch_bounds__(256) void gemm_bf16_128(
    const u16* __restrict__ A, const u16* __restrict__ Bt,
    const float* __restrict__ bias, const float* __restrict__ res,
    float* __restrict__ Cf, u16* __restrict__ Cb,
    int N, int K, int act) {
  __shared__ __align__(16) u16 As[128 * 32];
  __shared__ __align__(16) u16 Bs[128 * 32];
  const int nwg = gridDim.x * gridDim.y;
  const int lin = blockIdx.y * gridDim.x + blockIdx.x;
  const int o = xswz(lin, nwg >> 3);
  const int bxi = o % gridDim.x, byi = o / gridDim.x;
  const int t = threadIdx.x, w = t >> 6, lane = t & 63;
  const int lg = lane >> 4, li = lane & 15;
  const int bm = byi * 128, bn = bxi * 128;
  const int wr = (w >> 1) * 64, wc = (w & 1) * 64;
  f4 acc[4][4];
#pragma unroll
  for (int i = 0; i < 4; ++i)
#pragma unroll
    for (int j = 0; j < 4; ++j) acc[i][j] = f4{0.f, 0.f, 0.f, 0.f};
  const int rB = w * 32 + (lane >> 2);
  const int ps = lane & 3;
  for (int k0 = 0; k0 < K; k0 += 32) {
#pragma unroll
    for (int j = 0; j < 2; ++j) {
      int r = rB + j * 16;
      int ls = ps ^ ((r >> 1) & 3);
      __builtin_amdgcn_global_load_lds(
          (const __attribute__((address_space(1))) void*)(A + (size_t)(bm + r) * K + k0 + ls * 8),
          (__attribute__((address_space(3))) void*)(As + (w * 32 + j * 16) * 32),
          16, 0, 0);
      __builtin_amdgcn_global_load_lds(
          (const __attribute__((address_space(1))) void*)(Bt + (size_t)(bn + r) * K + k0 + ls * 8),
          (__attribute__((address_space(3))) void*)(Bs + (w * 32 + j * 16) * 32),
          16, 0, 0);
    }
    __syncthreads();
    s8v af[4], bf[4];
#pragma unroll
    for (int f = 0; f < 4; ++f) {
      int ra = wr + f * 16 + li;
      af[f] = *(const s8v*)(As + ra * 32 + ((lg ^ ((ra >> 1) & 3)) * 8));
      int rb = wc + f * 16 + li;
      bf[f] = *(const s8v*)(Bs + rb * 32 + ((lg ^ ((rb >> 1) & 3)) * 8));
    }
#pragma unroll
    for (int fi = 0; fi < 4; ++fi)
#pragma unroll
      for (int fj = 0; fj < 4; ++fj)
        acc[fi][fj] = __builtin_amdgcn_mfma_f32_16x16x32_bf16(af[fi], bf[fj], acc[fi][fj], 0, 0, 0);
    __syncthreads();
  }
#pragma unroll
  for (int fi = 0; fi < 4; ++fi)
#pragma unroll
    for (int fj = 0; fj < 4; ++fj)
#pragma unroll
      for (int r = 0; r < 4; ++r) {
        int row = bm + wr + fi * 16 + lg * 4 + r;
        int col = bn + wc + fj * 16 + li;
        float v = acc[fi][fj][r] + bias[col];
        if (res && row < ML_) v += res[(size_t)row * N + col];
        if (act == 1) v = gelu_tanh(v);
        if (Cf && row < ML_) Cf[(size_t)row * N + col] = v;
        if (Cb) Cb[(size_t)row * N + col] = f2b(v);
      }
}

// ---------------- bf16 MFMA GEMM, BM=64/BK=64: half the barrier drains ------
// Stage both 32-wide K-halves in one phase (linear LDS dest, source col
// pre-XOR'd by row&7; reads apply same XOR -> 2-way bank aliasing, free).
__global__ __launch_bounds__(256) void gemm_bf16_k64(
    const u16* __restrict__ A, const u16* __restrict__ Bt,
    const float* __restrict__ bias, const float* __restrict__ res,
    float* __restrict__ Cf, u16* __restrict__ Cb,
    int N, int K, int act) {
  __shared__ __align__(16) u16 As[64 * 64];
  __shared__ __align__(16) u16 Bs[128 * 64];
  const int nwg = gridDim.x * gridDim.y;
  const int lin = blockIdx.y * gridDim.x + blockIdx.x;
  const int o = xswz(lin, nwg >> 3);
  const int bxi = o % gridDim.x, byi = o / gridDim.x;
  const int t = threadIdx.x, w = t >> 6, lane = t & 63;
  const int lg = lane >> 4, li = lane & 15;
  const int bm = byi * 64, bn = bxi * 128;
  const int wr = (w >> 1) * 32, wc = (w & 1) * 64;
  f4 acc[2][4];
#pragma unroll
  for (int i = 0; i < 2; ++i)
#pragma unroll
    for (int j = 0; j < 4; ++j) acc[i][j] = f4{0.f, 0.f, 0.f, 0.f};
  const int rloc = lane >> 3;          // 0..7 rows per wave-instruction
  const int slot = lane & 7;           // physical 16B slot written
  for (int k0 = 0; k0 < K; k0 += 64) {
    // A: 64 rows, 2 wave-instructions of 8 rows each per wave
#pragma unroll
    for (int j = 0; j < 2; ++j) {
      int r = w * 8 + j * 32 + rloc;
      int ls = slot ^ (r & 7);
      __builtin_amdgcn_global_load_lds(
          (const __attribute__((address_space(1))) void*)(A + (size_t)(bm + r) * K + k0 + ls * 8),
          (__attribute__((address_space(3))) void*)(As + (w * 8 + j * 32) * 64),
          16, 0, 0);
    }
    // B: 128 rows, 4 wave-instructions
#pragma unroll
    for (int j = 0; j < 4; ++j) {
      int r = w * 8 + j * 32 + rloc;
      int ls = slot ^ (r & 7);
      __builtin_amdgcn_global_load_lds(
          (const __attribute__((address_space(1))) void*)(Bt + (size_t)(bn + r) * K + k0 + ls * 8),
          (__attribute__((address_space(3))) void*)(Bs + (w * 8 + j * 32) * 64),
          16, 0, 0);
    }
    __syncthreads();
#pragma unroll
    for (int ks = 0; ks < 2; ++ks) {
      s8v af[2], bf[4];
#pragma unroll
      for (int f = 0; f < 2; ++f) {
        int ra = wr + f * 16 + li;
        af[f] = *(const s8v*)(As + ra * 64 + (((ks * 4 + lg) ^ (ra & 7)) * 8));
      }
#pragma unroll
      for (int f = 0; f < 4; ++f) {
        int rb = wc + f * 16 + li;
        bf[f] = *(const s8v*)(Bs + rb * 64 + (((ks * 4 + lg) ^ (rb & 7)) * 8));
      }
#pragma unroll
      for (int fi = 0; fi < 2; ++fi)
#pragma unroll
        for (int fj = 0; fj < 4; ++fj)
          acc[fi][fj] = __builtin_amdgcn_mfma_f32_16x16x32_bf16(af[fi], bf[fj], acc[fi][fj], 0, 0, 0);
    }
    __syncthreads();
  }
#pragma unroll
  for (int fi = 0; fi < 2; ++fi)
#pragma unroll
    for (int fj = 0; fj < 4; ++fj)
#pragma unroll
      for (int r = 0; r < 4; ++r) {
        int row = bm + wr + fi * 16 + lg * 4 + r;
        int col = bn + wc + fj * 16 + li;
        float v = acc[fi][fj][r] + bias[col];
        if (res && row < ML_) v += res[(size_t)row * N + col];
        if (act == 1) v = gelu_tanh(v);
        if (Cf && row < ML_) Cf[(size_t)row * N + col] = v;
        if (Cb) Cb[(size_t)row * N + col] = f2b(v);
      }
}

// ---------------- layernorm: wave per row, vectorized -----------------------
__global__ __launch_bounds__(256) void layernorm_ip(float* __restrict__ Xb,
                                                    const float* __restrict__ g,
                                                    const float* __restrict__ bta,
                                                    u16* __restrict__ outb) {
  int row = blockIdx.x * 4 + (threadIdx.x >> 6);
  int lane = threadIdx.x & 63;
  float* x = Xb + (size_t)row * DM_;
  f4 a = *(f4*)(x + lane * 8);
  f4 b = *(f4*)(x + lane * 8 + 4);
  float s = a[0] + a[1] + a[2] + a[3] + b[0] + b[1] + b[2] + b[3];
  for (int off = 32; off; off >>= 1) s += __shfl_xor(s, off);
  float mu = s * (1.f / 512.f);
  float vs = 0.f;
#pragma unroll
  for (int i = 0; i < 4; ++i) { a[i] -= mu; b[i] -= mu; vs += a[i] * a[i] + b[i] * b[i]; }
  for (int off = 32; off; off >>= 1) vs += __shfl_xor(vs, off);
  float rs = rsqrtf(vs * (1.f / 512.f) + 1e-5f);
  f4 g0 = *(const f4*)(g + lane * 8), g1 = *(const f4*)(g + lane * 8 + 4);
  f4 c0 = *(const f4*)(bta + lane * 8), c1 = *(const f4*)(bta + lane * 8 + 4);
  float r0 = a[0] * rs * g0[0] + c0[0];
  float r1 = a[1] * rs * g0[1] + c0[1];
  float r2 = a[2] * rs * g0[2] + c0[2];
  float r3 = a[3] * rs * g0[3] + c0[3];
  float r4 = b[0] * rs * g1[0] + c1[0];
  float r5 = b[1] * rs * g1[1] + c1[1];
  float r6 = b[2] * rs * g1[2] + c1[2];
  float r7 = b[3] * rs * g1[3] + c1[3];
  x[lane * 8 + 0] = r0; x[lane * 8 + 1] = r1; x[lane * 8 + 2] = r2; x[lane * 8 + 3] = r3;
  x[lane * 8 + 4] = r4; x[lane * 8 + 5] = r5; x[lane * 8 + 6] = r6; x[lane * 8 + 7] = r7;
  unsigned ob[4];
  ob[0] = cvt_pk(r0, r1); ob[1] = cvt_pk(r2, r3);
  ob[2] = cvt_pk(r4, r5); ob[3] = cvt_pk(r6, r7);
  *(s8v*)(outb + (size_t)row * DM_ + lane * 8) = *(s8v*)ob;
}

// ---------------- ProbSparse sparsity measure M (bf16 qkv), swizzled --------
__global__ __launch_bounds__(256) void probM(const u16* __restrict__ qkv,
                                             const int* __restrict__ sidx,
                                             float* __restrict__ Mout) {
  int wid = threadIdx.x / 64, lane = threadIdx.x % 64;
  int o = xswz(blockIdx.x, (B_ * H_ * L_ / 4) >> 3);
  int g = o * 4 + wid;
  int l = g % L_;
  int bh = g / L_;
  int h = bh % H_, b = bh / H_;
  __shared__ float qs[4][64];
  qs[wid][lane] = b2f(qkv[((size_t)b * L_ + l) * 1536 + h * 64 + lane]);
  __syncthreads();
  float dot = 0.f;
  if (lane < SK_) {
    int ks = sidx[l * SK_ + lane];
    const u16* kr = qkv + ((size_t)b * L_ + ks) * 1536 + 512 + h * 64;
#pragma unroll
    for (int j = 0; j < 8; ++j) {
      s8v v = *(const s8v*)(kr + j * 8);
#pragma unroll
      for (int i = 0; i < 8; ++i) dot += qs[wid][j * 8 + i] * b2f((u16)v[i]);
    }
  }
  float vmax = (lane < SK_) ? dot : -INFINITY;
  float vsum = (lane < SK_) ? dot : 0.f;
  for (int off = 32; off; off >>= 1) {
    vmax = fmaxf(vmax, __shfl_xor(vmax, off));
    vsum += __shfl_xor(vsum, off);
  }
  if (lane == 0) Mout[g] = vmax - vsum / (float)L_;
}

// ---------------- radix-select top-40 (matches lax.top_k selection set) -----
__global__ __launch_bounds__(256) void radix_topk(const float* __restrict__ Mv,
                                                  int* __restrict__ top) {
  const int bh = blockIdx.x;
  const int t = threadIdx.x;
  const int base = t * 6;
  unsigned key[6];
#pragma unroll
  for (int i = 0; i < 6; ++i) {
    int ix = base + i;
    unsigned k = 0u;
    if (ix < L_) {
      union { float f; unsigned u; } c; c.f = Mv[(size_t)bh * L_ + ix];
      k = c.u ^ ((c.u & 0x80000000u) ? 0xFFFFFFFFu : 0x80000000u);
    }
    key[i] = k;
  }
  __shared__ int wred[4];
  __shared__ int s_a[256], s_b[256];
  unsigned prefix = 0u;
  for (int b = 31; b >= 0; --b) {
    unsigned cand = prefix | (1u << b);
    int c = 0;
#pragma unroll
    for (int i = 0; i < 6; ++i) c += (key[i] >= cand);
    for (int off = 32; off; off >>= 1) c += __shfl_xor(c, off);
    if ((t & 63) == 0) wred[t >> 6] = c;
    __syncthreads();
    int tot = wred[0] + wred[1] + wred[2] + wred[3];
    if (tot >= SK_) prefix = cand;
    __syncthreads();
  }
  const unsigned T = prefix;
  int gt = 0, tie = 0;
#pragma unroll
  for (int i = 0; i < 6; ++i) { gt += (key[i] > T); tie += (key[i] == T); }
  s_a[t] = gt; s_b[t] = tie;
  __syncthreads();
  for (int off = 1; off < 256; off <<= 1) {
    int va = (t >= off) ? s_a[t - off] : 0;
    int vb = (t >= off) ? s_b[t - off] : 0;
    __syncthreads();
    s_a[t] += va; s_b[t] += vb;
    __syncthreads();
  }
  const int n_strict = s_a[255];
  const int gt_base = s_a[t] - gt;
  const int tie_base = s_b[t] - tie;
  const int need = SK_ - n_strict;
  int lgt = 0, ltie = 0;
#pragma unroll
  for (int i = 0; i < 6; ++i) {
    int ix = base + i;
    if (key[i] > T) {
      top[bh * SK_ + gt_base + lgt] = ix; ++lgt;
    } else if (key[i] == T) {
      int r = tie_base + ltie; ++ltie;
      if (r < need) top[bh * SK_ + n_strict + r] = ix;
    }
  }
}

// ---------------- V^T build + fused per-tile V column sums ------------------
__global__ __launch_bounds__(256) void transpose_v(const u16* __restrict__ src,
                                                   int stride, int voff0,
                                                   u16* __restrict__ VT,
                                                   float* __restrict__ vpart) {
  int o = xswz(blockIdx.x, (B_ * H_ * 24) >> 3);
  int kt = o % 24, bh = o / 24;
  int h = bh & 7, b = bh >> 3;
  int kb = kt * 64;
  __shared__ u16 tile[64][72];
  int t = threadIdx.x;
#pragma unroll
  for (int rr = 0; rr < 2; ++rr) {
    int slot = rr * 256 + t;
    int key = slot >> 3, d = (slot & 7) * 8;
    int gk = kb + key; if (gk >= L_) gk = L_ - 1;
    s8v v = *(const s8v*)(src + (size_t)(b * L_ + gk) * stride + voff0 + h * 64 + d);
    *(s8v*)(&tile[key][d]) = v;
  }
  __syncthreads();
  int dim = t >> 2, k0 = (t & 3) * 16;
  u16 buf[16];
  float psum = 0.f;
#pragma unroll
  for (int i = 0; i < 16; ++i) {
    int key = k0 + i;
    buf[i] = (kb + key < L_) ? tile[key][dim] : (u16)0;
    psum += b2f(buf[i]);
  }
  *(s8v*)(VT + ((size_t)bh * 64 + dim) * LP_ + kb + k0) = *(s8v*)buf;
  *(s8v*)(VT + ((size_t)bh * 64 + dim) * LP_ + kb + k0 + 8) = *(s8v*)(buf + 8);
  if (vpart) {
    psum += __shfl_xor(psum, 1);
    psum += __shfl_xor(psum, 2);
    if ((t & 3) == 0) vpart[((size_t)bh * 24 + kt) * 64 + dim] = psum;
  }
}

// ---------------- LDS-staged swapped-operand MFMA flash attention -----------
template<int MODE>
__global__ __launch_bounds__(256) void flash_attn(
    const u16* __restrict__ Qm, const u16* __restrict__ Kg,
    const u16* __restrict__ VT, const int* __restrict__ top,
    float* __restrict__ POf, u16* POa, u16* POb,
    float* __restrict__ PM, float* __restrict__ PL) {
  constexpr int QSTR = (MODE == 0) ? 512 : 1536;
  constexpr int KSTR = (MODE == 0) ? 1024 : 1536;
  constexpr int TILES = (MODE == 0) ? 12 : 3;
  constexpr int NB = (MODE == 0) ? 48 : 8;
  __shared__ __align__(16) u16 Kt[64 * 64];        // [key][slot^(key&7)]
  __shared__ __align__(16) u16 Vt[64 * 64];        // [dim][slot^(dim&7)]
  __shared__ __align__(16) unsigned Xch[4][576];   // per-wave P exchange
  const int o = xswz(blockIdx.x, (B_ * H_ * NB) >> 3);
  int bh, sp, qb;
  if (MODE == 0) {
    bh = o / 48; int rem = o % 48; qb = rem >> 1; sp = rem & 1;
  } else {
    bh = o / 8; sp = o % 8; qb = 0;
  }
  const int h = bh & 7, b = bh >> 3;
  const int qoff = h * 64;
  const int koff = ((MODE == 0) ? 0 : 512) + h * 64;
  const int t = threadIdx.x, w = t >> 6, lane = t & 63;
  const int lg = lane >> 4, li = lane & 15;
  const u16* vtg = VT + (size_t)bh * 64 * LP_;
  unsigned* xw = Xch[w];
  u16* xw16 = (u16*)xw;

  int qrow;
  if (MODE == 0) {
    int q = qb * 64 + w * 16 + li;
    qrow = b * L_ + ((q < L_) ? q : (L_ - 1));
  } else {
    int u = w * 16 + li; if (u >= SK_) u = SK_ - 1;
    qrow = b * L_ + top[bh * SK_ + u];
  }
  s8v qf0 = *(const s8v*)(Qm + (size_t)qrow * QSTR + qoff + lg * 8);
  s8v qf1 = *(const s8v*)(Qm + (size_t)qrow * QSTR + qoff + 32 + lg * 8);

  f4 o4[4];                          // o4[n][r] = O^T[d=n*16+lg*4+r][q=li]
#pragma unroll
  for (int n = 0; n < 4; ++n) o4[n] = f4{0.f, 0.f, 0.f, 0.f};
  float m_run = -INFINITY, l_run = 0.f;   // per-lane (q=li)
  const int kt0 = sp * TILES;
  const int skey = lane >> 3;
  const int sslot = lane & 7;

#pragma unroll 1
  for (int ki = 0; ki < TILES; ++ki) {
    const int kb = (kt0 + ki) * 64;
#pragma unroll
    for (int j = 0; j < 2; ++j) {
      int row = w * 16 + j * 8 + skey;
      int gk = kb + row; if (gk >= L_) gk = L_ - 1;
      int ck = sslot ^ (row & 7);
      __builtin_amdgcn_global_load_lds(
          (const __attribute__((address_space(1))) void*)(Kg + (size_t)(b * L_ + gk) * KSTR + koff + ck * 8),
          (__attribute__((address_space(3))) void*)(Kt + (w * 16 + j * 8) * 64),
          16, 0, 0);
      int cv = sslot ^ (row & 7);
      __builtin_amdgcn_global_load_lds(
          (const __attribute__((address_space(1))) void*)(vtg + (size_t)row * LP_ + kb + cv * 8),
          (__attribute__((address_space(3))) void*)(Vt + (w * 16 + j * 8) * 64),
          16, 0, 0);
    }
    __syncthreads();
    f4 s[4];
#pragma unroll
    for (int c = 0; c < 4; ++c) {
      int key = c * 16 + li;
      s8v kf = *(const s8v*)(Kt + key * 64 + ((lg ^ (key & 7)) * 8));
      s8v kg2 = *(const s8v*)(Kt + key * 64 + (((lg + 4) ^ (key & 7)) * 8));
      f4 z = f4{0.f, 0.f, 0.f, 0.f};
      z = __builtin_amdgcn_mfma_f32_16x16x32_bf16(kf, qf0, z, 0, 0, 0);
      z = __builtin_amdgcn_mfma_f32_16x16x32_bf16(kg2, qf1, z, 0, 0, 0);
      s[c] = z * 0.125f;
    }
    if (kb + 64 > L_) {
#pragma unroll
      for (int c = 0; c < 4; ++c)
#pragma unroll
        for (int r = 0; r < 4; ++r)
          if (kb + c * 16 + lg * 4 + r >= L_) s[c][r] = -INFINITY;
    }
    float tm = -INFINITY;
#pragma unroll
    for (int c = 0; c < 4; ++c)
      tm = fmaxf(tm, fmaxf(fmaxf(s[c][0], s[c][1]), fmaxf(s[c][2], s[c][3])));
    tm = fmaxf(tm, __shfl_xor(tm, 16));
    tm = fmaxf(tm, __shfl_xor(tm, 32));
    // T13 defer-max: only rescale when some lane's max grew past threshold.
    if (!__all(tm <= m_run + 8.f)) {
      float mn = fmaxf(m_run, tm);
      float sc = __expf(m_run - mn);
      l_run *= sc;
      m_run = mn;
#pragma unroll
      for (int n = 0; n < 4; ++n) o4[n] *= sc;
    }
    float p[4][4];
    float rs = 0.f;
#pragma unroll
    for (int c = 0; c < 4; ++c)
#pragma unroll
      for (int r = 0; r < 4; ++r) { p[c][r] = __expf(s[c][r] - m_run); rs += p[c][r]; }
    rs += __shfl_xor(rs, 16);
    rs += __shfl_xor(rs, 32);
    l_run += rs;
    // pack P via v_cvt_pk_bf16_f32 (1 VALU op per pair vs ~9 manual)
#pragma unroll
    for (int c = 0; c < 4; ++c)
#pragma unroll
      for (int rp = 0; rp < 2; ++rp)
        xw[li * 36 + c * 8 + lg * 2 + rp] = cvt_pk(p[c][2 * rp], p[c][2 * rp + 1]);
    s8v pb0 = *(const s8v*)(xw + li * 36 + lg * 4);
    s8v pb1 = *(const s8v*)(xw + li * 36 + 16 + lg * 4);
#pragma unroll
    for (int n = 0; n < 4; ++n) {
      int dim = n * 16 + li;
      s8v vb0 = *(const s8v*)(Vt + dim * 64 + ((lg ^ (dim & 7)) * 8));
      o4[n] = __builtin_amdgcn_mfma_f32_16x16x32_bf16(vb0, pb0, o4[n], 0, 0, 0);
    }
#pragma unroll
    for (int n = 0; n < 4; ++n) {
      int dim = n * 16 + li;
      s8v vb1 = *(const s8v*)(Vt + dim * 64 + (((lg + 4) ^ (dim & 7)) * 8));
      o4[n] = __builtin_amdgcn_mfma_f32_16x16x32_bf16(vb1, pb1, o4[n], 0, 0, 0);
    }
    __syncthreads();
  }

  if (MODE == 0) {
    // per-wave LDS transpose [q][d] (packed stores), coalesced bf16 out
#pragma unroll
    for (int n = 0; n < 4; ++n)
#pragma unroll
      for (int rp = 0; rp < 2; ++rp)
        xw[li * 36 + n * 8 + lg * 2 + rp] = cvt_pk(o4[n][2 * rp], o4[n][2 * rp + 1]);
    u16* PO = sp ? POb : POa;
    const int pid = (bh * 24 + qb) * 2 + sp;
    int q_local = lane >> 2, d0 = (lane & 3) * 16;
    int q = qb * 64 + w * 16 + q_local;
    s8v v0 = *(const s8v*)(xw16 + q_local * 72 + d0);
    s8v v1 = *(const s8v*)(xw16 + q_local * 72 + d0 + 8);
    if (q < L_) {
      u16* dst = PO + ((size_t)(b * L_ + q)) * DM_ + qoff + d0;
      *(s8v*)dst = v0;
      *(s8v*)(dst + 8) = v1;
    }
    if (lg == 0) {
      PM[pid * 64 + w * 16 + li] = m_run;
      PL[pid * 64 + w * 16 + li] = l_run;
    }
  } else {
    int base = (bh * 8 + sp) * 64 + w * 16 + li;
#pragma unroll
    for (int n = 0; n < 4; ++n)
#pragma unroll
      for (int r = 0; r < 4; ++r)
        POf[(size_t)base * 64 + n * 16 + lg * 4 + r] = o4[n][r];
    if (lg == 0) {
      PM[base] = m_run;
      PL[base] = l_run;
    }
  }
}

// ---------------- combine 2-way cross partials (POb == ctxb, in place) ------
__global__ __launch_bounds__(256) void combine_cross(const u16* __restrict__ PO0,
                                                     const float* __restrict__ PM,
                                                     const float* __restrict__ PL,
                                                     u16* ctxb) {
  int idx = blockIdx.x * 256 + threadIdx.x;
  int row = idx >> 9, col = idx & 511;
  int b = row / L_, q = row - b * L_;
  int h = col >> 6;
  int bh = b * 8 + h, qbk = q >> 6, qi = q & 63;
  int p0 = ((bh * 24 + qbk) * 2) * 64 + qi;
  float m0 = PM[p0], m1 = PM[p0 + 64];
  float l0 = PL[p0], l1 = PL[p0 + 64];
  float M = fmaxf(m0, m1);
  float w0 = __expf(m0 - M), w1 = __expf(m1 - M);
  float inv = 1.f / (w0 * l0 + w1 * l1);
  float o0 = b2f(PO0[idx]);
  float o1 = b2f(ctxb[idx]);
  ctxb[idx] = f2b((w0 * o0 + w1 * o1) * inv);
}

// ---------------- fused combine split-K partials + scatter into ctxb --------
__global__ __launch_bounds__(256) void combine_prob_scatter(
    const float* __restrict__ PO, const float* __restrict__ PM,
    const float* __restrict__ PL, const int* __restrict__ top,
    u16* __restrict__ ctxb) {
  int bh = blockIdx.x;
  int t = threadIdx.x;
  int u = t >> 2, dg = (t & 3) * 16;
  if (u >= SK_) return;
  float M = -INFINITY;
  for (int s = 0; s < 8; ++s) M = fmaxf(M, PM[(bh * 8 + s) * 64 + u]);
  float wgt[8];
  float den = 0.f;
  for (int s = 0; s < 8; ++s) {
    wgt[s] = __expf(PM[(bh * 8 + s) * 64 + u] - M);
    den += wgt[s] * PL[(bh * 8 + s) * 64 + u];
  }
  float inv = 1.f / den;
  int h = bh & 7, b = bh >> 3;
  int l = top[bh * SK_ + u];
  u16* dst = ctxb + ((size_t)(b * L_ + l)) * DM_ + h * 64;
  for (int d = dg; d < dg + 16; ++d) {
    float acc = 0.f;
    for (int s = 0; s < 8; ++s) acc += wgt[s] * PO[(((size_t)bh * 8 + s) * 64 + u) * 64 + d];
    dst[d] = f2b(acc * inv);
  }
}

// ---------------- ctx = broadcast vmean (24 tile-partials inline) -----------
__global__ __launch_bounds__(256) void fill_ctx(const float* __restrict__ part,
                                                u16* __restrict__ ctxb) {
  int idx = blockIdx.x * 256 + threadIdx.x;
  int d = idx % 64;
  int h = (idx / 64) % H_;
  int b = idx / (L_ * DM_);
  int bh = b * 8 + h;
  float s = 0.f;
#pragma unroll
  for (int seg = 0; seg < 24; ++seg) s += part[((size_t)bh * 24 + seg) * 64 + d];
  ctxb[idx] = f2b(s * (1.f / (float)L_));
}

// ---------------- host side --------------------------------------------------
extern "C" void kernel_launch(void* const* d_in, const int* in_sizes, int n_in,
                              void* d_out, int out_size, void* d_ws, size_t ws_size,
                              hipStream_t stream) {
  const float* inflow   = (const float*)d_in[4];
  const float* W_emb_e  = (const float*)d_in[5];
  const float* b_emb_e  = (const float*)d_in[6];
  const float* W_emb_d  = (const float*)d_in[7];
  const float* b_emb_d  = (const float*)d_in[8];
  const float* enc_Wqkv = (const float*)d_in[9];
  const float* enc_bqkv = (const float*)d_in[10];
  const float* enc_Wo   = (const float*)d_in[11];
  const float* enc_bo   = (const float*)d_in[12];
  const float* enc_ln1g = (const float*)d_in[13];
  const float* enc_ln1b = (const float*)d_in[14];
  const float* enc_Wf1  = (const float*)d_in[15];
  const float* enc_bf1  = (const float*)d_in[16];
  const float* enc_Wf2  = (const float*)d_in[17];
  const float* enc_bf2  = (const float*)d_in[18];
  const float* enc_ln2g = (const float*)d_in[19];
  const float* enc_ln2b = (const float*)d_in[20];
  const float* enc_ng   = (const float*)d_in[21];
  const float* enc_nb   = (const float*)d_in[22];
  const float* dec_Wqkv = (const float*)d_in[23];
  const float* dec_bqkv = (const float*)d_in[24];
  const float* dec_Wo_s = (const float*)d_in[25];
  const float* dec_bo_s = (const float*)d_in[26];
  const float* dec_ln1g = (const float*)d_in[27];
  const float* dec_ln1b = (const float*)d_in[28];
  const float* dec_Wq_c = (const float*)d_in[29];
  const float* dec_bq_c = (const float*)d_in[30];
  const float* dec_Wkv  = (const float*)d_in[31];
  const float* dec_bkv  = (const float*)d_in[32];
  const float* dec_Wo_c = (const float*)d_in[33];
  const float* dec_bo_c = (const float*)d_in[34];
  const float* dec_ln2g = (const float*)d_in[35];
  const float* dec_ln2b = (const float*)d_in[36];
  const float* dec_Wf1  = (const float*)d_in[37];
  const float* dec_bf1  = (const float*)d_in[38];
  const float* dec_Wf2  = (const float*)d_in[39];
  const float* dec_bf2  = (const float*)d_in[40];
  const float* dec_ln3g = (const float*)d_in[41];
  const float* dec_ln3b = (const float*)d_in[42];
  const float* W_proj   = (const float*)d_in[43];
  const float* b_proj   = (const float*)d_in[44];
  const float* W1       = (const float*)d_in[45];
  const float* b1       = (const float*)d_in[46];
  const float* W3       = (const float*)d_in[47];
  const float* b3       = (const float*)d_in[48];
  const int*   samp     = (const int*)d_in[49];
  float* out = (float*)d_out;

  float* ws  = (float*)d_ws;
  float* PE  = ws;                       // 778240 f (dead after embeds -> PMc/PLc)
  float* X   = PE + 778240;              // 72960 f
  float* ACT = X + 72960;                // 3112960 f
  float* REG = ACT + 3112960;            // 6291456 f shared region
  float* MME = REG + 6291456;            // 48640 f
  float* CTT = MME + 48640;              // 81920 f (VME24: 49152 f)
  float* VME = CTT + 81920;              // 2048 f (unused)
  int*   TOP = (int*)(VME + 2048);       // 1280 i
  float* TAIL = VME + 2048 + 1280;
  u16* ENCb = (u16*)TAIL;                       // 6144*512 u16
  u16* DECb = (u16*)(TAIL + 1572864);
  u16* CTXb = (u16*)(TAIL + 2 * 1572864);
  u16* WBF  = (u16*)(TAIL + 3 * 1572864);       // 10485760 u16
  // prob split-K partials: FRESH memory after WBF (no CTXb overlay)
  float* POp = (float*)(WBF + 10485760);        // 1048576 f
  float* PMp = POp + 1048576;                   // 16384 f
  float* PLp = PMp + 16384;                     // 16384 f
  u16*   PO0 = (u16*)(PLp + 16384);             // cross split-0 partials [6144][512]

  // region overlays (prob phase)
  u16* QKVb = (u16*)REG;                 // [6144][1536]
  u16* FFb  = (u16*)REG;                 // [6144][2048]
  u16* VT   = (u16*)REG + 9437184;       // [32][64][1536] u16
  // region overlays (cross phase)
  u16* QCb  = (u16*)REG;                 // [6144][512]
  u16* KVCb = (u16*)REG + 3145728;       // [6144][1024] (K at +0, V at +512)
  // cross partial stats in dead PE region (32*24*2*64 = 98304 each)
  float* PMc = PE;
  float* PLc = PE + 98304;
  float* VME24 = CTT;                    // 32*24*64 = 49152 f

  auto GB = [&](const u16* A, const u16* Bt, const float* bias, const float* res,
                float* Cf, u16* Cb, int N, int K, int act) {
    if (N <= 512) {
      dim3 g(N / 128, MP_ / 64);
      gemm_bf16_k64<<<g, 256, 0, stream>>>(A, Bt, bias, res, Cf, Cb, N, K, act);
    } else {
      dim3 g(N / 128, MP_ / 128);
      gemm_bf16_128<<<g, 256, 0, stream>>>(A, Bt, bias, res, Cf, Cb, N, K, act);
    }
  };
  auto PROB = [&](const int* sidx) {
    probM<<<B_ * H_ * L_ / 4, 256, 0, stream>>>(QKVb, sidx, MME);
    radix_topk<<<B_ * H_, 256, 0, stream>>>(MME, TOP);
    transpose_v<<<B_ * H_ * 24, 256, 0, stream>>>(QKVb, 1536, 1024, VT, VME24);
    flash_attn<1><<<B_ * H_ * 8, 256, 0, stream>>>(QKVb, QKVb, VT, TOP, POp,
                                                   nullptr, nullptr, PMp, PLp);
    fill_ctx<<<ML_ * DM_ / 256, 256, 0, stream>>>(VME24, CTXb);
    combine_prob_scatter<<<B_ * H_, 256, 0, stream>>>(POp, PMp, PLp, TOP, CTXb);
  };

  pe_kernel<<<(L_ * DM_ + 255) / 256, 256, 0, stream>>>(PE);
  extract_x<<<(ML_ * 12 + 255) / 256, 256, 0, stream>>>(inflow, X);

  // one fused weight-conversion dispatch (LDS tiled transpose)
  {
    CvtArgs a;
    const float* s[15] = {
      enc_Wqkv, enc_Wqkv + 512 * 1536, enc_Wo, enc_Wo + 512 * 512,
      enc_Wf1, enc_Wf1 + 512 * 2048, enc_Wf2, enc_Wf2 + 2048 * 512,
      dec_Wqkv, dec_Wo_s, dec_Wq_c, dec_Wkv, dec_Wo_c, dec_Wf1, dec_Wf2 };
    unsigned cumt[16] = { 0u, 768u, 1536u, 1792u, 2048u, 3072u,
                          4096u, 5120u, 6144u, 6912u, 7168u,
                          7424u, 7936u, 8192u, 9216u, 10240u };
    unsigned lk[15] = { 9, 9, 9, 9, 9, 9, 11, 11, 9, 9, 9, 9, 9, 9, 11 };
    for (int i = 0; i < 15; ++i) { a.src[i] = s[i]; a.lk[i] = lk[i]; }
    for (int i = 0; i < 16; ++i) a.cumt[i] = cumt[i];
    cvt_all<<<10240, 256, 0, stream>>>(a, WBF);
  }
  u16* Wt_qkv_e0 = WBF + 0;
  u16* Wt_qkv_e1 = WBF + 786432;
  u16* Wt_o_e0   = WBF + 1572864;
  u16* Wt_o_e1   = WBF + 1835008;
  u16* Wt_f1_e0  = WBF + 2097152;
  u16* Wt_f1_e1  = WBF + 3145728;
  u16* Wt_f2_e0  = WBF + 4194304;
  u16* Wt_f2_e1  = WBF + 5242880;
  u16* Wt_qkv_d  = WBF + 6291456;
  u16* Wt_o_s    = WBF + 7077888;
  u16* Wt_q_c    = WBF + 7340032;
  u16* Wt_kv_c   = WBF + 7602176;
  u16* Wt_o_c    = WBF + 8126464;
  u16* Wt_f1_d   = WBF + 8388608;
  u16* Wt_f2_d   = WBF + 9437184;

  // ---------------- encoder ----------------
  embed_fused<<<MP_ / 4, 256, 0, stream>>>(X, W_emb_e, b_emb_e, PE, ACT, ENCb);

  const u16* Wqkv_e[2] = {Wt_qkv_e0, Wt_qkv_e1};
  const u16* Wo_e[2]   = {Wt_o_e0, Wt_o_e1};
  const u16* Wf1_e[2]  = {Wt_f1_e0, Wt_f1_e1};
  const u16* Wf2_e[2]  = {Wt_f2_e0, Wt_f2_e1};
  for (int i = 0; i < 2; ++i) {
    GB(ENCb, Wqkv_e[i], enc_bqkv + i * 1536, nullptr, nullptr, QKVb, 1536, 512, 0);
    PROB(samp + (size_t)i * L_ * SK_);
    GB(CTXb, Wo_e[i], enc_bo + i * 512, ACT, ACT, nullptr, 512, 512, 0);
    layernorm_ip<<<ML_ / 4, 256, 0, stream>>>(ACT, enc_ln1g + i * 512, enc_ln1b + i * 512, ENCb);
    GB(ENCb, Wf1_e[i], enc_bf1 + i * 2048, nullptr, nullptr, FFb, 2048, 512, 1);
    GB(FFb, Wf2_e[i], enc_bf2 + i * 512, ACT, ACT, nullptr, 512, 2048, 0);
    layernorm_ip<<<ML_ / 4, 256, 0, stream>>>(ACT, enc_ln2g + i * 512, enc_ln2b + i * 512, ENCb);
  }
  layernorm_ip<<<ML_ / 4, 256, 0, stream>>>(ACT, enc_ng, enc_nb, ENCb);

  // ---------------- decoder ----------------
  embed_fused<<<MP_ / 4, 256, 0, stream>>>(X, W_emb_d, b_emb_d, PE, ACT, DECb);
  GB(DECb, Wt_qkv_d, dec_bqkv, nullptr, nullptr, QKVb, 1536, 512, 0);
  PROB(samp + (size_t)2 * L_ * SK_);
  GB(CTXb, Wt_o_s, dec_bo_s, ACT, ACT, nullptr, 512, 512, 0);
  layernorm_ip<<<ML_ / 4, 256, 0, stream>>>(ACT, dec_ln1g, dec_ln1b, DECb);

  // cross attention: Q GEMM + merged K/V GEMM (N=1024, KVC layout)
  GB(DECb, Wt_q_c, dec_bq_c, nullptr, nullptr, QCb, 512, 512, 0);
  GB(ENCb, Wt_kv_c, dec_bkv, nullptr, nullptr, KVCb, 1024, 512, 0);
  transpose_v<<<B_ * H_ * 24, 256, 0, stream>>>(KVCb, 1024, 512, VT, nullptr);
  flash_attn<0><<<B_ * H_ * 48, 256, 0, stream>>>(QCb, KVCb, VT, nullptr, nullptr,
                                                  PO0, CTXb, PMc, PLc);
  combine_cross<<<ML_ * DM_ / 256, 256, 0, stream>>>(PO0, PMc, PLc, CTXb);
  GB(CTXb, Wt_o_c, dec_bo_c, ACT, ACT, nullptr, 512, 512, 0);
  layernorm_ip<<<ML_ / 4, 256, 0, stream>>>(ACT, dec_ln2g, dec_ln2b, DECb);

  GB(DECb, Wt_f1_d, dec_bf1, nullptr, nullptr, FFb, 2048, 512, 1);
  GB(FFb, Wt_f2_d, dec_bf2, ACT, ACT, nullptr, 512, 2048, 0);
  layernorm_ip<<<ML_ / 4, 256, 0, stream>>>(ACT, dec_ln3g, dec_ln3b, DECb);

  // fused head
  head_fused<<<ML_ / 4, 256, 0, stream>>>(ACT, X, W_proj, b_proj, W1, b1, W3, b3, out);
}

// Round 17
// 841.023 us; speedup vs baseline: 1.2427x; 1.0019x over previous
//
#include <hip/hip_runtime.h>
#include <math.h>

#define B_ 4
#define H_ 8
#define L_ 1520
#define DM_ 512
#define DFF_ 2048
#define SK_ 40
#define ML_ (B_*L_)   /* 6080 rows */
#define MP_ 6144      /* padded rows for MFMA GEMM */
#define LP_ 1536      /* padded key count for V^T */

typedef unsigned short u16;
typedef short s8v __attribute__((ext_vector_type(8)));
typedef float f4 __attribute__((ext_vector_type(4)));

__device__ __forceinline__ u16 f2b(float x) {
  union { float f; unsigned u; } c; c.f = x;
  unsigned r = c.u + 0x7FFFu + ((c.u >> 16) & 1u);
  return (u16)(r >> 16);
}
__device__ __forceinline__ float b2f(u16 h) {
  union { unsigned u; float f; } c; c.u = ((unsigned)h) << 16;
  return c.f;
}
// packed f32 pair -> 2x bf16 in one u32 (lo = a, hi = b); single VALU op
__device__ __forceinline__ unsigned cvt_pk(float a, float b) {
  unsigned r;
  asm volatile("v_cvt_pk_bf16_f32 %0, %1, %2" : "=v"(r) : "v"(a), "v"(b));
  return r;
}
__device__ __forceinline__ float gelu_tanh(float x) {
  float x3 = x * x * x;
  return 0.5f * x * (1.f + tanhf(0.79788456080286536f * (x + 0.044715f * x3)));
}
// XCD-chunked bijective swizzle; requires nwg % 8 == 0 (cpx = nwg/8).
__device__ __forceinline__ int xswz(int bid, int cpx) {
  return (bid & 7) * cpx + (bid >> 3);
}

// ---------------- positional encoding (double precision to match numpy) ----
__global__ __launch_bounds__(256) void pe_kernel(float* __restrict__ pe) {
  int idx = blockIdx.x * 256 + threadIdx.x;
  if (idx >= L_ * DM_) return;
  int pos = idx / DM_, i = idx % DM_;
  double expo = (double)(2 * (i / 2)) / (double)DM_;
  double ang = (double)pos / pow(10000.0, expo);
  pe[idx] = (i & 1) ? (float)cos(ang) : (float)sin(ang);
}

// ---------------- x = inflow[:,2:14].reshape (contiguous slice) -------------
__global__ __launch_bounds__(256) void extract_x(const float* __restrict__ inflow,
                                                 float* __restrict__ X) {
  int idx = blockIdx.x * 256 + threadIdx.x;
  if (idx >= ML_ * 12) return;
  int b = idx / (L_ * 12);
  int rem = idx - b * (L_ * 12);
  X[idx] = inflow[(size_t)b * 14 * L_ + 2 * L_ + rem];
}

// ---------------- fused weight convert+transpose (LDS tiled, coalesced) -----
struct CvtArgs {
  const float* src[15];
  unsigned cumt[16];   // cumulative 32x32-tile counts
  unsigned lk[15];     // log2(K) per segment
};
__global__ __launch_bounds__(256) void cvt_all(CvtArgs a, u16* __restrict__ dst) {
  __shared__ float tl[32][33];
  int bt = blockIdx.x;                 // grid exact: 10240 tiles
  int s = 0;
#pragma unroll
  for (int i = 1; i < 15; ++i) s += (bt >= (int)a.cumt[i]);
  int lt = bt - a.cumt[s];
  unsigned lk = a.lk[s];
  unsigned K = 1u << lk;
  unsigned N = ((a.cumt[s + 1] - a.cumt[s]) << 10) >> lk;
  unsigned tiles_n = N >> 5;
  unsigned k0 = (lt / tiles_n) * 32, n0 = (lt % tiles_n) * 32;
  const float* src = a.src[s];
  int r = threadIdx.x >> 5, c = threadIdx.x & 31;
#pragma unroll
  for (int i = 0; i < 4; ++i)
    tl[r + 8 * i][c] = src[(size_t)(k0 + r + 8 * i) * N + n0 + c];
  __syncthreads();
  u16* d = dst + ((size_t)a.cumt[s] << 10);
#pragma unroll
  for (int i = 0; i < 4; ++i)
    d[(size_t)(n0 + r + 8 * i) * K + k0 + c] = f2b(tl[c][r + 8 * i]);
}

// ---------------- fused embed: ACT = X@W + b + PE ; ACTb = bf16(ACT) --------
__global__ __launch_bounds__(256) void embed_fused(
    const float* __restrict__ X, const float* __restrict__ W,
    const float* __restrict__ bias, const float* __restrict__ PE,
    float* __restrict__ ACT, u16* __restrict__ ACTb) {
  int row = blockIdx.x * 4 + (threadIdx.x >> 6);
  int lane = threadIdx.x & 63;
  int d0 = lane * 8;
  if (row >= ML_) {
    s8v z = {0, 0, 0, 0, 0, 0, 0, 0};
    *(s8v*)(ACTb + (size_t)row * DM_ + d0) = z;
    return;
  }
  int prow = row % L_;
  f4 a0 = *(const f4*)(bias + d0);
  f4 a1 = *(const f4*)(bias + d0 + 4);
  a0 += *(const f4*)(PE + (size_t)prow * DM_ + d0);
  a1 += *(const f4*)(PE + (size_t)prow * DM_ + d0 + 4);
  const float* xr = X + (size_t)row * 12;
#pragma unroll
  for (int t = 0; t < 12; ++t) {
    float xv = xr[t];
    a0 += xv * *(const f4*)(W + (size_t)t * DM_ + d0);
    a1 += xv * *(const f4*)(W + (size_t)t * DM_ + d0 + 4);
  }
  float* dst = ACT + (size_t)row * DM_ + d0;
  *(f4*)dst = a0;
  *(f4*)(dst + 4) = a1;
  unsigned ob[4];
  ob[0] = cvt_pk(a0[0], a0[1]); ob[1] = cvt_pk(a0[2], a0[3]);
  ob[2] = cvt_pk(a1[0], a1[1]); ob[3] = cvt_pk(a1[2], a1[3]);
  *(s8v*)(ACTb + (size_t)row * DM_ + d0) = *(s8v*)ob;
}

// ---------------- fused head: out = relu((DEC@Wp+bp+X)@W1+b1)@W3+b3 ---------
__global__ __launch_bounds__(256) void head_fused(
    const float* __restrict__ DEC, const float* __restrict__ X,
    const float* __restrict__ Wp, const float* __restrict__ bp,
    const float* __restrict__ W1, const float* __restrict__ b1,
    const float* __restrict__ W3, const float* __restrict__ b3,
    float* __restrict__ out) {
  int row = blockIdx.x * 4 + (threadIdx.x >> 6);
  int lane = threadIdx.x & 63;
  int d0 = lane * 8;
  const float* dec = DEC + (size_t)row * DM_ + d0;
  f4 v0 = *(const f4*)dec;
  f4 v1 = *(const f4*)(dec + 4);
  float pj[12];
#pragma unroll
  for (int j = 0; j < 12; ++j) pj[j] = 0.f;
#pragma unroll
  for (int i = 0; i < 8; ++i) {
    float dv = (i < 4) ? v0[i] : v1[i - 4];
    const float* wr = Wp + (size_t)(d0 + i) * 12;
#pragma unroll
    for (int j = 0; j < 12; ++j) pj[j] += dv * wr[j];
  }
  for (int off = 32; off; off >>= 1) {
#pragma unroll
    for (int j = 0; j < 12; ++j) pj[j] += __shfl_xor(pj[j], off);
  }
  float o12[12];
#pragma unroll
  for (int j = 0; j < 12; ++j) o12[j] = pj[j] + bp[j] + X[(size_t)row * 12 + j];
  int k0 = lane * 2;
  float h0 = b1[k0], h1 = b1[k0 + 1];
#pragma unroll
  for (int j = 0; j < 12; ++j) {
    h0 += o12[j] * W1[j * 128 + k0];
    h1 += o12[j] * W1[j * 128 + k0 + 1];
  }
  h0 = fmaxf(h0, 0.f);
  h1 = fmaxf(h1, 0.f);
  float op[3];
#pragma unroll
  for (int p = 0; p < 3; ++p)
    op[p] = h0 * W3[k0 * 3 + p] + h1 * W3[(k0 + 1) * 3 + p];
  for (int off = 32; off; off >>= 1) {
#pragma unroll
    for (int p = 0; p < 3; ++p) op[p] += __shfl_xor(op[p], off);
  }
  if (lane == 0) {
#pragma unroll
    for (int p = 0; p < 3; ++p) out[(size_t)row * 3 + p] = op[p] + b3[p];
  }
}

// ---------------- bf16 MFMA GEMM, BM=128/BK=32, single-buffered -------------
__global__ __launch_bounds__(256) void gemm_bf16_128(
    const u16* __restrict__ A, const u16* __restrict__ Bt,
    const float* __restrict__ bias, const float* __restrict__ res,
    float* __restrict__ Cf, u16* __restrict__ Cb,
    int N, int K, int act) {
  __shared__ __align__(16) u16 As[128 * 32];
  __shared__ __align__(16) u16 Bs[128 * 32];
  const int nwg = gridDim.x * gridDim.y;
  const int lin = blockIdx.y * gridDim.x + blockIdx.x;
  const int o = xswz(lin, nwg >> 3);
  const int bxi = o % gridDim.x, byi = o / gridDim.x;
  const int t = threadIdx.x, w = t >> 6, lane = t & 63;
  const int lg = lane >> 4, li = lane & 15;
  const int bm = byi * 128, bn = bxi * 128;
  const int wr = (w >> 1) * 64, wc = (w & 1) * 64;
  f4 acc[4][4];
#pragma unroll
  for (int i = 0; i < 4; ++i)
#pragma unroll
    for (int j = 0; j < 4; ++j) acc[i][j] = f4{0.f, 0.f, 0.f, 0.f};
  const int rB = w * 32 + (lane >> 2);
  const int ps = lane & 3;
  for (int k0 = 0; k0 < K; k0 += 32) {
#pragma unroll
    for (int j = 0; j < 2; ++j) {
      int r = rB + j * 16;
      int ls = ps ^ ((r >> 1) & 3);
      __builtin_amdgcn_global_load_lds(
          (const __attribute__((address_space(1))) void*)(A + (size_t)(bm + r) * K + k0 + ls * 8),
          (__attribute__((address_space(3))) void*)(As + (w * 32 + j * 16) * 32),
          16, 0, 0);
      __builtin_amdgcn_global_load_lds(
          (const __attribute__((address_space(1))) void*)(Bt + (size_t)(bn + r) * K + k0 + ls * 8),
          (__attribute__((address_space(3))) void*)(Bs + (w * 32 + j * 16) * 32),
          16, 0, 0);
    }
    __syncthreads();
    s8v af[4], bf[4];
#pragma unroll
    for (int f = 0; f < 4; ++f) {
      int ra = wr + f * 16 + li;
      af[f] = *(const s8v*)(As + ra * 32 + ((lg ^ ((ra >> 1) & 3)) * 8));
      int rb = wc + f * 16 + li;
      bf[f] = *(const s8v*)(Bs + rb * 32 + ((lg ^ ((rb >> 1) & 3)) * 8));
    }
#pragma unroll
    for (int fi = 0; fi < 4; ++fi)
#pragma unroll
      for (int fj = 0; fj < 4; ++fj)
        acc[fi][fj] = __builtin_amdgcn_mfma_f32_16x16x32_bf16(af[fi], bf[fj], acc[fi][fj], 0, 0, 0);
    __syncthreads();
  }
#pragma unroll
  for (int fi = 0; fi < 4; ++fi)
#pragma unroll
    for (int fj = 0; fj < 4; ++fj)
#pragma unroll
      for (int r = 0; r < 4; ++r) {
        int row = bm + wr + fi * 16 + lg * 4 + r;
        int col = bn + wc + fj * 16 + li;
        float v = acc[fi][fj][r] + bias[col];
        if (res && row < ML_) v += res[(size_t)row * N + col];
        if (act == 1) v = gelu_tanh(v);
        if (Cf && row < ML_) Cf[(size_t)row * N + col] = v;
        if (Cb) Cb[(size_t)row * N + col] = f2b(v);
      }
}

// ---------------- bf16 MFMA GEMM, BM=64/BK=64: half the barrier drains ------
// Stage both 32-wide K-halves in one phase (linear LDS dest, source col
// pre-XOR'd by row&7; reads apply same XOR -> 2-way bank aliasing, free).
__global__ __launch_bounds__(256) void gemm_bf16_k64(
    const u16* __restrict__ A, const u16* __restrict__ Bt,
    const float* __restrict__ bias, const float* __restrict__ res,
    float* __restrict__ Cf, u16* __restrict__ Cb,
    int N, int K, int act) {
  __shared__ __align__(16) u16 As[64 * 64];
  __shared__ __align__(16) u16 Bs[128 * 64];
  const int nwg = gridDim.x * gridDim.y;
  const int lin = blockIdx.y * gridDim.x + blockIdx.x;
  const int o = xswz(lin, nwg >> 3);
  const int bxi = o % gridDim.x, byi = o / gridDim.x;
  const int t = threadIdx.x, w = t >> 6, lane = t & 63;
  const int lg = lane >> 4, li = lane & 15;
  const int bm = byi * 64, bn = bxi * 128;
  const int wr = (w >> 1) * 32, wc = (w & 1) * 64;
  f4 acc[2][4];
#pragma unroll
  for (int i = 0; i < 2; ++i)
#pragma unroll
    for (int j = 0; j < 4; ++j) acc[i][j] = f4{0.f, 0.f, 0.f, 0.f};
  const int rloc = lane >> 3;          // 0..7 rows per wave-instruction
  const int slot = lane & 7;           // physical 16B slot written
  for (int k0 = 0; k0 < K; k0 += 64) {
    // A: 64 rows, 2 wave-instructions of 8 rows each per wave
#pragma unroll
    for (int j = 0; j < 2; ++j) {
      int r = w * 8 + j * 32 + rloc;
      int ls = slot ^ (r & 7);
      __builtin_amdgcn_global_load_lds(
          (const __attribute__((address_space(1))) void*)(A + (size_t)(bm + r) * K + k0 + ls * 8),
          (__attribute__((address_space(3))) void*)(As + (w * 8 + j * 32) * 64),
          16, 0, 0);
    }
    // B: 128 rows, 4 wave-instructions
#pragma unroll
    for (int j = 0; j < 4; ++j) {
      int r = w * 8 + j * 32 + rloc;
      int ls = slot ^ (r & 7);
      __builtin_amdgcn_global_load_lds(
          (const __attribute__((address_space(1))) void*)(Bt + (size_t)(bn + r) * K + k0 + ls * 8),
          (__attribute__((address_space(3))) void*)(Bs + (w * 8 + j * 32) * 64),
          16, 0, 0);
    }
    __syncthreads();
#pragma unroll
    for (int ks = 0; ks < 2; ++ks) {
      s8v af[2], bf[4];
#pragma unroll
      for (int f = 0; f < 2; ++f) {
        int ra = wr + f * 16 + li;
        af[f] = *(const s8v*)(As + ra * 64 + (((ks * 4 + lg) ^ (ra & 7)) * 8));
      }
#pragma unroll
      for (int f = 0; f < 4; ++f) {
        int rb = wc + f * 16 + li;
        bf[f] = *(const s8v*)(Bs + rb * 64 + (((ks * 4 + lg) ^ (rb & 7)) * 8));
      }
#pragma unroll
      for (int fi = 0; fi < 2; ++fi)
#pragma unroll
        for (int fj = 0; fj < 4; ++fj)
          acc[fi][fj] = __builtin_amdgcn_mfma_f32_16x16x32_bf16(af[fi], bf[fj], acc[fi][fj], 0, 0, 0);
    }
    __syncthreads();
  }
#pragma unroll
  for (int fi = 0; fi < 2; ++fi)
#pragma unroll
    for (int fj = 0; fj < 4; ++fj)
#pragma unroll
      for (int r = 0; r < 4; ++r) {
        int row = bm + wr + fi * 16 + lg * 4 + r;
        int col = bn + wc + fj * 16 + li;
        float v = acc[fi][fj][r] + bias[col];
        if (res && row < ML_) v += res[(size_t)row * N + col];
        if (act == 1) v = gelu_tanh(v);
        if (Cf && row < ML_) Cf[(size_t)row * N + col] = v;
        if (Cb) Cb[(size_t)row * N + col] = f2b(v);
      }
}

// ---------------- layernorm: wave per row, vectorized -----------------------
__global__ __launch_bounds__(256) void layernorm_ip(float* __restrict__ Xb,
                                                    const float* __restrict__ g,
                                                    const float* __restrict__ bta,
                                                    u16* __restrict__ outb) {
  int row = blockIdx.x * 4 + (threadIdx.x >> 6);
  int lane = threadIdx.x & 63;
  float* x = Xb + (size_t)row * DM_;
  f4 a = *(f4*)(x + lane * 8);
  f4 b = *(f4*)(x + lane * 8 + 4);
  float s = a[0] + a[1] + a[2] + a[3] + b[0] + b[1] + b[2] + b[3];
  for (int off = 32; off; off >>= 1) s += __shfl_xor(s, off);
  float mu = s * (1.f / 512.f);
  float vs = 0.f;
#pragma unroll
  for (int i = 0; i < 4; ++i) { a[i] -= mu; b[i] -= mu; vs += a[i] * a[i] + b[i] * b[i]; }
  for (int off = 32; off; off >>= 1) vs += __shfl_xor(vs, off);
  float rs = rsqrtf(vs * (1.f / 512.f) + 1e-5f);
  f4 g0 = *(const f4*)(g + lane * 8), g1 = *(const f4*)(g + lane * 8 + 4);
  f4 c0 = *(const f4*)(bta + lane * 8), c1 = *(const f4*)(bta + lane * 8 + 4);
  float r0 = a[0] * rs * g0[0] + c0[0];
  float r1 = a[1] * rs * g0[1] + c0[1];
  float r2 = a[2] * rs * g0[2] + c0[2];
  float r3 = a[3] * rs * g0[3] + c0[3];
  float r4 = b[0] * rs * g1[0] + c1[0];
  float r5 = b[1] * rs * g1[1] + c1[1];
  float r6 = b[2] * rs * g1[2] + c1[2];
  float r7 = b[3] * rs * g1[3] + c1[3];
  x[lane * 8 + 0] = r0; x[lane * 8 + 1] = r1; x[lane * 8 + 2] = r2; x[lane * 8 + 3] = r3;
  x[lane * 8 + 4] = r4; x[lane * 8 + 5] = r5; x[lane * 8 + 6] = r6; x[lane * 8 + 7] = r7;
  unsigned ob[4];
  ob[0] = cvt_pk(r0, r1); ob[1] = cvt_pk(r2, r3);
  ob[2] = cvt_pk(r4, r5); ob[3] = cvt_pk(r6, r7);
  *(s8v*)(outb + (size_t)row * DM_ + lane * 8) = *(s8v*)ob;
}

// ---------------- ProbSparse sparsity measure M (bf16 qkv), swizzled --------
__global__ __launch_bounds__(256) void probM(const u16* __restrict__ qkv,
                                             const int* __restrict__ sidx,
                                             float* __restrict__ Mout) {
  int wid = threadIdx.x / 64, lane = threadIdx.x % 64;
  int o = xswz(blockIdx.x, (B_ * H_ * L_ / 4) >> 3);
  int g = o * 4 + wid;
  int l = g % L_;
  int bh = g / L_;
  int h = bh % H_, b = bh / H_;
  __shared__ float qs[4][64];
  qs[wid][lane] = b2f(qkv[((size_t)b * L_ + l) * 1536 + h * 64 + lane]);
  __syncthreads();
  float dot = 0.f;
  if (lane < SK_) {
    int ks = sidx[l * SK_ + lane];
    const u16* kr = qkv + ((size_t)b * L_ + ks) * 1536 + 512 + h * 64;
#pragma unroll
    for (int j = 0; j < 8; ++j) {
      s8v v = *(const s8v*)(kr + j * 8);
#pragma unroll
      for (int i = 0; i < 8; ++i) dot += qs[wid][j * 8 + i] * b2f((u16)v[i]);
    }
  }
  float vmax = (lane < SK_) ? dot : -INFINITY;
  float vsum = (lane < SK_) ? dot : 0.f;
  for (int off = 32; off; off >>= 1) {
    vmax = fmaxf(vmax, __shfl_xor(vmax, off));
    vsum += __shfl_xor(vsum, off);
  }
  if (lane == 0) Mout[g] = vmax - vsum / (float)L_;
}

// ---------------- radix-select top-40 (matches lax.top_k selection set) -----
__global__ __launch_bounds__(256) void radix_topk(const float* __restrict__ Mv,
                                                  int* __restrict__ top) {
  const int bh = blockIdx.x;
  const int t = threadIdx.x;
  const int base = t * 6;
  unsigned key[6];
#pragma unroll
  for (int i = 0; i < 6; ++i) {
    int ix = base + i;
    unsigned k = 0u;
    if (ix < L_) {
      union { float f; unsigned u; } c; c.f = Mv[(size_t)bh * L_ + ix];
      k = c.u ^ ((c.u & 0x80000000u) ? 0xFFFFFFFFu : 0x80000000u);
    }
    key[i] = k;
  }
  __shared__ int wred[4];
  __shared__ int s_a[256], s_b[256];
  unsigned prefix = 0u;
  for (int b = 31; b >= 0; --b) {
    unsigned cand = prefix | (1u << b);
    int c = 0;
#pragma unroll
    for (int i = 0; i < 6; ++i) c += (key[i] >= cand);
    for (int off = 32; off; off >>= 1) c += __shfl_xor(c, off);
    if ((t & 63) == 0) wred[t >> 6] = c;
    __syncthreads();
    int tot = wred[0] + wred[1] + wred[2] + wred[3];
    if (tot >= SK_) prefix = cand;
    __syncthreads();
  }
  const unsigned T = prefix;
  int gt = 0, tie = 0;
#pragma unroll
  for (int i = 0; i < 6; ++i) { gt += (key[i] > T); tie += (key[i] == T); }
  s_a[t] = gt; s_b[t] = tie;
  __syncthreads();
  for (int off = 1; off < 256; off <<= 1) {
    int va = (t >= off) ? s_a[t - off] : 0;
    int vb = (t >= off) ? s_b[t - off] : 0;
    __syncthreads();
    s_a[t] += va; s_b[t] += vb;
    __syncthreads();
  }
  const int n_strict = s_a[255];
  const int gt_base = s_a[t] - gt;
  const int tie_base = s_b[t] - tie;
  const int need = SK_ - n_strict;
  int lgt = 0, ltie = 0;
#pragma unroll
  for (int i = 0; i < 6; ++i) {
    int ix = base + i;
    if (key[i] > T) {
      top[bh * SK_ + gt_base + lgt] = ix; ++lgt;
    } else if (key[i] == T) {
      int r = tie_base + ltie; ++ltie;
      if (r < need) top[bh * SK_ + n_strict + r] = ix;
    }
  }
}

// ---------------- V^T build + fused per-tile V column sums ------------------
__global__ __launch_bounds__(256) void transpose_v(const u16* __restrict__ src,
                                                   int stride, int voff0,
                                                   u16* __restrict__ VT,
                                                   float* __restrict__ vpart) {
  int o = xswz(blockIdx.x, (B_ * H_ * 24) >> 3);
  int kt = o % 24, bh = o / 24;
  int h = bh & 7, b = bh >> 3;
  int kb = kt * 64;
  __shared__ u16 tile[64][72];
  int t = threadIdx.x;
#pragma unroll
  for (int rr = 0; rr < 2; ++rr) {
    int slot = rr * 256 + t;
    int key = slot >> 3, d = (slot & 7) * 8;
    int gk = kb + key; if (gk >= L_) gk = L_ - 1;
    s8v v = *(const s8v*)(src + (size_t)(b * L_ + gk) * stride + voff0 + h * 64 + d);
    *(s8v*)(&tile[key][d]) = v;
  }
  __syncthreads();
  int dim = t >> 2, k0 = (t & 3) * 16;
  u16 buf[16];
  float psum = 0.f;
#pragma unroll
  for (int i = 0; i < 16; ++i) {
    int key = k0 + i;
    buf[i] = (kb + key < L_) ? tile[key][dim] : (u16)0;
    psum += b2f(buf[i]);
  }
  *(s8v*)(VT + ((size_t)bh * 64 + dim) * LP_ + kb + k0) = *(s8v*)buf;
  *(s8v*)(VT + ((size_t)bh * 64 + dim) * LP_ + kb + k0 + 8) = *(s8v*)(buf + 8);
  if (vpart) {
    psum += __shfl_xor(psum, 1);
    psum += __shfl_xor(psum, 2);
    if ((t & 3) == 0) vpart[((size_t)bh * 24 + kt) * 64 + dim] = psum;
  }
}

// ---------------- LDS-staged swapped-operand MFMA flash attention -----------
template<int MODE>
__global__ __launch_bounds__(256) void flash_attn(
    const u16* __restrict__ Qm, const u16* __restrict__ Kg,
    const u16* __restrict__ VT, const int* __restrict__ top,
    float* __restrict__ POf, u16* POa, u16* POb,
    float* __restrict__ PM, float* __restrict__ PL) {
  constexpr int QSTR = (MODE == 0) ? 512 : 1536;
  constexpr int KSTR = (MODE == 0) ? 1024 : 1536;
  constexpr int TILES = (MODE == 0) ? 12 : 3;
  constexpr int NB = (MODE == 0) ? 48 : 8;
  __shared__ __align__(16) u16 Kt[64 * 64];        // [key][slot^(key&7)]
  __shared__ __align__(16) u16 Vt[64 * 64];        // [dim][slot^(dim&7)]
  __shared__ __align__(16) unsigned Xch[4][576];   // per-wave P exchange
  const int o = xswz(blockIdx.x, (B_ * H_ * NB) >> 3);
  int bh, sp, qb;
  if (MODE == 0) {
    bh = o / 48; int rem = o % 48; qb = rem >> 1; sp = rem & 1;
  } else {
    bh = o / 8; sp = o % 8; qb = 0;
  }
  const int h = bh & 7, b = bh >> 3;
  const int qoff = h * 64;
  const int koff = ((MODE == 0) ? 0 : 512) + h * 64;
  const int t = threadIdx.x, w = t >> 6, lane = t & 63;
  const int lg = lane >> 4, li = lane & 15;
  const u16* vtg = VT + (size_t)bh * 64 * LP_;
  unsigned* xw = Xch[w];
  u16* xw16 = (u16*)xw;

  int qrow;
  if (MODE == 0) {
    int q = qb * 64 + w * 16 + li;
    qrow = b * L_ + ((q < L_) ? q : (L_ - 1));
  } else {
    int u = w * 16 + li; if (u >= SK_) u = SK_ - 1;
    qrow = b * L_ + top[bh * SK_ + u];
  }
  s8v qf0 = *(const s8v*)(Qm + (size_t)qrow * QSTR + qoff + lg * 8);
  s8v qf1 = *(const s8v*)(Qm + (size_t)qrow * QSTR + qoff + 32 + lg * 8);

  f4 o4[4];                          // o4[n][r] = O^T[d=n*16+lg*4+r][q=li]
#pragma unroll
  for (int n = 0; n < 4; ++n) o4[n] = f4{0.f, 0.f, 0.f, 0.f};
  float m_run = -INFINITY, l_run = 0.f;   // per-lane (q=li)
  const int kt0 = sp * TILES;
  const int skey = lane >> 3;
  const int sslot = lane & 7;

#pragma unroll 1
  for (int ki = 0; ki < TILES; ++ki) {
    const int kb = (kt0 + ki) * 64;
#pragma unroll
    for (int j = 0; j < 2; ++j) {
      int row = w * 16 + j * 8 + skey;
      int gk = kb + row; if (gk >= L_) gk = L_ - 1;
      int ck = sslot ^ (row & 7);
      __builtin_amdgcn_global_load_lds(
          (const __attribute__((address_space(1))) void*)(Kg + (size_t)(b * L_ + gk) * KSTR + koff + ck * 8),
          (__attribute__((address_space(3))) void*)(Kt + (w * 16 + j * 8) * 64),
          16, 0, 0);
      int cv = sslot ^ (row & 7);
      __builtin_amdgcn_global_load_lds(
          (const __attribute__((address_space(1))) void*)(vtg + (size_t)row * LP_ + kb + cv * 8),
          (__attribute__((address_space(3))) void*)(Vt + (w * 16 + j * 8) * 64),
          16, 0, 0);
    }
    __syncthreads();
    f4 s[4];
#pragma unroll
    for (int c = 0; c < 4; ++c) {
      int key = c * 16 + li;
      s8v kf = *(const s8v*)(Kt + key * 64 + ((lg ^ (key & 7)) * 8));
      s8v kg2 = *(const s8v*)(Kt + key * 64 + (((lg + 4) ^ (key & 7)) * 8));
      f4 z = f4{0.f, 0.f, 0.f, 0.f};
      z = __builtin_amdgcn_mfma_f32_16x16x32_bf16(kf, qf0, z, 0, 0, 0);
      z = __builtin_amdgcn_mfma_f32_16x16x32_bf16(kg2, qf1, z, 0, 0, 0);
      s[c] = z * 0.125f;
    }
    if (kb + 64 > L_) {
#pragma unroll
      for (int c = 0; c < 4; ++c)
#pragma unroll
        for (int r = 0; r < 4; ++r)
          if (kb + c * 16 + lg * 4 + r >= L_) s[c][r] = -INFINITY;
    }
    float tm = -INFINITY;
#pragma unroll
    for (int c = 0; c < 4; ++c)
      tm = fmaxf(tm, fmaxf(fmaxf(s[c][0], s[c][1]), fmaxf(s[c][2], s[c][3])));
    tm = fmaxf(tm, __shfl_xor(tm, 16));
    tm = fmaxf(tm, __shfl_xor(tm, 32));
    // T13 defer-max: only rescale when some lane's max grew past threshold.
    if (!__all(tm <= m_run + 8.f)) {
      float mn = fmaxf(m_run, tm);
      float sc = __expf(m_run - mn);
      l_run *= sc;
      m_run = mn;
#pragma unroll
      for (int n = 0; n < 4; ++n) o4[n] *= sc;
    }
    float p[4][4];
    float rs = 0.f;
#pragma unroll
    for (int c = 0; c < 4; ++c)
#pragma unroll
      for (int r = 0; r < 4; ++r) { p[c][r] = __expf(s[c][r] - m_run); rs += p[c][r]; }
    rs += __shfl_xor(rs, 16);
    rs += __shfl_xor(rs, 32);
    l_run += rs;
    // pack P via v_cvt_pk_bf16_f32 (1 VALU op per pair vs ~9 manual)
#pragma unroll
    for (int c = 0; c < 4; ++c)
#pragma unroll
      for (int rp = 0; rp < 2; ++rp)
        xw[li * 36 + c * 8 + lg * 2 + rp] = cvt_pk(p[c][2 * rp], p[c][2 * rp + 1]);
    s8v pb0 = *(const s8v*)(xw + li * 36 + lg * 4);
    s8v pb1 = *(const s8v*)(xw + li * 36 + 16 + lg * 4);
#pragma unroll
    for (int n = 0; n < 4; ++n) {
      int dim = n * 16 + li;
      s8v vb0 = *(const s8v*)(Vt + dim * 64 + ((lg ^ (dim & 7)) * 8));
      o4[n] = __builtin_amdgcn_mfma_f32_16x16x32_bf16(vb0, pb0, o4[n], 0, 0, 0);
    }
#pragma unroll
    for (int n = 0; n < 4; ++n) {
      int dim = n * 16 + li;
      s8v vb1 = *(const s8v*)(Vt + dim * 64 + (((lg + 4) ^ (dim & 7)) * 8));
      o4[n] = __builtin_amdgcn_mfma_f32_16x16x32_bf16(vb1, pb1, o4[n], 0, 0, 0);
    }
    __syncthreads();
  }

  if (MODE == 0) {
    // per-wave LDS transpose [q][d] (packed stores), coalesced bf16 out
#pragma unroll
    for (int n = 0; n < 4; ++n)
#pragma unroll
      for (int rp = 0; rp < 2; ++rp)
        xw[li * 36 + n * 8 + lg * 2 + rp] = cvt_pk(o4[n][2 * rp], o4[n][2 * rp + 1]);
    u16* PO = sp ? POb : POa;
    const int pid = (bh * 24 + qb) * 2 + sp;
    int q_local = lane >> 2, d0 = (lane & 3) * 16;
    int q = qb * 64 + w * 16 + q_local;
    s8v v0 = *(const s8v*)(xw16 + q_local * 72 + d0);
    s8v v1 = *(const s8v*)(xw16 + q_local * 72 + d0 + 8);
    if (q < L_) {
      u16* dst = PO + ((size_t)(b * L_ + q)) * DM_ + qoff + d0;
      *(s8v*)dst = v0;
      *(s8v*)(dst + 8) = v1;
    }
    if (lg == 0) {
      PM[pid * 64 + w * 16 + li] = m_run;
      PL[pid * 64 + w * 16 + li] = l_run;
    }
  } else {
    int base = (bh * 8 + sp) * 64 + w * 16 + li;
#pragma unroll
    for (int n = 0; n < 4; ++n)
#pragma unroll
      for (int r = 0; r < 4; ++r)
        POf[(size_t)base * 64 + n * 16 + lg * 4 + r] = o4[n][r];
    if (lg == 0) {
      PM[base] = m_run;
      PL[base] = l_run;
    }
  }
}

// ---------------- combine 2-way cross partials (POb == ctxb, in place) ------
__global__ __launch_bounds__(256) void combine_cross(const u16* __restrict__ PO0,
                                                     const float* __restrict__ PM,
                                                     const float* __restrict__ PL,
                                                     u16* ctxb) {
  int idx = blockIdx.x * 256 + threadIdx.x;
  int row = idx >> 9, col = idx & 511;
  int b = row / L_, q = row - b * L_;
  int h = col >> 6;
  int bh = b * 8 + h, qbk = q >> 6, qi = q & 63;
  int p0 = ((bh * 24 + qbk) * 2) * 64 + qi;
  float m0 = PM[p0], m1 = PM[p0 + 64];
  float l0 = PL[p0], l1 = PL[p0 + 64];
  float M = fmaxf(m0, m1);
  float w0 = __expf(m0 - M), w1 = __expf(m1 - M);
  float inv = 1.f / (w0 * l0 + w1 * l1);
  float o0 = b2f(PO0[idx]);
  float o1 = b2f(ctxb[idx]);
  ctxb[idx] = f2b((w0 * o0 + w1 * o1) * inv);
}

// ---------------- fused combine split-K partials + scatter into ctxb --------
__global__ __launch_bounds__(256) void combine_prob_scatter(
    const float* __restrict__ PO, const float* __restrict__ PM,
    const float* __restrict__ PL, const int* __restrict__ top,
    u16* __restrict__ ctxb) {
  int bh = blockIdx.x;
  int t = threadIdx.x;
  int u = t >> 2, dg = (t & 3) * 16;
  if (u >= SK_) return;
  float M = -INFINITY;
  for (int s = 0; s < 8; ++s) M = fmaxf(M, PM[(bh * 8 + s) * 64 + u]);
  float wgt[8];
  float den = 0.f;
  for (int s = 0; s < 8; ++s) {
    wgt[s] = __expf(PM[(bh * 8 + s) * 64 + u] - M);
    den += wgt[s] * PL[(bh * 8 + s) * 64 + u];
  }
  float inv = 1.f / den;
  int h = bh & 7, b = bh >> 3;
  int l = top[bh * SK_ + u];
  u16* dst = ctxb + ((size_t)(b * L_ + l)) * DM_ + h * 64;
  for (int d = dg; d < dg + 16; ++d) {
    float acc = 0.f;
    for (int s = 0; s < 8; ++s) acc += wgt[s] * PO[(((size_t)bh * 8 + s) * 64 + u) * 64 + d];
    dst[d] = f2b(acc * inv);
  }
}

// ---------------- ctx = broadcast vmean (24 tile-partials inline) -----------
__global__ __launch_bounds__(256) void fill_ctx(const float* __restrict__ part,
                                                u16* __restrict__ ctxb) {
  int idx = blockIdx.x * 256 + threadIdx.x;
  int d = idx % 64;
  int h = (idx / 64) % H_;
  int b = idx / (L_ * DM_);
  int bh = b * 8 + h;
  float s = 0.f;
#pragma unroll
  for (int seg = 0; seg < 24; ++seg) s += part[((size_t)bh * 24 + seg) * 64 + d];
  ctxb[idx] = f2b(s * (1.f / (float)L_));
}

// ---------------- host side --------------------------------------------------
extern "C" void kernel_launch(void* const* d_in, const int* in_sizes, int n_in,
                              void* d_out, int out_size, void* d_ws, size_t ws_size,
                              hipStream_t stream) {
  const float* inflow   = (const float*)d_in[4];
  const float* W_emb_e  = (const float*)d_in[5];
  const float* b_emb_e  = (const float*)d_in[6];
  const float* W_emb_d  = (const float*)d_in[7];
  const float* b_emb_d  = (const float*)d_in[8];
  const float* enc_Wqkv = (const float*)d_in[9];
  const float* enc_bqkv = (const float*)d_in[10];
  const float* enc_Wo   = (const float*)d_in[11];
  const float* enc_bo   = (const float*)d_in[12];
  const float* enc_ln1g = (const float*)d_in[13];
  const float* enc_ln1b = (const float*)d_in[14];
  const float* enc_Wf1  = (const float*)d_in[15];
  const float* enc_bf1  = (const float*)d_in[16];
  const float* enc_Wf2  = (const float*)d_in[17];
  const float* enc_bf2  = (const float*)d_in[18];
  const float* enc_ln2g = (const float*)d_in[19];
  const float* enc_ln2b = (const float*)d_in[20];
  const float* enc_ng   = (const float*)d_in[21];
  const float* enc_nb   = (const float*)d_in[22];
  const float* dec_Wqkv = (const float*)d_in[23];
  const float* dec_bqkv = (const float*)d_in[24];
  const float* dec_Wo_s = (const float*)d_in[25];
  const float* dec_bo_s = (const float*)d_in[26];
  const float* dec_ln1g = (const float*)d_in[27];
  const float* dec_ln1b = (const float*)d_in[28];
  const float* dec_Wq_c = (const float*)d_in[29];
  const float* dec_bq_c = (const float*)d_in[30];
  const float* dec_Wkv  = (const float*)d_in[31];
  const float* dec_bkv  = (const float*)d_in[32];
  const float* dec_Wo_c = (const float*)d_in[33];
  const float* dec_bo_c = (const float*)d_in[34];
  const float* dec_ln2g = (const float*)d_in[35];
  const float* dec_ln2b = (const float*)d_in[36];
  const float* dec_Wf1  = (const float*)d_in[37];
  const float* dec_bf1  = (const float*)d_in[38];
  const float* dec_Wf2  = (const float*)d_in[39];
  const float* dec_bf2  = (const float*)d_in[40];
  const float* dec_ln3g = (const float*)d_in[41];
  const float* dec_ln3b = (const float*)d_in[42];
  const float* W_proj   = (const float*)d_in[43];
  const float* b_proj   = (const float*)d_in[44];
  const float* W1       = (const float*)d_in[45];
  const float* b1       = (const float*)d_in[46];
  const float* W3       = (const float*)d_in[47];
  const float* b3       = (const float*)d_in[48];
  const int*   samp     = (const int*)d_in[49];
  float* out = (float*)d_out;

  float* ws  = (float*)d_ws;
  float* PE  = ws;                       // 778240 f (dead after embeds -> PMc/PLc)
  float* X   = PE + 778240;              // 72960 f
  float* ACT = X + 72960;                // 3112960 f
  float* REG = ACT + 3112960;            // 6291456 f shared region
  float* MME = REG + 6291456;            // 48640 f
  float* CTT = MME + 48640;              // 81920 f (VME24: 49152 f)
  float* VME = CTT + 81920;              // 2048 f (unused)
  int*   TOP = (int*)(VME + 2048);       // 1280 i
  float* TAIL = VME + 2048 + 1280;
  u16* ENCb = (u16*)TAIL;                       // 6144*512 u16
  u16* DECb = (u16*)(TAIL + 1572864);
  u16* CTXb = (u16*)(TAIL + 2 * 1572864);
  u16* WBF  = (u16*)(TAIL + 3 * 1572864);       // 10485760 u16
  // prob split-K partials: FRESH memory after WBF (no CTXb overlay)
  float* POp = (float*)(WBF + 10485760);        // 1048576 f
  float* PMp = POp + 1048576;                   // 16384 f
  float* PLp = PMp + 16384;                     // 16384 f
  u16*   PO0 = (u16*)(PLp + 16384);             // cross split-0 partials [6144][512]

  // region overlays (prob phase)
  u16* QKVb = (u16*)REG;                 // [6144][1536]
  u16* FFb  = (u16*)REG;                 // [6144][2048]
  u16* VT   = (u16*)REG + 9437184;       // [32][64][1536] u16
  // region overlays (cross phase)
  u16* QCb  = (u16*)REG;                 // [6144][512]
  u16* KVCb = (u16*)REG + 3145728;       // [6144][1024] (K at +0, V at +512)
  // cross partial stats in dead PE region (32*24*2*64 = 98304 each)
  float* PMc = PE;
  float* PLc = PE + 98304;
  float* VME24 = CTT;                    // 32*24*64 = 49152 f

  auto GB = [&](const u16* A, const u16* Bt, const float* bias, const float* res,
                float* Cf, u16* Cb, int N, int K, int act) {
    if (N <= 512) {
      dim3 g(N / 128, MP_ / 64);
      gemm_bf16_k64<<<g, 256, 0, stream>>>(A, Bt, bias, res, Cf, Cb, N, K, act);
    } else {
      dim3 g(N / 128, MP_ / 128);
      gemm_bf16_128<<<g, 256, 0, stream>>>(A, Bt, bias, res, Cf, Cb, N, K, act);
    }
  };
  auto PROB = [&](const int* sidx) {
    probM<<<B_ * H_ * L_ / 4, 256, 0, stream>>>(QKVb, sidx, MME);
    radix_topk<<<B_ * H_, 256, 0, stream>>>(MME, TOP);
    transpose_v<<<B_ * H_ * 24, 256, 0, stream>>>(QKVb, 1536, 1024, VT, VME24);
    flash_attn<1><<<B_ * H_ * 8, 256, 0, stream>>>(QKVb, QKVb, VT, TOP, POp,
                                                   nullptr, nullptr, PMp, PLp);
    fill_ctx<<<ML_ * DM_ / 256, 256, 0, stream>>>(VME24, CTXb);
    combine_prob_scatter<<<B_ * H_, 256, 0, stream>>>(POp, PMp, PLp, TOP, CTXb);
  };

  pe_kernel<<<(L_ * DM_ + 255) / 256, 256, 0, stream>>>(PE);
  extract_x<<<(ML_ * 12 + 255) / 256, 256, 0, stream>>>(inflow, X);

  // one fused weight-conversion dispatch (LDS tiled transpose)
  {
    CvtArgs a;
    const float* s[15] = {
      enc_Wqkv, enc_Wqkv + 512 * 1536, enc_Wo, enc_Wo + 512 * 512,
      enc_Wf1, enc_Wf1 + 512 * 2048, enc_Wf2, enc_Wf2 + 2048 * 512,
      dec_Wqkv, dec_Wo_s, dec_Wq_c, dec_Wkv, dec_Wo_c, dec_Wf1, dec_Wf2 };
    unsigned cumt[16] = { 0u, 768u, 1536u, 1792u, 2048u, 3072u,
                          4096u, 5120u, 6144u, 6912u, 7168u,
                          7424u, 7936u, 8192u, 9216u, 10240u };
    unsigned lk[15] = { 9, 9, 9, 9, 9, 9, 11, 11, 9, 9, 9, 9, 9, 9, 11 };
    for (int i = 0; i < 15; ++i) { a.src[i] = s[i]; a.lk[i] = lk[i]; }
    for (int i = 0; i < 16; ++i) a.cumt[i] = cumt[i];
    cvt_all<<<10240, 256, 0, stream>>>(a, WBF);
  }
  u16* Wt_qkv_e0 = WBF + 0;
  u16* Wt_qkv_e1 = WBF + 786432;
  u16* Wt_o_e0   = WBF + 1572864;
  u16* Wt_o_e1   = WBF + 1835008;
  u16* Wt_f1_e0  = WBF + 2097152;
  u16* Wt_f1_e1  = WBF + 3145728;
  u16* Wt_f2_e0  = WBF + 4194304;
  u16* Wt_f2_e1  = WBF + 5242880;
  u16* Wt_qkv_d  = WBF + 6291456;
  u16* Wt_o_s    = WBF + 7077888;
  u16* Wt_q_c    = WBF + 7340032;
  u16* Wt_kv_c   = WBF + 7602176;
  u16* Wt_o_c    = WBF + 8126464;
  u16* Wt_f1_d   = WBF + 8388608;
  u16* Wt_f2_d   = WBF + 9437184;

  // ---------------- encoder ----------------
  embed_fused<<<MP_ / 4, 256, 0, stream>>>(X, W_emb_e, b_emb_e, PE, ACT, ENCb);

  const u16* Wqkv_e[2] = {Wt_qkv_e0, Wt_qkv_e1};
  const u16* Wo_e[2]   = {Wt_o_e0, Wt_o_e1};
  const u16* Wf1_e[2]  = {Wt_f1_e0, Wt_f1_e1};
  const u16* Wf2_e[2]  = {Wt_f2_e0, Wt_f2_e1};
  for (int i = 0; i < 2; ++i) {
    GB(ENCb, Wqkv_e[i], enc_bqkv + i * 1536, nullptr, nullptr, QKVb, 1536, 512, 0);
    PROB(samp + (size_t)i * L_ * SK_);
    GB(CTXb, Wo_e[i], enc_bo + i * 512, ACT, ACT, nullptr, 512, 512, 0);
    layernorm_ip<<<ML_ / 4, 256, 0, stream>>>(ACT, enc_ln1g + i * 512, enc_ln1b + i * 512, ENCb);
    GB(ENCb, Wf1_e[i], enc_bf1 + i * 2048, nullptr, nullptr, FFb, 2048, 512, 1);
    GB(FFb, Wf2_e[i], enc_bf2 + i * 512, ACT, ACT, nullptr, 512, 2048, 0);
    layernorm_ip<<<ML_ / 4, 256, 0, stream>>>(ACT, enc_ln2g + i * 512, enc_ln2b + i * 512, ENCb);
  }
  layernorm_ip<<<ML_ / 4, 256, 0, stream>>>(ACT, enc_ng, enc_nb, ENCb);

  // ---------------- decoder ----------------
  embed_fused<<<MP_ / 4, 256, 0, stream>>>(X, W_emb_d, b_emb_d, PE, ACT, DECb);
  GB(DECb, Wt_qkv_d, dec_bqkv, nullptr, nullptr, QKVb, 1536, 512, 0);
  PROB(samp + (size_t)2 * L_ * SK_);
  GB(CTXb, Wt_o_s, dec_bo_s, ACT, ACT, nullptr, 512, 512, 0);
  layernorm_ip<<<ML_ / 4, 256, 0, stream>>>(ACT, dec_ln1g, dec_ln1b, DECb);

  // cross attention: Q GEMM + merged K/V GEMM (N=1024, KVC layout)
  GB(DECb, Wt_q_c, dec_bq_c, nullptr, nullptr, QCb, 512, 512, 0);
  GB(ENCb, Wt_kv_c, dec_bkv, nullptr, nullptr, KVCb, 1024, 512, 0);
  transpose_v<<<B_ * H_ * 24, 256, 0, stream>>>(KVCb, 1024, 512, VT, nullptr);
  flash_attn<0><<<B_ * H_ * 48, 256, 0, stream>>>(QCb, KVCb, VT, nullptr, nullptr,
                                                  PO0, CTXb, PMc, PLc);
  combine_cross<<<ML_ * DM_ / 256, 256, 0, stream>>>(PO0, PMc, PLc, CTXb);
  GB(CTXb, Wt_o_c, dec_bo_c, ACT, ACT, nullptr, 512, 512, 0);
  layernorm_ip<<<ML_ / 4, 256, 0, stream>>>(ACT, dec_ln2g, dec_ln2b, DECb);

  GB(DECb, Wt_f1_d, dec_bf1, nullptr, nullptr, FFb, 2048, 512, 1);
  GB(FFb, Wt_f2_d, dec_bf2, ACT, ACT, nullptr, 512, 2048, 0);
  layernorm_ip<<<ML_ / 4, 256, 0, stream>>>(ACT, dec_ln3g, dec_ln3b, DECb);

  // fused head
  head_fused<<<ML_ / 4, 256, 0, stream>>>(ACT, X, W_proj, b_proj, W1, b1, W3, b3, out);
}

// Round 18
// 807.417 us; speedup vs baseline: 1.2944x; 1.0416x over previous
//
#include <hip/hip_runtime.h>
#include <math.h>

#define B_ 4
#define H_ 8
#define L_ 1520
#define DM_ 512
#define DFF_ 2048
#define SK_ 40
#define ML_ (B_*L_)   /* 6080 rows */
#define MP_ 6144      /* padded rows for MFMA GEMM */
#define LP_ 1536      /* padded key count for V^T */

typedef unsigned short u16;
typedef short s8v __attribute__((ext_vector_type(8)));
typedef float f4 __attribute__((ext_vector_type(4)));

__device__ __forceinline__ u16 f2b(float x) {
  union { float f; unsigned u; } c; c.f = x;
  unsigned r = c.u + 0x7FFFu + ((c.u >> 16) & 1u);
  return (u16)(r >> 16);
}
__device__ __forceinline__ float b2f(u16 h) {
  union { unsigned u; float f; } c; c.u = ((unsigned)h) << 16;
  return c.f;
}
// packed f32 pair -> 2x bf16 in one u32 (lo = a, hi = b); single VALU op
__device__ __forceinline__ unsigned cvt_pk(float a, float b) {
  unsigned r;
  asm volatile("v_cvt_pk_bf16_f32 %0, %1, %2" : "=v"(r) : "v"(a), "v"(b));
  return r;
}
__device__ __forceinline__ float gelu_tanh(float x) {
  float x3 = x * x * x;
  return 0.5f * x * (1.f + tanhf(0.79788456080286536f * (x + 0.044715f * x3)));
}
// XCD-chunked bijective swizzle; requires nwg % 8 == 0 (cpx = nwg/8).
__device__ __forceinline__ int xswz(int bid, int cpx) {
  return (bid & 7) * cpx + (bid >> 3);
}

// ---------------- positional encoding (double precision to match numpy) ----
__global__ __launch_bounds__(256) void pe_kernel(float* __restrict__ pe) {
  int idx = blockIdx.x * 256 + threadIdx.x;
  if (idx >= L_ * DM_) return;
  int pos = idx / DM_, i = idx % DM_;
  double expo = (double)(2 * (i / 2)) / (double)DM_;
  double ang = (double)pos / pow(10000.0, expo);
  pe[idx] = (i & 1) ? (float)cos(ang) : (float)sin(ang);
}

// ---------------- x = inflow[:,2:14].reshape (contiguous slice) -------------
__global__ __launch_bounds__(256) void extract_x(const float* __restrict__ inflow,
                                                 float* __restrict__ X) {
  int idx = blockIdx.x * 256 + threadIdx.x;
  if (idx >= ML_ * 12) return;
  int b = idx / (L_ * 12);
  int rem = idx - b * (L_ * 12);
  X[idx] = inflow[(size_t)b * 14 * L_ + 2 * L_ + rem];
}

// ---------------- fused weight convert+transpose (LDS tiled, coalesced) -----
struct CvtArgs {
  const float* src[15];
  unsigned cumt[16];   // cumulative 32x32-tile counts
  unsigned lk[15];     // log2(K) per segment
};
__global__ __launch_bounds__(256) void cvt_all(CvtArgs a, u16* __restrict__ dst) {
  __shared__ float tl[32][33];
  int bt = blockIdx.x;                 // grid exact: 10240 tiles
  int s = 0;
#pragma unroll
  for (int i = 1; i < 15; ++i) s += (bt >= (int)a.cumt[i]);
  int lt = bt - a.cumt[s];
  unsigned lk = a.lk[s];
  unsigned K = 1u << lk;
  unsigned N = ((a.cumt[s + 1] - a.cumt[s]) << 10) >> lk;
  unsigned tiles_n = N >> 5;
  unsigned k0 = (lt / tiles_n) * 32, n0 = (lt % tiles_n) * 32;
  const float* src = a.src[s];
  int r = threadIdx.x >> 5, c = threadIdx.x & 31;
#pragma unroll
  for (int i = 0; i < 4; ++i)
    tl[r + 8 * i][c] = src[(size_t)(k0 + r + 8 * i) * N + n0 + c];
  __syncthreads();
  u16* d = dst + ((size_t)a.cumt[s] << 10);
#pragma unroll
  for (int i = 0; i < 4; ++i)
    d[(size_t)(n0 + r + 8 * i) * K + k0 + c] = f2b(tl[c][r + 8 * i]);
}

// ---------------- fused embed: ACT = X@W + b + PE ; ACTb = bf16(ACT) --------
__global__ __launch_bounds__(256) void embed_fused(
    const float* __restrict__ X, const float* __restrict__ W,
    const float* __restrict__ bias, const float* __restrict__ PE,
    float* __restrict__ ACT, u16* __restrict__ ACTb) {
  int row = blockIdx.x * 4 + (threadIdx.x >> 6);
  int lane = threadIdx.x & 63;
  int d0 = lane * 8;
  if (row >= ML_) {
    s8v z = {0, 0, 0, 0, 0, 0, 0, 0};
    *(s8v*)(ACTb + (size_t)row * DM_ + d0) = z;
    return;
  }
  int prow = row % L_;
  f4 a0 = *(const f4*)(bias + d0);
  f4 a1 = *(const f4*)(bias + d0 + 4);
  a0 += *(const f4*)(PE + (size_t)prow * DM_ + d0);
  a1 += *(const f4*)(PE + (size_t)prow * DM_ + d0 + 4);
  const float* xr = X + (size_t)row * 12;
#pragma unroll
  for (int t = 0; t < 12; ++t) {
    float xv = xr[t];
    a0 += xv * *(const f4*)(W + (size_t)t * DM_ + d0);
    a1 += xv * *(const f4*)(W + (size_t)t * DM_ + d0 + 4);
  }
  float* dst = ACT + (size_t)row * DM_ + d0;
  *(f4*)dst = a0;
  *(f4*)(dst + 4) = a1;
  unsigned ob[4];
  ob[0] = cvt_pk(a0[0], a0[1]); ob[1] = cvt_pk(a0[2], a0[3]);
  ob[2] = cvt_pk(a1[0], a1[1]); ob[3] = cvt_pk(a1[2], a1[3]);
  *(s8v*)(ACTb + (size_t)row * DM_ + d0) = *(s8v*)ob;
}

// ---------------- fused head: out = relu((DEC@Wp+bp+X)@W1+b1)@W3+b3 ---------
__global__ __launch_bounds__(256) void head_fused(
    const float* __restrict__ DEC, const float* __restrict__ X,
    const float* __restrict__ Wp, const float* __restrict__ bp,
    const float* __restrict__ W1, const float* __restrict__ b1,
    const float* __restrict__ W3, const float* __restrict__ b3,
    float* __restrict__ out) {
  int row = blockIdx.x * 4 + (threadIdx.x >> 6);
  int lane = threadIdx.x & 63;
  int d0 = lane * 8;
  const float* dec = DEC + (size_t)row * DM_ + d0;
  f4 v0 = *(const f4*)dec;
  f4 v1 = *(const f4*)(dec + 4);
  float pj[12];
#pragma unroll
  for (int j = 0; j < 12; ++j) pj[j] = 0.f;
#pragma unroll
  for (int i = 0; i < 8; ++i) {
    float dv = (i < 4) ? v0[i] : v1[i - 4];
    const float* wr = Wp + (size_t)(d0 + i) * 12;
#pragma unroll
    for (int j = 0; j < 12; ++j) pj[j] += dv * wr[j];
  }
  for (int off = 32; off; off >>= 1) {
#pragma unroll
    for (int j = 0; j < 12; ++j) pj[j] += __shfl_xor(pj[j], off);
  }
  float o12[12];
#pragma unroll
  for (int j = 0; j < 12; ++j) o12[j] = pj[j] + bp[j] + X[(size_t)row * 12 + j];
  int k0 = lane * 2;
  float h0 = b1[k0], h1 = b1[k0 + 1];
#pragma unroll
  for (int j = 0; j < 12; ++j) {
    h0 += o12[j] * W1[j * 128 + k0];
    h1 += o12[j] * W1[j * 128 + k0 + 1];
  }
  h0 = fmaxf(h0, 0.f);
  h1 = fmaxf(h1, 0.f);
  float op[3];
#pragma unroll
  for (int p = 0; p < 3; ++p)
    op[p] = h0 * W3[k0 * 3 + p] + h1 * W3[(k0 + 1) * 3 + p];
  for (int off = 32; off; off >>= 1) {
#pragma unroll
    for (int p = 0; p < 3; ++p) op[p] += __shfl_xor(op[p], off);
  }
  if (lane == 0) {
#pragma unroll
    for (int p = 0; p < 3; ++p) out[(size_t)row * 3 + p] = op[p] + b3[p];
  }
}

// ---------------- bf16 MFMA GEMM, BM=64/BK=64: half the barrier drains ------
// Stage both 32-wide K-halves in one phase (linear LDS dest, source col
// pre-XOR'd by row&7; reads apply same XOR -> 2-way bank aliasing, free).
__global__ __launch_bounds__(256) void gemm_bf16_k64(
    const u16* __restrict__ A, const u16* __restrict__ Bt,
    const float* __restrict__ bias, const float* __restrict__ res,
    float* __restrict__ Cf, u16* __restrict__ Cb,
    int N, int K, int act) {
  __shared__ __align__(16) u16 As[64 * 64];
  __shared__ __align__(16) u16 Bs[128 * 64];
  const int nwg = gridDim.x * gridDim.y;
  const int lin = blockIdx.y * gridDim.x + blockIdx.x;
  const int o = xswz(lin, nwg >> 3);
  const int bxi = o % gridDim.x, byi = o / gridDim.x;
  const int t = threadIdx.x, w = t >> 6, lane = t & 63;
  const int lg = lane >> 4, li = lane & 15;
  const int bm = byi * 64, bn = bxi * 128;
  const int wr = (w >> 1) * 32, wc = (w & 1) * 64;
  f4 acc[2][4];
#pragma unroll
  for (int i = 0; i < 2; ++i)
#pragma unroll
    for (int j = 0; j < 4; ++j) acc[i][j] = f4{0.f, 0.f, 0.f, 0.f};
  const int rloc = lane >> 3;          // 0..7 rows per wave-instruction
  const int slot = lane & 7;           // physical 16B slot written
  for (int k0 = 0; k0 < K; k0 += 64) {
    // A: 64 rows, 2 wave-instructions of 8 rows each per wave
#pragma unroll
    for (int j = 0; j < 2; ++j) {
      int r = w * 8 + j * 32 + rloc;
      int ls = slot ^ (r & 7);
      __builtin_amdgcn_global_load_lds(
          (const __attribute__((address_space(1))) void*)(A + (size_t)(bm + r) * K + k0 + ls * 8),
          (__attribute__((address_space(3))) void*)(As + (w * 8 + j * 32) * 64),
          16, 0, 0);
    }
    // B: 128 rows, 4 wave-instructions
#pragma unroll
    for (int j = 0; j < 4; ++j) {
      int r = w * 8 + j * 32 + rloc;
      int ls = slot ^ (r & 7);
      __builtin_amdgcn_global_load_lds(
          (const __attribute__((address_space(1))) void*)(Bt + (size_t)(bn + r) * K + k0 + ls * 8),
          (__attribute__((address_space(3))) void*)(Bs + (w * 8 + j * 32) * 64),
          16, 0, 0);
    }
    __syncthreads();
#pragma unroll
    for (int ks = 0; ks < 2; ++ks) {
      s8v af[2], bf[4];
#pragma unroll
      for (int f = 0; f < 2; ++f) {
        int ra = wr + f * 16 + li;
        af[f] = *(const s8v*)(As + ra * 64 + (((ks * 4 + lg) ^ (ra & 7)) * 8));
      }
#pragma unroll
      for (int f = 0; f < 4; ++f) {
        int rb = wc + f * 16 + li;
        bf[f] = *(const s8v*)(Bs + rb * 64 + (((ks * 4 + lg) ^ (rb & 7)) * 8));
      }
#pragma unroll
      for (int fi = 0; fi < 2; ++fi)
#pragma unroll
        for (int fj = 0; fj < 4; ++fj)
          acc[fi][fj] = __builtin_amdgcn_mfma_f32_16x16x32_bf16(af[fi], bf[fj], acc[fi][fj], 0, 0, 0);
    }
    __syncthreads();
  }
#pragma unroll
  for (int fi = 0; fi < 2; ++fi)
#pragma unroll
    for (int fj = 0; fj < 4; ++fj)
#pragma unroll
      for (int r = 0; r < 4; ++r) {
        int row = bm + wr + fi * 16 + lg * 4 + r;
        int col = bn + wc + fj * 16 + li;
        float v = acc[fi][fj][r] + bias[col];
        if (res && row < ML_) v += res[(size_t)row * N + col];
        if (act == 1) v = gelu_tanh(v);
        if (Cf && row < ML_) Cf[(size_t)row * N + col] = v;
        if (Cb) Cb[(size_t)row * N + col] = f2b(v);
      }
}

// ---------------- layernorm: wave per row, vectorized -----------------------
__global__ __launch_bounds__(256) void layernorm_ip(float* __restrict__ Xb,
                                                    const float* __restrict__ g,
                                                    const float* __restrict__ bta,
                                                    u16* __restrict__ outb) {
  int row = blockIdx.x * 4 + (threadIdx.x >> 6);
  int lane = threadIdx.x & 63;
  float* x = Xb + (size_t)row * DM_;
  f4 a = *(f4*)(x + lane * 8);
  f4 b = *(f4*)(x + lane * 8 + 4);
  float s = a[0] + a[1] + a[2] + a[3] + b[0] + b[1] + b[2] + b[3];
  for (int off = 32; off; off >>= 1) s += __shfl_xor(s, off);
  float mu = s * (1.f / 512.f);
  float vs = 0.f;
#pragma unroll
  for (int i = 0; i < 4; ++i) { a[i] -= mu; b[i] -= mu; vs += a[i] * a[i] + b[i] * b[i]; }
  for (int off = 32; off; off >>= 1) vs += __shfl_xor(vs, off);
  float rs = rsqrtf(vs * (1.f / 512.f) + 1e-5f);
  f4 g0 = *(const f4*)(g + lane * 8), g1 = *(const f4*)(g + lane * 8 + 4);
  f4 c0 = *(const f4*)(bta + lane * 8), c1 = *(const f4*)(bta + lane * 8 + 4);
  float r0 = a[0] * rs * g0[0] + c0[0];
  float r1 = a[1] * rs * g0[1] + c0[1];
  float r2 = a[2] * rs * g0[2] + c0[2];
  float r3 = a[3] * rs * g0[3] + c0[3];
  float r4 = b[0] * rs * g1[0] + c1[0];
  float r5 = b[1] * rs * g1[1] + c1[1];
  float r6 = b[2] * rs * g1[2] + c1[2];
  float r7 = b[3] * rs * g1[3] + c1[3];
  x[lane * 8 + 0] = r0; x[lane * 8 + 1] = r1; x[lane * 8 + 2] = r2; x[lane * 8 + 3] = r3;
  x[lane * 8 + 4] = r4; x[lane * 8 + 5] = r5; x[lane * 8 + 6] = r6; x[lane * 8 + 7] = r7;
  unsigned ob[4];
  ob[0] = cvt_pk(r0, r1); ob[1] = cvt_pk(r2, r3);
  ob[2] = cvt_pk(r4, r5); ob[3] = cvt_pk(r6, r7);
  *(s8v*)(outb + (size_t)row * DM_ + lane * 8) = *(s8v*)ob;
}

// ---------------- ProbSparse sparsity measure M (bf16 qkv), swizzled --------
__global__ __launch_bounds__(256) void probM(const u16* __restrict__ qkv,
                                             const int* __restrict__ sidx,
                                             float* __restrict__ Mout) {
  int wid = threadIdx.x / 64, lane = threadIdx.x % 64;
  int o = xswz(blockIdx.x, (B_ * H_ * L_ / 4) >> 3);
  int g = o * 4 + wid;
  int l = g % L_;
  int bh = g / L_;
  int h = bh % H_, b = bh / H_;
  __shared__ float qs[4][64];
  qs[wid][lane] = b2f(qkv[((size_t)b * L_ + l) * 1536 + h * 64 + lane]);
  __syncthreads();
  float dot = 0.f;
  if (lane < SK_) {
    int ks = sidx[l * SK_ + lane];
    const u16* kr = qkv + ((size_t)b * L_ + ks) * 1536 + 512 + h * 64;
#pragma unroll
    for (int j = 0; j < 8; ++j) {
      s8v v = *(const s8v*)(kr + j * 8);
#pragma unroll
      for (int i = 0; i < 8; ++i) dot += qs[wid][j * 8 + i] * b2f((u16)v[i]);
    }
  }
  float vmax = (lane < SK_) ? dot : -INFINITY;
  float vsum = (lane < SK_) ? dot : 0.f;
  for (int off = 32; off; off >>= 1) {
    vmax = fmaxf(vmax, __shfl_xor(vmax, off));
    vsum += __shfl_xor(vsum, off);
  }
  if (lane == 0) Mout[g] = vmax - vsum / (float)L_;
}

// ---------------- radix-select top-40 (matches lax.top_k selection set) -----
__global__ __launch_bounds__(256) void radix_topk(const float* __restrict__ Mv,
                                                  int* __restrict__ top) {
  const int bh = blockIdx.x;
  const int t = threadIdx.x;
  const int base = t * 6;
  unsigned key[6];
#pragma unroll
  for (int i = 0; i < 6; ++i) {
    int ix = base + i;
    unsigned k = 0u;
    if (ix < L_) {
      union { float f; unsigned u; } c; c.f = Mv[(size_t)bh * L_ + ix];
      k = c.u ^ ((c.u & 0x80000000u) ? 0xFFFFFFFFu : 0x80000000u);
    }
    key[i] = k;
  }
  __shared__ int wred[4];
  __shared__ int s_a[256], s_b[256];
  unsigned prefix = 0u;
  for (int b = 31; b >= 0; --b) {
    unsigned cand = prefix | (1u << b);
    int c = 0;
#pragma unroll
    for (int i = 0; i < 6; ++i) c += (key[i] >= cand);
    for (int off = 32; off; off >>= 1) c += __shfl_xor(c, off);
    if ((t & 63) == 0) wred[t >> 6] = c;
    __syncthreads();
    int tot = wred[0] + wred[1] + wred[2] + wred[3];
    if (tot >= SK_) prefix = cand;
    __syncthreads();
  }
  const unsigned T = prefix;
  int gt = 0, tie = 0;
#pragma unroll
  for (int i = 0; i < 6; ++i) { gt += (key[i] > T); tie += (key[i] == T); }
  s_a[t] = gt; s_b[t] = tie;
  __syncthreads();
  for (int off = 1; off < 256; off <<= 1) {
    int va = (t >= off) ? s_a[t - off] : 0;
    int vb = (t >= off) ? s_b[t - off] : 0;
    __syncthreads();
    s_a[t] += va; s_b[t] += vb;
    __syncthreads();
  }
  const int n_strict = s_a[255];
  const int gt_base = s_a[t] - gt;
  const int tie_base = s_b[t] - tie;
  const int need = SK_ - n_strict;
  int lgt = 0, ltie = 0;
#pragma unroll
  for (int i = 0; i < 6; ++i) {
    int ix = base + i;
    if (key[i] > T) {
      top[bh * SK_ + gt_base + lgt] = ix; ++lgt;
    } else if (key[i] == T) {
      int r = tie_base + ltie; ++ltie;
      if (r < need) top[bh * SK_ + n_strict + r] = ix;
    }
  }
}

// ---------------- V^T build + fused per-tile V column sums ------------------
__global__ __launch_bounds__(256) void transpose_v(const u16* __restrict__ src,
                                                   int stride, int voff0,
                                                   u16* __restrict__ VT,
                                                   float* __restrict__ vpart) {
  int o = xswz(blockIdx.x, (B_ * H_ * 24) >> 3);
  int kt = o % 24, bh = o / 24;
  int h = bh & 7, b = bh >> 3;
  int kb = kt * 64;
  __shared__ u16 tile[64][72];
  int t = threadIdx.x;
#pragma unroll
  for (int rr = 0; rr < 2; ++rr) {
    int slot = rr * 256 + t;
    int key = slot >> 3, d = (slot & 7) * 8;
    int gk = kb + key; if (gk >= L_) gk = L_ - 1;
    s8v v = *(const s8v*)(src + (size_t)(b * L_ + gk) * stride + voff0 + h * 64 + d);
    *(s8v*)(&tile[key][d]) = v;
  }
  __syncthreads();
  int dim = t >> 2, k0 = (t & 3) * 16;
  u16 buf[16];
  float psum = 0.f;
#pragma unroll
  for (int i = 0; i < 16; ++i) {
    int key = k0 + i;
    buf[i] = (kb + key < L_) ? tile[key][dim] : (u16)0;
    psum += b2f(buf[i]);
  }
  *(s8v*)(VT + ((size_t)bh * 64 + dim) * LP_ + kb + k0) = *(s8v*)buf;
  *(s8v*)(VT + ((size_t)bh * 64 + dim) * LP_ + kb + k0 + 8) = *(s8v*)(buf + 8);
  if (vpart) {
    psum += __shfl_xor(psum, 1);
    psum += __shfl_xor(psum, 2);
    if ((t & 3) == 0) vpart[((size_t)bh * 24 + kt) * 64 + dim] = psum;
  }
}

// ---------------- LDS-staged swapped-operand MFMA flash attention -----------
template<int MODE>
__global__ __launch_bounds__(256) void flash_attn(
    const u16* __restrict__ Qm, const u16* __restrict__ Kg,
    const u16* __restrict__ VT, const int* __restrict__ top,
    float* __restrict__ POf, u16* POa, u16* POb,
    float* __restrict__ PM, float* __restrict__ PL) {
  constexpr int QSTR = (MODE == 0) ? 512 : 1536;
  constexpr int KSTR = (MODE == 0) ? 1024 : 1536;
  constexpr int TILES = (MODE == 0) ? 12 : 3;
  constexpr int NB = (MODE == 0) ? 48 : 8;
  __shared__ __align__(16) u16 Kt[64 * 64];        // [key][slot^(key&7)]
  __shared__ __align__(16) u16 Vt[64 * 64];        // [dim][slot^(dim&7)]
  __shared__ __align__(16) unsigned Xch[4][576];   // per-wave P exchange
  const int o = xswz(blockIdx.x, (B_ * H_ * NB) >> 3);
  int bh, sp, qb;
  if (MODE == 0) {
    bh = o / 48; int rem = o % 48; qb = rem >> 1; sp = rem & 1;
  } else {
    bh = o / 8; sp = o % 8; qb = 0;
  }
  const int h = bh & 7, b = bh >> 3;
  const int qoff = h * 64;
  const int koff = ((MODE == 0) ? 0 : 512) + h * 64;
  const int t = threadIdx.x, w = t >> 6, lane = t & 63;
  const int lg = lane >> 4, li = lane & 15;
  const u16* vtg = VT + (size_t)bh * 64 * LP_;
  unsigned* xw = Xch[w];
  u16* xw16 = (u16*)xw;

  int qrow;
  if (MODE == 0) {
    int q = qb * 64 + w * 16 + li;
    qrow = b * L_ + ((q < L_) ? q : (L_ - 1));
  } else {
    int u = w * 16 + li; if (u >= SK_) u = SK_ - 1;
    qrow = b * L_ + top[bh * SK_ + u];
  }
  s8v qf0 = *(const s8v*)(Qm + (size_t)qrow * QSTR + qoff + lg * 8);
  s8v qf1 = *(const s8v*)(Qm + (size_t)qrow * QSTR + qoff + 32 + lg * 8);

  f4 o4[4];                          // o4[n][r] = O^T[d=n*16+lg*4+r][q=li]
#pragma unroll
  for (int n = 0; n < 4; ++n) o4[n] = f4{0.f, 0.f, 0.f, 0.f};
  float m_run = -INFINITY, l_run = 0.f;   // per-lane (q=li)
  const int kt0 = sp * TILES;
  const int skey = lane >> 3;
  const int sslot = lane & 7;

#pragma unroll 1
  for (int ki = 0; ki < TILES; ++ki) {
    const int kb = (kt0 + ki) * 64;
#pragma unroll
    for (int j = 0; j < 2; ++j) {
      int row = w * 16 + j * 8 + skey;
      int gk = kb + row; if (gk >= L_) gk = L_ - 1;
      int ck = sslot ^ (row & 7);
      __builtin_amdgcn_global_load_lds(
          (const __attribute__((address_space(1))) void*)(Kg + (size_t)(b * L_ + gk) * KSTR + koff + ck * 8),
          (__attribute__((address_space(3))) void*)(Kt + (w * 16 + j * 8) * 64),
          16, 0, 0);
      int cv = sslot ^ (row & 7);
      __builtin_amdgcn_global_load_lds(
          (const __attribute__((address_space(1))) void*)(vtg + (size_t)row * LP_ + kb + cv * 8),
          (__attribute__((address_space(3))) void*)(Vt + (w * 16 + j * 8) * 64),
          16, 0, 0);
    }
    __syncthreads();
    f4 s[4];
#pragma unroll
    for (int c = 0; c < 4; ++c) {
      int key = c * 16 + li;
      s8v kf = *(const s8v*)(Kt + key * 64 + ((lg ^ (key & 7)) * 8));
      s8v kg2 = *(const s8v*)(Kt + key * 64 + (((lg + 4) ^ (key & 7)) * 8));
      f4 z = f4{0.f, 0.f, 0.f, 0.f};
      z = __builtin_amdgcn_mfma_f32_16x16x32_bf16(kf, qf0, z, 0, 0, 0);
      z = __builtin_amdgcn_mfma_f32_16x16x32_bf16(kg2, qf1, z, 0, 0, 0);
      s[c] = z * 0.125f;
    }
    if (kb + 64 > L_) {
#pragma unroll
      for (int c = 0; c < 4; ++c)
#pragma unroll
        for (int r = 0; r < 4; ++r)
          if (kb + c * 16 + lg * 4 + r >= L_) s[c][r] = -INFINITY;
    }
    float tm = -INFINITY;
#pragma unroll
    for (int c = 0; c < 4; ++c)
      tm = fmaxf(tm, fmaxf(fmaxf(s[c][0], s[c][1]), fmaxf(s[c][2], s[c][3])));
    tm = fmaxf(tm, __shfl_xor(tm, 16));
    tm = fmaxf(tm, __shfl_xor(tm, 32));
    // T13 defer-max: only rescale when some lane's max grew past threshold.
    if (!__all(tm <= m_run + 8.f)) {
      float mn = fmaxf(m_run, tm);
      float sc = __expf(m_run - mn);
      l_run *= sc;
      m_run = mn;
#pragma unroll
      for (int n = 0; n < 4; ++n) o4[n] *= sc;
    }
    float p[4][4];
    float rs = 0.f;
#pragma unroll
    for (int c = 0; c < 4; ++c)
#pragma unroll
      for (int r = 0; r < 4; ++r) { p[c][r] = __expf(s[c][r] - m_run); rs += p[c][r]; }
    rs += __shfl_xor(rs, 16);
    rs += __shfl_xor(rs, 32);
    l_run += rs;
    // pack P via v_cvt_pk_bf16_f32 (1 VALU op per pair vs ~9 manual)
#pragma unroll
    for (int c = 0; c < 4; ++c)
#pragma unroll
      for (int rp = 0; rp < 2; ++rp)
        xw[li * 36 + c * 8 + lg * 2 + rp] = cvt_pk(p[c][2 * rp], p[c][2 * rp + 1]);
    s8v pb0 = *(const s8v*)(xw + li * 36 + lg * 4);
    s8v pb1 = *(const s8v*)(xw + li * 36 + 16 + lg * 4);
#pragma unroll
    for (int n = 0; n < 4; ++n) {
      int dim = n * 16 + li;
      s8v vb0 = *(const s8v*)(Vt + dim * 64 + ((lg ^ (dim & 7)) * 8));
      o4[n] = __builtin_amdgcn_mfma_f32_16x16x32_bf16(vb0, pb0, o4[n], 0, 0, 0);
    }
#pragma unroll
    for (int n = 0; n < 4; ++n) {
      int dim = n * 16 + li;
      s8v vb1 = *(const s8v*)(Vt + dim * 64 + (((lg + 4) ^ (dim & 7)) * 8));
      o4[n] = __builtin_amdgcn_mfma_f32_16x16x32_bf16(vb1, pb1, o4[n], 0, 0, 0);
    }
    __syncthreads();
  }

  if (MODE == 0) {
    // per-wave LDS transpose [q][d] (packed stores), coalesced bf16 out
#pragma unroll
    for (int n = 0; n < 4; ++n)
#pragma unroll
      for (int rp = 0; rp < 2; ++rp)
        xw[li * 36 + n * 8 + lg * 2 + rp] = cvt_pk(o4[n][2 * rp], o4[n][2 * rp + 1]);
    u16* PO = sp ? POb : POa;
    const int pid = (bh * 24 + qb) * 2 + sp;
    int q_local = lane >> 2, d0 = (lane & 3) * 16;
    int q = qb * 64 + w * 16 + q_local;
    s8v v0 = *(const s8v*)(xw16 + q_local * 72 + d0);
    s8v v1 = *(const s8v*)(xw16 + q_local * 72 + d0 + 8);
    if (q < L_) {
      u16* dst = PO + ((size_t)(b * L_ + q)) * DM_ + qoff + d0;
      *(s8v*)dst = v0;
      *(s8v*)(dst + 8) = v1;
    }
    if (lg == 0) {
      PM[pid * 64 + w * 16 + li] = m_run;
      PL[pid * 64 + w * 16 + li] = l_run;
    }
  } else {
    int base = (bh * 8 + sp) * 64 + w * 16 + li;
#pragma unroll
    for (int n = 0; n < 4; ++n)
#pragma unroll
      for (int r = 0; r < 4; ++r)
        POf[(size_t)base * 64 + n * 16 + lg * 4 + r] = o4[n][r];
    if (lg == 0) {
      PM[base] = m_run;
      PL[base] = l_run;
    }
  }
}

// ---------------- combine 2-way cross partials (POb == ctxb, in place) ------
__global__ __launch_bounds__(256) void combine_cross(const u16* __restrict__ PO0,
                                                     const float* __restrict__ PM,
                                                     const float* __restrict__ PL,
                                                     u16* ctxb) {
  int idx = blockIdx.x * 256 + threadIdx.x;
  int row = idx >> 9, col = idx & 511;
  int b = row / L_, q = row - b * L_;
  int h = col >> 6;
  int bh = b * 8 + h, qbk = q >> 6, qi = q & 63;
  int p0 = ((bh * 24 + qbk) * 2) * 64 + qi;
  float m0 = PM[p0], m1 = PM[p0 + 64];
  float l0 = PL[p0], l1 = PL[p0 + 64];
  float M = fmaxf(m0, m1);
  float w0 = __expf(m0 - M), w1 = __expf(m1 - M);
  float inv = 1.f / (w0 * l0 + w1 * l1);
  float o0 = b2f(PO0[idx]);
  float o1 = b2f(ctxb[idx]);
  ctxb[idx] = f2b((w0 * o0 + w1 * o1) * inv);
}

// ---------------- fused combine split-K partials + scatter into ctxb --------
__global__ __launch_bounds__(256) void combine_prob_scatter(
    const float* __restrict__ PO, const float* __restrict__ PM,
    const float* __restrict__ PL, const int* __restrict__ top,
    u16* __restrict__ ctxb) {
  int bh = blockIdx.x;
  int t = threadIdx.x;
  int u = t >> 2, dg = (t & 3) * 16;
  if (u >= SK_) return;
  float M = -INFINITY;
  for (int s = 0; s < 8; ++s) M = fmaxf(M, PM[(bh * 8 + s) * 64 + u]);
  float wgt[8];
  float den = 0.f;
  for (int s = 0; s < 8; ++s) {
    wgt[s] = __expf(PM[(bh * 8 + s) * 64 + u] - M);
    den += wgt[s] * PL[(bh * 8 + s) * 64 + u];
  }
  float inv = 1.f / den;
  int h = bh & 7, b = bh >> 3;
  int l = top[bh * SK_ + u];
  u16* dst = ctxb + ((size_t)(b * L_ + l)) * DM_ + h * 64;
  for (int d = dg; d < dg + 16; ++d) {
    float acc = 0.f;
    for (int s = 0; s < 8; ++s) acc += wgt[s] * PO[(((size_t)bh * 8 + s) * 64 + u) * 64 + d];
    dst[d] = f2b(acc * inv);
  }
}

// ---------------- ctx = broadcast vmean (24 tile-partials inline) -----------
__global__ __launch_bounds__(256) void fill_ctx(const float* __restrict__ part,
                                                u16* __restrict__ ctxb) {
  int idx = blockIdx.x * 256 + threadIdx.x;
  int d = idx % 64;
  int h = (idx / 64) % H_;
  int b = idx / (L_ * DM_);
  int bh = b * 8 + h;
  float s = 0.f;
#pragma unroll
  for (int seg = 0; seg < 24; ++seg) s += part[((size_t)bh * 24 + seg) * 64 + d];
  ctxb[idx] = f2b(s * (1.f / (float)L_));
}

// ---------------- host side --------------------------------------------------
extern "C" void kernel_launch(void* const* d_in, const int* in_sizes, int n_in,
                              void* d_out, int out_size, void* d_ws, size_t ws_size,
                              hipStream_t stream) {
  const float* inflow   = (const float*)d_in[4];
  const float* W_emb_e  = (const float*)d_in[5];
  const float* b_emb_e  = (const float*)d_in[6];
  const float* W_emb_d  = (const float*)d_in[7];
  const float* b_emb_d  = (const float*)d_in[8];
  const float* enc_Wqkv = (const float*)d_in[9];
  const float* enc_bqkv = (const float*)d_in[10];
  const float* enc_Wo   = (const float*)d_in[11];
  const float* enc_bo   = (const float*)d_in[12];
  const float* enc_ln1g = (const float*)d_in[13];
  const float* enc_ln1b = (const float*)d_in[14];
  const float* enc_Wf1  = (const float*)d_in[15];
  const float* enc_bf1  = (const float*)d_in[16];
  const float* enc_Wf2  = (const float*)d_in[17];
  const float* enc_bf2  = (const float*)d_in[18];
  const float* enc_ln2g = (const float*)d_in[19];
  const float* enc_ln2b = (const float*)d_in[20];
  const float* enc_ng   = (const float*)d_in[21];
  const float* enc_nb   = (const float*)d_in[22];
  const float* dec_Wqkv = (const float*)d_in[23];
  const float* dec_bqkv = (const float*)d_in[24];
  const float* dec_Wo_s = (const float*)d_in[25];
  const float* dec_bo_s = (const float*)d_in[26];
  const float* dec_ln1g = (const float*)d_in[27];
  const float* dec_ln1b = (const float*)d_in[28];
  const float* dec_Wq_c = (const float*)d_in[29];
  const float* dec_bq_c = (const float*)d_in[30];
  const float* dec_Wkv  = (const float*)d_in[31];
  const float* dec_bkv  = (const float*)d_in[32];
  const float* dec_Wo_c = (const float*)d_in[33];
  const float* dec_bo_c = (const float*)d_in[34];
  const float* dec_ln2g = (const float*)d_in[35];
  const float* dec_ln2b = (const float*)d_in[36];
  const float* dec_Wf1  = (const float*)d_in[37];
  const float* dec_bf1  = (const float*)d_in[38];
  const float* dec_Wf2  = (const float*)d_in[39];
  const float* dec_bf2  = (const float*)d_in[40];
  const float* dec_ln3g = (const float*)d_in[41];
  const float* dec_ln3b = (const float*)d_in[42];
  const float* W_proj   = (const float*)d_in[43];
  const float* b_proj   = (const float*)d_in[44];
  const float* W1       = (const float*)d_in[45];
  const float* b1       = (const float*)d_in[46];
  const float* W3       = (const float*)d_in[47];
  const float* b3       = (const float*)d_in[48];
  const int*   samp     = (const int*)d_in[49];
  float* out = (float*)d_out;

  float* ws  = (float*)d_ws;
  float* PE  = ws;                       // 778240 f (dead after embeds -> PMc/PLc)
  float* X   = PE + 778240;              // 72960 f
  float* ACT = X + 72960;                // 3112960 f
  float* REG = ACT + 3112960;            // 6291456 f shared region
  float* MME = REG + 6291456;            // 48640 f
  float* CTT = MME + 48640;              // 81920 f (VME24: 49152 f)
  float* VME = CTT + 81920;              // 2048 f (unused)
  int*   TOP = (int*)(VME + 2048);       // 1280 i
  float* TAIL = VME + 2048 + 1280;
  u16* ENCb = (u16*)TAIL;                       // 6144*512 u16
  u16* DECb = (u16*)(TAIL + 1572864);
  u16* CTXb = (u16*)(TAIL + 2 * 1572864);
  u16* WBF  = (u16*)(TAIL + 3 * 1572864);       // 10485760 u16
  // prob split-K partials: FRESH memory after WBF (no CTXb overlay)
  float* POp = (float*)(WBF + 10485760);        // 1048576 f
  float* PMp = POp + 1048576;                   // 16384 f
  float* PLp = PMp + 16384;                     // 16384 f
  u16*   PO0 = (u16*)(PLp + 16384);             // cross split-0 partials [6144][512]

  // region overlays (prob phase)
  u16* QKVb = (u16*)REG;                 // [6144][1536]
  u16* FFb  = (u16*)REG;                 // [6144][2048]
  u16* VT   = (u16*)REG + 9437184;       // [32][64][1536] u16
  // region overlays (cross phase)
  u16* QCb  = (u16*)REG;                 // [6144][512]
  u16* KVCb = (u16*)REG + 3145728;       // [6144][1024] (K at +0, V at +512)
  // cross partial stats in dead PE region (32*24*2*64 = 98304 each)
  float* PMc = PE;
  float* PLc = PE + 98304;
  float* VME24 = CTT;                    // 32*24*64 = 49152 f

  auto GB = [&](const u16* A, const u16* Bt, const float* bias, const float* res,
                float* Cf, u16* Cb, int N, int K, int act) {
    dim3 g(N / 128, MP_ / 64);
    gemm_bf16_k64<<<g, 256, 0, stream>>>(A, Bt, bias, res, Cf, Cb, N, K, act);
  };
  auto PROB = [&](const int* sidx) {
    probM<<<B_ * H_ * L_ / 4, 256, 0, stream>>>(QKVb, sidx, MME);
    radix_topk<<<B_ * H_, 256, 0, stream>>>(MME, TOP);
    transpose_v<<<B_ * H_ * 24, 256, 0, stream>>>(QKVb, 1536, 1024, VT, VME24);
    flash_attn<1><<<B_ * H_ * 8, 256, 0, stream>>>(QKVb, QKVb, VT, TOP, POp,
                                                   nullptr, nullptr, PMp, PLp);
    fill_ctx<<<ML_ * DM_ / 256, 256, 0, stream>>>(VME24, CTXb);
    combine_prob_scatter<<<B_ * H_, 256, 0, stream>>>(POp, PMp, PLp, TOP, CTXb);
  };

  pe_kernel<<<(L_ * DM_ + 255) / 256, 256, 0, stream>>>(PE);
  extract_x<<<(ML_ * 12 + 255) / 256, 256, 0, stream>>>(inflow, X);

  // one fused weight-conversion dispatch (LDS tiled transpose)
  {
    CvtArgs a;
    const float* s[15] = {
      enc_Wqkv, enc_Wqkv + 512 * 1536, enc_Wo, enc_Wo + 512 * 512,
      enc_Wf1, enc_Wf1 + 512 * 2048, enc_Wf2, enc_Wf2 + 2048 * 512,
      dec_Wqkv, dec_Wo_s, dec_Wq_c, dec_Wkv, dec_Wo_c, dec_Wf1, dec_Wf2 };
    unsigned cumt[16] = { 0u, 768u, 1536u, 1792u, 2048u, 3072u,
                          4096u, 5120u, 6144u, 6912u, 7168u,
                          7424u, 7936u, 8192u, 9216u, 10240u };
    unsigned lk[15] = { 9, 9, 9, 9, 9, 9, 11, 11, 9, 9, 9, 9, 9, 9, 11 };
    for (int i = 0; i < 15; ++i) { a.src[i] = s[i]; a.lk[i] = lk[i]; }
    for (int i = 0; i < 16; ++i) a.cumt[i] = cumt[i];
    cvt_all<<<10240, 256, 0, stream>>>(a, WBF);
  }
  u16* Wt_qkv_e0 = WBF + 0;
  u16* Wt_qkv_e1 = WBF + 786432;
  u16* Wt_o_e0   = WBF + 1572864;
  u16* Wt_o_e1   = WBF + 1835008;
  u16* Wt_f1_e0  = WBF + 2097152;
  u16* Wt_f1_e1  = WBF + 3145728;
  u16* Wt_f2_e0  = WBF + 4194304;
  u16* Wt_f2_e1  = WBF + 5242880;
  u16* Wt_qkv_d  = WBF + 6291456;
  u16* Wt_o_s    = WBF + 7077888;
  u16* Wt_q_c    = WBF + 7340032;
  u16* Wt_kv_c   = WBF + 7602176;
  u16* Wt_o_c    = WBF + 8126464;
  u16* Wt_f1_d   = WBF + 8388608;
  u16* Wt_f2_d   = WBF + 9437184;

  // ---------------- encoder ----------------
  embed_fused<<<MP_ / 4, 256, 0, stream>>>(X, W_emb_e, b_emb_e, PE, ACT, ENCb);

  const u16* Wqkv_e[2] = {Wt_qkv_e0, Wt_qkv_e1};
  const u16* Wo_e[2]   = {Wt_o_e0, Wt_o_e1};
  const u16* Wf1_e[2]  = {Wt_f1_e0, Wt_f1_e1};
  const u16* Wf2_e[2]  = {Wt_f2_e0, Wt_f2_e1};
  for (int i = 0; i < 2; ++i) {
    GB(ENCb, Wqkv_e[i], enc_bqkv + i * 1536, nullptr, nullptr, QKVb, 1536, 512, 0);
    PROB(samp + (size_t)i * L_ * SK_);
    GB(CTXb, Wo_e[i], enc_bo + i * 512, ACT, ACT, nullptr, 512, 512, 0);
    layernorm_ip<<<ML_ / 4, 256, 0, stream>>>(ACT, enc_ln1g + i * 512, enc_ln1b + i * 512, ENCb);
    GB(ENCb, Wf1_e[i], enc_bf1 + i * 2048, nullptr, nullptr, FFb, 2048, 512, 1);
    GB(FFb, Wf2_e[i], enc_bf2 + i * 512, ACT, ACT, nullptr, 512, 2048, 0);
    layernorm_ip<<<ML_ / 4, 256, 0, stream>>>(ACT, enc_ln2g + i * 512, enc_ln2b + i * 512, ENCb);
  }
  layernorm_ip<<<ML_ / 4, 256, 0, stream>>>(ACT, enc_ng, enc_nb, ENCb);

  // ---------------- decoder ----------------
  embed_fused<<<MP_ / 4, 256, 0, stream>>>(X, W_emb_d, b_emb_d, PE, ACT, DECb);
  GB(DECb, Wt_qkv_d, dec_bqkv, nullptr, nullptr, QKVb, 1536, 512, 0);
  PROB(samp + (size_t)2 * L_ * SK_);
  GB(CTXb, Wt_o_s, dec_bo_s, ACT, ACT, nullptr, 512, 512, 0);
  layernorm_ip<<<ML_ / 4, 256, 0, stream>>>(ACT, dec_ln1g, dec_ln1b, DECb);

  // cross attention: Q GEMM + merged K/V GEMM (N=1024, KVC layout)
  GB(DECb, Wt_q_c, dec_bq_c, nullptr, nullptr, QCb, 512, 512, 0);
  GB(ENCb, Wt_kv_c, dec_bkv, nullptr, nullptr, KVCb, 1024, 512, 0);
  transpose_v<<<B_ * H_ * 24, 256, 0, stream>>>(KVCb, 1024, 512, VT, nullptr);
  flash_attn<0><<<B_ * H_ * 48, 256, 0, stream>>>(QCb, KVCb, VT, nullptr, nullptr,
                                                  PO0, CTXb, PMc, PLc);
  combine_cross<<<ML_ * DM_ / 256, 256, 0, stream>>>(PO0, PMc, PLc, CTXb);
  GB(CTXb, Wt_o_c, dec_bo_c, ACT, ACT, nullptr, 512, 512, 0);
  layernorm_ip<<<ML_ / 4, 256, 0, stream>>>(ACT, dec_ln2g, dec_ln2b, DECb);

  GB(DECb, Wt_f1_d, dec_bf1, nullptr, nullptr, FFb, 2048, 512, 1);
  GB(FFb, Wt_f2_d, dec_bf2, ACT, ACT, nullptr, 512, 2048, 0);
  layernorm_ip<<<ML_ / 4, 256, 0, stream>>>(ACT, dec_ln3g, dec_ln3b, DECb);

  // fused head
  head_fused<<<ML_ / 4, 256, 0, stream>>>(ACT, X, W_proj, b_proj, W1, b1, W3, b3, out);
}